// Round 1
// baseline (10778.654 us; speedup 1.0000x reference)
//
#include <hip/hip_runtime.h>
#include <cstddef>
#include <cstdint>

// Problem constants
#define E_EDGES 1000000
#define NU 100000
#define NM 20000
#define DU 128
#define DM 404
#define HIDDIM 256
#define OUTDIM 128

constexpr int KT = 32;

// ---------------- degree counts ----------------
__global__ __launch_bounds__(256) void count_kernel(const int* __restrict__ src,
                                                    const int* __restrict__ dst,
                                                    float* __restrict__ cu,
                                                    float* __restrict__ cm, int E) {
  int e = blockIdx.x * 256 + threadIdx.x;
  if (e < E) {
    unsafeAtomicAdd(&cu[src[e]], 1.0f);
    unsafeAtomicAdd(&cm[dst[e]], 1.0f);
  }
}

__global__ __launch_bounds__(256) void rcp_kernel(float* __restrict__ c, int n) {
  int i = blockIdx.x * 256 + threadIdx.x;
  if (i < n) c[i] = 1.0f / fmaxf(c[i], 1.0f);
}

// ---------------- edge scatter-add: agg[sidx[e]] += feat[gidx[e]] ----------------
template <int D>
__global__ __launch_bounds__(256) void scatter_add_kernel(const float* __restrict__ feat,
                                                          const int* __restrict__ gidx,
                                                          const int* __restrict__ sidx,
                                                          float* __restrict__ agg, int E) {
  constexpr int TPE = D / 4;  // threads per edge (float4 each)
  long long idx = (long long)blockIdx.x * 256 + threadIdx.x;
  int e = (int)(idx / TPE);
  if (e >= E) return;
  int c = (int)(idx % TPE) * 4;
  int g = gidx[e];
  int s = sidx[e];
  const float4 v = *reinterpret_cast<const float4*>(&feat[(size_t)g * D + c]);
  float* p = &agg[(size_t)s * D + c];
  unsafeAtomicAdd(p + 0, v.x);
  unsafeAtomicAdd(p + 1, v.y);
  unsafeAtomicAdd(p + 2, v.z);
  unsafeAtomicAdd(p + 3, v.w);
}

// ---------------- fused SAGE row GEMM ----------------
// out[row, :] = maybe_relu( [AGG]  (S[row,:]*rcp[row]) @ Wl
//                          + X[row,:] @ Wr
//                          + [ELEM] S[row,:]*rcp[row]
//                          + [AGG||ELEM] bias )
// Block: 256 threads = 64 col-threads x 4 row-groups; tile = 32 rows x N cols.
// rows must be a multiple of 32 (20000 and 100000 both are).
template <int N, bool AGG, bool ELEM, bool RELU>
__global__ __launch_bounds__(256) void sage_row_kernel(
    const float* __restrict__ S, const float* __restrict__ rcp,
    const float* __restrict__ Wl, int Kl,
    const float* __restrict__ X, const float* __restrict__ Wr, int Kr,
    const float* __restrict__ bias,
    float* __restrict__ out, int rows) {
  constexpr int CN = N / 64;  // cols per thread: 4 (N=256) or 2 (N=128)
  constexpr bool HAS_BIAS = AGG || ELEM;
  const int tid = threadIdx.x;
  const int tn = tid & 63;
  const int tg = tid >> 6;
  const int row0 = blockIdx.x * 32;
  const int n0 = tn * CN;
  const int r0 = tg * 8;

  __shared__ float a_t[KT][32];   // transposed A tile: a_t[k][m]
  __shared__ float w_t[KT][N];    // W tile

  float acc[8][CN];
#pragma unroll
  for (int r = 0; r < 8; ++r)
#pragma unroll
    for (int c = 0; c < CN; ++c) acc[r][c] = 0.0f;

  auto fma_k = [&](int k) {
    float av[8];
    *reinterpret_cast<float4*>(&av[0]) = *reinterpret_cast<const float4*>(&a_t[k][r0]);
    *reinterpret_cast<float4*>(&av[4]) = *reinterpret_cast<const float4*>(&a_t[k][r0 + 4]);
    float wv[CN];
    if constexpr (CN == 4) {
      *reinterpret_cast<float4*>(&wv[0]) = *reinterpret_cast<const float4*>(&w_t[k][n0]);
    } else {
      float2 t2v = *reinterpret_cast<const float2*>(&w_t[k][n0]);
      wv[0] = t2v.x; wv[1] = t2v.y;
    }
#pragma unroll
    for (int r = 0; r < 8; ++r)
#pragma unroll
      for (int c = 0; c < CN; ++c) acc[r][c] = fmaf(av[r], wv[c], acc[r][c]);
  };

  for (int phase = (AGG ? 0 : 1); phase < 2; ++phase) {
    const float* A = (phase == 0) ? S : X;
    const float* W = (phase == 0) ? Wl : Wr;
    const int K = (phase == 0) ? Kl : Kr;
    const bool scale = AGG && (phase == 0);

    for (int k0 = 0; k0 < K; k0 += KT) {
      __syncthreads();
      // stage A tile (scaled by rcp[row] in phase 0 of AGG)
      {
        const int m = tid >> 3;          // 0..31 (row within tile)
        const int kq = tid & 7;          // 0..7
        const int row = row0 + m;
        const int k = k0 + kq * 4;
        float4 v = make_float4(0.f, 0.f, 0.f, 0.f);
        if (k < K) v = *reinterpret_cast<const float4*>(&A[(size_t)row * K + k]);
        const float sc = scale ? rcp[row] : 1.0f;
        a_t[kq * 4 + 0][m] = v.x * sc;
        a_t[kq * 4 + 1][m] = v.y * sc;
        a_t[kq * 4 + 2][m] = v.z * sc;
        a_t[kq * 4 + 3][m] = v.w * sc;
      }
      // stage W tile
      {
        constexpr int NV = (KT * N / 4) / 256;
#pragma unroll
        for (int v4 = 0; v4 < NV; ++v4) {
          const int li = v4 * 256 + tid;
          const int k = li / (N / 4);
          const int n = (li % (N / 4)) * 4;
          float4 wv = make_float4(0.f, 0.f, 0.f, 0.f);
          if (k0 + k < K) wv = *reinterpret_cast<const float4*>(&W[(size_t)(k0 + k) * N + n]);
          *reinterpret_cast<float4*>(&w_t[k][n]) = wv;
        }
      }
      __syncthreads();
      const int kmax = (K - k0 < KT) ? (K - k0) : KT;
      if (kmax == KT) {
#pragma unroll
        for (int k = 0; k < KT; ++k) fma_k(k);
      } else {
        for (int k = 0; k < kmax; ++k) fma_k(k);
      }
    }
  }

  // epilogue
  float bv[CN];
  if constexpr (HAS_BIAS) {
    if constexpr (CN == 4) {
      *reinterpret_cast<float4*>(&bv[0]) = *reinterpret_cast<const float4*>(&bias[n0]);
    } else {
      float2 t2v = *reinterpret_cast<const float2*>(&bias[n0]);
      bv[0] = t2v.x; bv[1] = t2v.y;
    }
  }
#pragma unroll
  for (int r = 0; r < 8; ++r) {
    const int row = row0 + r0 + r;
    float vals[CN];
#pragma unroll
    for (int c = 0; c < CN; ++c) vals[c] = acc[r][c];
    if constexpr (ELEM) {
      const float sc = rcp[row];
      float sv[CN];
      if constexpr (CN == 4) {
        *reinterpret_cast<float4*>(&sv[0]) = *reinterpret_cast<const float4*>(&S[(size_t)row * N + n0]);
      } else {
        float2 t2v = *reinterpret_cast<const float2*>(&S[(size_t)row * N + n0]);
        sv[0] = t2v.x; sv[1] = t2v.y;
      }
#pragma unroll
      for (int c = 0; c < CN; ++c) vals[c] = fmaf(sv[c], sc, vals[c]);
    }
    if constexpr (HAS_BIAS) {
#pragma unroll
      for (int c = 0; c < CN; ++c) vals[c] += bv[c];
    }
    if constexpr (RELU) {
#pragma unroll
      for (int c = 0; c < CN; ++c) vals[c] = fmaxf(vals[c], 0.0f);
    }
    if constexpr (CN == 4) {
      *reinterpret_cast<float4*>(&out[(size_t)row * N + n0]) = *reinterpret_cast<const float4*>(&vals[0]);
    } else {
      float2 t2v; t2v.x = vals[0]; t2v.y = vals[1];
      *reinterpret_cast<float2*>(&out[(size_t)row * N + n0]) = t2v;
    }
  }
}

extern "C" void kernel_launch(void* const* d_in, const int* in_sizes, int n_in,
                              void* d_out, int out_size, void* d_ws, size_t ws_size,
                              hipStream_t stream) {
  const float* x_user  = (const float*)d_in[0];
  const float* x_movie = (const float*)d_in[1];
  const int*   esrc    = (const int*)d_in[2];
  const int*   edst    = (const int*)d_in[3];
  const float* w1_rm_l = (const float*)d_in[4];
  const float* b1_rm   = (const float*)d_in[5];
  const float* w1_rm_r = (const float*)d_in[6];
  const float* w1_mu_l = (const float*)d_in[7];
  const float* b1_mu   = (const float*)d_in[8];
  const float* w1_mu_r = (const float*)d_in[9];
  const float* w2_rm_l = (const float*)d_in[10];
  const float* b2_rm   = (const float*)d_in[11];
  const float* w2_rm_r = (const float*)d_in[12];
  const float* w2_mu_l = (const float*)d_in[13];
  const float* b2_mu   = (const float*)d_in[14];
  const float* w2_mu_r = (const float*)d_in[15];

  // workspace arena (floats)
  // slot0  [0, 5.12M)      : S1m (2.56M) -> t1 (5.12M) -> t2 (2.56M)
  // slot1  [5.12M, 10.24M) : h_movie
  // slot2  [10.24M, 35.84M): S1u -> h_user (in-place)
  // slot3  [35.84M, 53.76M): S2m (5.12M) + S2u (12.8M)
  // cnt    [53.76M, 53.88M): cnt_m (20k) + cnt_u (100k)  (stored as reciprocals)
  if (ws_size < 53880000ull * 4ull) return;  // insufficient scratch -> fail loudly
  float* ws      = (float*)d_ws;
  float* slot0   = ws;
  float* h_movie = ws + 5120000;
  float* slot2   = ws + 10240000;   // S1u / h_user
  float* S2m     = ws + 35840000;
  float* S2u     = ws + 40960000;
  float* cnt_m   = ws + 53760000;
  float* cnt_u   = ws + 53780000;

  float* out_movie = (float*)d_out;
  float* out_user  = (float*)d_out + (size_t)NM * OUTDIM;  // +2,560,000

  // zero accumulation buffers (must happen every call; harness doesn't re-poison)
  hipMemsetAsync(slot0, 0, (size_t)NM * DU * 4, stream);               // S1m 10.24MB
  hipMemsetAsync(slot2, 0, (size_t)NU * HIDDIM * 4, stream);           // S1u 102.4MB
  hipMemsetAsync(S2m, 0, ((size_t)NM * HIDDIM + (size_t)NU * OUTDIM) * 4, stream);  // S2m+S2u
  hipMemsetAsync(cnt_m, 0, (size_t)(NM + NU) * 4, stream);

  // degrees -> reciprocals
  count_kernel<<<(E_EDGES + 255) / 256, 256, 0, stream>>>(esrc, edst, cnt_u, cnt_m, E_EDGES);
  rcp_kernel<<<(NM + 255) / 256, 256, 0, stream>>>(cnt_m, NM);
  rcp_kernel<<<(NU + 255) / 256, 256, 0, stream>>>(cnt_u, NU);

  // L1 movie side: S1m += x_user[esrc] at rows edst
  scatter_add_kernel<DU><<<E_EDGES * (DU / 4) / 256, 256, 0, stream>>>(
      x_user, esrc, edst, slot0, E_EDGES);
  // h_movie = relu((S1m*rcp_m)@w1_rm_l + b1_rm + x_movie@w1_rm_r)
  sage_row_kernel<HIDDIM, true, false, true><<<NM / 32, 256, 0, stream>>>(
      slot0, cnt_m, w1_rm_l, DU, x_movie, w1_rm_r, DM, b1_rm, h_movie, NM);

  // L1 user side: t1 = x_movie @ w1_mu_l  (slot0; S1m now dead)
  sage_row_kernel<HIDDIM, false, false, false><<<NM / 32, 256, 0, stream>>>(
      nullptr, nullptr, nullptr, 0, x_movie, w1_mu_l, DM, nullptr, slot0, NM);
  // S1u += t1[edst] at rows esrc
  scatter_add_kernel<HIDDIM><<<E_EDGES * (HIDDIM / 4) / 256, 256, 0, stream>>>(
      slot0, edst, esrc, slot2, E_EDGES);
  // h_user = relu(S1u*rcp_u + b1_mu + x_user@w1_mu_r)   (in-place into slot2)
  sage_row_kernel<HIDDIM, false, true, true><<<NU / 32, 256, 0, stream>>>(
      slot2, cnt_u, nullptr, 0, x_user, w1_mu_r, DU, b1_mu, slot2, NU);

  // L2 movie side: S2m += h_user[esrc] at rows edst
  scatter_add_kernel<HIDDIM><<<E_EDGES * (HIDDIM / 4) / 256, 256, 0, stream>>>(
      slot2, esrc, edst, S2m, E_EDGES);
  // out_movie = (S2m*rcp_m)@w2_rm_l + b2_rm + h_movie@w2_rm_r
  sage_row_kernel<OUTDIM, true, false, false><<<NM / 32, 256, 0, stream>>>(
      S2m, cnt_m, w2_rm_l, HIDDIM, h_movie, w2_rm_r, HIDDIM, b2_rm, out_movie, NM);

  // L2 user side: t2 = h_movie @ w2_mu_l (slot0; t1 dead)
  sage_row_kernel<OUTDIM, false, false, false><<<NM / 32, 256, 0, stream>>>(
      nullptr, nullptr, nullptr, 0, h_movie, w2_mu_l, HIDDIM, nullptr, slot0, NM);
  // S2u += t2[edst] at rows esrc
  scatter_add_kernel<OUTDIM><<<E_EDGES * (OUTDIM / 4) / 256, 256, 0, stream>>>(
      slot0, edst, esrc, S2u, E_EDGES);
  // out_user = S2u*rcp_u + b2_mu + h_user@w2_mu_r
  sage_row_kernel<OUTDIM, false, true, false><<<NU / 32, 256, 0, stream>>>(
      S2u, cnt_u, nullptr, 0, slot2, w2_mu_r, HIDDIM, b2_mu, out_user, NU);
}

// Round 2
// 1442.619 us; speedup vs baseline: 7.4716x; 7.4716x over previous
//
#include <hip/hip_runtime.h>
#include <cstddef>
#include <cstdint>

// Problem constants
#define E_EDGES 1000000
#define NU 100000
#define NM 20000
#define DU 128
#define DM 404
#define HIDDIM 256
#define OUTDIM 128

constexpr int KT = 32;

// ---------------- degree histogram ----------------
__global__ __launch_bounds__(256) void hist_kernel(const int* __restrict__ esrc,
                                                   const int* __restrict__ edst,
                                                   int* __restrict__ deg_u,
                                                   int* __restrict__ deg_m, int E) {
  int e = blockIdx.x * 256 + threadIdx.x;
  if (e < E) {
    atomicAdd(&deg_u[esrc[e]], 1);
    atomicAdd(&deg_m[edst[e]], 1);
  }
}

// ---------------- exclusive scan (single workgroup, wave-scan + LDS) ----------------
__global__ __launch_bounds__(1024) void scan_kernel(const int* __restrict__ deg,
                                                    int* __restrict__ off, int n) {
  const int tid = threadIdx.x;
  const int lane = tid & 63;
  const int w = tid >> 6;  // 16 waves
  __shared__ int wsum[16];
  int carry = 0;
  for (int base = 0; base < n; base += 1024) {
    const int i = base + tid;
    const int v = (i < n) ? deg[i] : 0;
    // inclusive wave scan
    int s = v;
#pragma unroll
    for (int d = 1; d < 64; d <<= 1) {
      int t = __shfl_up(s, d, 64);
      if (lane >= d) s += t;
    }
    if (lane == 63) wsum[w] = s;
    __syncthreads();
    int woff = 0, ctot = 0;
#pragma unroll
    for (int j = 0; j < 16; ++j) {
      int x = wsum[j];
      if (j < w) woff += x;
      ctot += x;
    }
    if (i < n) off[i] = carry + woff + s - v;  // exclusive
    carry += ctot;
    __syncthreads();
  }
  if (tid == 0) off[n] = carry;
}

__global__ __launch_bounds__(256) void copy_int_kernel(const int* __restrict__ a,
                                                       int* __restrict__ b, int n) {
  int i = blockIdx.x * 256 + threadIdx.x;
  if (i < n) b[i] = a[i];
}

// ---------------- CSR fill (atomic cursors) ----------------
__global__ __launch_bounds__(256) void csr_fill_kernel(const int* __restrict__ esrc,
                                                       const int* __restrict__ edst,
                                                       int* __restrict__ cur_m,
                                                       int* __restrict__ cur_u,
                                                       int* __restrict__ csr_m,
                                                       int* __restrict__ csr_u, int E) {
  int e = blockIdx.x * 256 + threadIdx.x;
  if (e >= E) return;
  const int s = esrc[e], d = edst[e];
  const int pm = atomicAdd(&cur_m[d], 1);
  csr_m[pm] = s;  // for each movie: list of user ids
  const int pu = atomicAdd(&cur_u[s], 1);
  csr_u[pu] = d;  // for each user: list of movie ids
}

// ---------------- gather-mean: out[node,:] = mean over idx[off[node]..off[node+1]) of table[idx,:]
// One wave per destination node; 4 waves (4 nodes) per block.
template <int D>
__global__ __launch_bounds__(256) void gather_mean_kernel(const float* __restrict__ table,
                                                          const int* __restrict__ off,
                                                          const int* __restrict__ idx,
                                                          float* __restrict__ out, int n) {
  const int w = threadIdx.x >> 6;
  const int lane = threadIdx.x & 63;
  const int node = blockIdx.x * 4 + w;
  if (node >= n) return;
  const int beg = off[node], end = off[node + 1];
  const int deg = end - beg;
  float acc[4] = {0.f, 0.f, 0.f, 0.f};
  if constexpr (D == 256) {
    const int c = lane * 4;
    for (int p = beg; p < end; ++p) {
      const int r = idx[p];
      const float4 v = *reinterpret_cast<const float4*>(&table[(size_t)r * D + c]);
      acc[0] += v.x; acc[1] += v.y; acc[2] += v.z; acc[3] += v.w;
    }
    const float sc = 1.0f / fmaxf((float)deg, 1.0f);
    float4 o;
    o.x = acc[0] * sc; o.y = acc[1] * sc; o.z = acc[2] * sc; o.w = acc[3] * sc;
    *reinterpret_cast<float4*>(&out[(size_t)node * D + c]) = o;
  } else {  // D==128: two edges per iteration (half-wave each)
    const int h = lane >> 5;
    const int c = (lane & 31) * 4;
    for (int p = beg + h; p < end; p += 2) {
      const int r = idx[p];
      const float4 v = *reinterpret_cast<const float4*>(&table[(size_t)r * D + c]);
      acc[0] += v.x; acc[1] += v.y; acc[2] += v.z; acc[3] += v.w;
    }
#pragma unroll
    for (int k2 = 0; k2 < 4; ++k2) acc[k2] += __shfl_down(acc[k2], 32, 64);
    if (h == 0) {
      const float sc = 1.0f / fmaxf((float)deg, 1.0f);
      float4 o;
      o.x = acc[0] * sc; o.y = acc[1] * sc; o.z = acc[2] * sc; o.w = acc[3] * sc;
      *reinterpret_cast<float4*>(&out[(size_t)node * D + c]) = o;
    }
  }
}

// ---------------- fused SAGE row GEMM ----------------
// out[row,:] = maybe_relu( [TWOG] S[row,:] @ Wl
//                         + X[row,:] @ Wr
//                         + [ELEM] S[row,:]
//                         + [TWOG||ELEM] bias )
// Block: 256 threads = 64 col-threads x 4 row-groups; tile = 32 rows x N cols.
template <int N, bool TWOG, bool ELEM, bool RELU>
__global__ __launch_bounds__(256) void sage_row_kernel(
    const float* __restrict__ S,
    const float* __restrict__ Wl, int Kl,
    const float* __restrict__ X, const float* __restrict__ Wr, int Kr,
    const float* __restrict__ bias,
    float* __restrict__ out, int rows) {
  constexpr int CN = N / 64;  // cols per thread: 4 (N=256) or 2 (N=128)
  constexpr bool HAS_BIAS = TWOG || ELEM;
  const int tid = threadIdx.x;
  const int tn = tid & 63;
  const int tg = tid >> 6;
  const int row0 = blockIdx.x * 32;
  const int n0 = tn * CN;
  const int r0 = tg * 8;

  __shared__ float a_t[KT][32];  // transposed A tile: a_t[k][m]
  __shared__ float w_t[KT][N];   // W tile

  float acc[8][CN];
#pragma unroll
  for (int r = 0; r < 8; ++r)
#pragma unroll
    for (int c = 0; c < CN; ++c) acc[r][c] = 0.0f;

  auto fma_k = [&](int k) {
    float av[8];
    *reinterpret_cast<float4*>(&av[0]) = *reinterpret_cast<const float4*>(&a_t[k][r0]);
    *reinterpret_cast<float4*>(&av[4]) = *reinterpret_cast<const float4*>(&a_t[k][r0 + 4]);
    float wv[CN];
    if constexpr (CN == 4) {
      *reinterpret_cast<float4*>(&wv[0]) = *reinterpret_cast<const float4*>(&w_t[k][n0]);
    } else {
      float2 t2v = *reinterpret_cast<const float2*>(&w_t[k][n0]);
      wv[0] = t2v.x; wv[1] = t2v.y;
    }
#pragma unroll
    for (int r = 0; r < 8; ++r)
#pragma unroll
      for (int c = 0; c < CN; ++c) acc[r][c] = fmaf(av[r], wv[c], acc[r][c]);
  };

  for (int phase = (TWOG ? 0 : 1); phase < 2; ++phase) {
    const float* A = (phase == 0) ? S : X;
    const float* W = (phase == 0) ? Wl : Wr;
    const int K = (phase == 0) ? Kl : Kr;

    for (int k0 = 0; k0 < K; k0 += KT) {
      __syncthreads();
      // stage A tile (transposed)
      {
        const int m = tid >> 3;  // 0..31
        const int kq = tid & 7;  // 0..7
        const int row = row0 + m;
        const int k = k0 + kq * 4;
        float4 v = make_float4(0.f, 0.f, 0.f, 0.f);
        if (k < K) v = *reinterpret_cast<const float4*>(&A[(size_t)row * K + k]);
        a_t[kq * 4 + 0][m] = v.x;
        a_t[kq * 4 + 1][m] = v.y;
        a_t[kq * 4 + 2][m] = v.z;
        a_t[kq * 4 + 3][m] = v.w;
      }
      // stage W tile
      {
        constexpr int NV = (KT * N / 4) / 256;
#pragma unroll
        for (int v4 = 0; v4 < NV; ++v4) {
          const int li = v4 * 256 + tid;
          const int k = li / (N / 4);
          const int n = (li % (N / 4)) * 4;
          float4 wv = make_float4(0.f, 0.f, 0.f, 0.f);
          if (k0 + k < K) wv = *reinterpret_cast<const float4*>(&W[(size_t)(k0 + k) * N + n]);
          *reinterpret_cast<float4*>(&w_t[k][n]) = wv;
        }
      }
      __syncthreads();
      const int kmax = (K - k0 < KT) ? (K - k0) : KT;
      if (kmax == KT) {
#pragma unroll
        for (int k = 0; k < KT; ++k) fma_k(k);
      } else {
        for (int k = 0; k < kmax; ++k) fma_k(k);
      }
    }
  }

  // epilogue
  float bv[CN];
  if constexpr (HAS_BIAS) {
    if constexpr (CN == 4) {
      *reinterpret_cast<float4*>(&bv[0]) = *reinterpret_cast<const float4*>(&bias[n0]);
    } else {
      float2 t2v = *reinterpret_cast<const float2*>(&bias[n0]);
      bv[0] = t2v.x; bv[1] = t2v.y;
    }
  }
#pragma unroll
  for (int r = 0; r < 8; ++r) {
    const int row = row0 + r0 + r;
    float vals[CN];
#pragma unroll
    for (int c = 0; c < CN; ++c) vals[c] = acc[r][c];
    if constexpr (ELEM) {
      float sv[CN];
      if constexpr (CN == 4) {
        *reinterpret_cast<float4*>(&sv[0]) = *reinterpret_cast<const float4*>(&S[(size_t)row * N + n0]);
      } else {
        float2 t2v = *reinterpret_cast<const float2*>(&S[(size_t)row * N + n0]);
        sv[0] = t2v.x; sv[1] = t2v.y;
      }
#pragma unroll
      for (int c = 0; c < CN; ++c) vals[c] += sv[c];
    }
    if constexpr (HAS_BIAS) {
#pragma unroll
      for (int c = 0; c < CN; ++c) vals[c] += bv[c];
    }
    if constexpr (RELU) {
#pragma unroll
      for (int c = 0; c < CN; ++c) vals[c] = fmaxf(vals[c], 0.0f);
    }
    if constexpr (CN == 4) {
      *reinterpret_cast<float4*>(&out[(size_t)row * N + n0]) = *reinterpret_cast<const float4*>(&vals[0]);
    } else {
      float2 t2v;
      t2v.x = vals[0]; t2v.y = vals[1];
      *reinterpret_cast<float2*>(&out[(size_t)row * N + n0]) = t2v;
    }
  }
}

extern "C" void kernel_launch(void* const* d_in, const int* in_sizes, int n_in,
                              void* d_out, int out_size, void* d_ws, size_t ws_size,
                              hipStream_t stream) {
  const float* x_user  = (const float*)d_in[0];
  const float* x_movie = (const float*)d_in[1];
  const int*   esrc    = (const int*)d_in[2];
  const int*   edst    = (const int*)d_in[3];
  const float* w1_rm_l = (const float*)d_in[4];
  const float* b1_rm   = (const float*)d_in[5];
  const float* w1_rm_r = (const float*)d_in[6];
  const float* w1_mu_l = (const float*)d_in[7];
  const float* b1_mu   = (const float*)d_in[8];
  const float* w1_mu_r = (const float*)d_in[9];
  const float* w2_rm_l = (const float*)d_in[10];
  const float* b2_rm   = (const float*)d_in[11];
  const float* w2_rm_r = (const float*)d_in[12];
  const float* w2_mu_l = (const float*)d_in[13];
  const float* b2_mu   = (const float*)d_in[14];
  const float* w2_mu_r = (const float*)d_in[15];

  // workspace layout (floats)
  // bufA [0, 25.6M)        : M1u -> h_user (in-place)
  // bufB [25.6M, 30.72M)   : t1 -> t2
  // bufC [30.72M, 35.84M)  : h_movie
  // bufD [35.84M, 48.64M)  : hu_l -> M2u
  // bufE [48.64M, 51.2M)   : M1m -> M2m
  // ints at +51.2M: deg_m(20000) off_m(20001) cur_m(20000)
  //                 deg_u(100000) off_u(100001) cur_u(100000)
  //                 csr_m(1M) csr_u(1M)
  if (ws_size < 214240008ull) return;  // insufficient scratch -> fail loudly
  float* ws   = (float*)d_ws;
  float* bufA = ws;
  float* bufB = ws + 25600000;
  float* bufC = ws + 30720000;
  float* bufD = ws + 35840000;
  float* bufE = ws + 48640000;
  int* iw    = (int*)(ws + 51200000);
  int* deg_m = iw;
  int* off_m = iw + 20000;
  int* cur_m = iw + 40001;
  int* deg_u = iw + 60001;
  int* off_u = iw + 160001;
  int* cur_u = iw + 260002;
  int* csr_m = iw + 360002;
  int* csr_u = iw + 1360002;

  float* out_movie = (float*)d_out;
  float* out_user  = (float*)d_out + (size_t)NM * OUTDIM;

  // ---- CSR build ----
  hipMemsetAsync(deg_m, 0, NM * sizeof(int), stream);
  hipMemsetAsync(deg_u, 0, NU * sizeof(int), stream);
  hist_kernel<<<(E_EDGES + 255) / 256, 256, 0, stream>>>(esrc, edst, deg_u, deg_m, E_EDGES);
  scan_kernel<<<1, 1024, 0, stream>>>(deg_m, off_m, NM);
  scan_kernel<<<1, 1024, 0, stream>>>(deg_u, off_u, NU);
  copy_int_kernel<<<(NM + 255) / 256, 256, 0, stream>>>(off_m, cur_m, NM);
  copy_int_kernel<<<(NU + 255) / 256, 256, 0, stream>>>(off_u, cur_u, NU);
  csr_fill_kernel<<<(E_EDGES + 255) / 256, 256, 0, stream>>>(esrc, edst, cur_m, cur_u,
                                                             csr_m, csr_u, E_EDGES);

  // ---- layer 1, movie side ----
  // M1m = mean_{users->movie} x_user   (bufE)
  gather_mean_kernel<DU><<<NM / 4, 256, 0, stream>>>(x_user, off_m, csr_m, bufE, NM);
  // h_movie = relu(M1m@w1_rm_l + b1_rm + x_movie@w1_rm_r)   (bufC)
  sage_row_kernel<HIDDIM, true, false, true><<<NM / 32, 256, 0, stream>>>(
      bufE, w1_rm_l, DU, x_movie, w1_rm_r, DM, b1_rm, bufC, NM);

  // ---- layer 1, user side ----
  // t1 = x_movie @ w1_mu_l   (bufB)
  sage_row_kernel<HIDDIM, false, false, false><<<NM / 32, 256, 0, stream>>>(
      nullptr, nullptr, 0, x_movie, w1_mu_l, DM, nullptr, bufB, NM);
  // M1u = mean_{movies->user} t1   (bufA)
  gather_mean_kernel<HIDDIM><<<NU / 4, 256, 0, stream>>>(bufB, off_u, csr_u, bufA, NU);
  // h_user = relu(M1u + x_user@w1_mu_r + b1_mu)   (in-place bufA)
  sage_row_kernel<HIDDIM, false, true, true><<<NU / 32, 256, 0, stream>>>(
      bufA, nullptr, 0, x_user, w1_mu_r, DU, b1_mu, bufA, NU);

  // ---- layer 2, movie side ----
  // hu_l = h_user @ w2_rm_l   (bufD) -- pre-transform so the gather is 128-dim
  sage_row_kernel<OUTDIM, false, false, false><<<NU / 32, 256, 0, stream>>>(
      nullptr, nullptr, 0, bufA, w2_rm_l, HIDDIM, nullptr, bufD, NU);
  // M2m = mean_{users->movie} hu_l   (bufE)
  gather_mean_kernel<OUTDIM><<<NM / 4, 256, 0, stream>>>(bufD, off_m, csr_m, bufE, NM);
  // out_movie = M2m + h_movie@w2_rm_r + b2_rm
  sage_row_kernel<OUTDIM, false, true, false><<<NM / 32, 256, 0, stream>>>(
      bufE, nullptr, 0, bufC, w2_rm_r, HIDDIM, b2_rm, out_movie, NM);

  // ---- layer 2, user side ----
  // t2 = h_movie @ w2_mu_l   (bufB)
  sage_row_kernel<OUTDIM, false, false, false><<<NM / 32, 256, 0, stream>>>(
      nullptr, nullptr, 0, bufC, w2_mu_l, HIDDIM, nullptr, bufB, NM);
  // M2u = mean_{movies->user} t2   (bufD)
  gather_mean_kernel<OUTDIM><<<NU / 4, 256, 0, stream>>>(bufB, off_u, csr_u, bufD, NU);
  // out_user = M2u + h_user@w2_mu_r + b2_mu
  sage_row_kernel<OUTDIM, false, true, false><<<NU / 32, 256, 0, stream>>>(
      bufD, nullptr, 0, bufA, w2_mu_r, HIDDIM, b2_mu, out_user, NU);
}

// Round 4
// 1014.392 us; speedup vs baseline: 10.6257x; 1.4222x over previous
//
#include <hip/hip_runtime.h>
#include <cstddef>
#include <cstdint>

#define E_EDGES 1000000
#define NU 100000
#define NM 20000
#define DU 128
#define DM 404      // D_MOVIE (NOT 532 — R2 bug)
#define HIDDIM 256
#define OUTDIM 128
#define XMW 544     // concat row width: 128 + 404 + 12 pad  (17*32)
#define K_MU 416    // x_movie K padded: 404 + 12            (13*32)

typedef short bf8_t __attribute__((ext_vector_type(8)));   // 8 bf16 (4 VGPR) MFMA A/B frag
typedef float f32x4 __attribute__((ext_vector_type(4)));   // MFMA C/D frag

__device__ __forceinline__ float b2f(unsigned short u) {
  union { unsigned int i; float f; } x; x.i = ((unsigned int)u) << 16; return x.f;
}
__device__ __forceinline__ unsigned short f2b(float f) {
  union { float f; unsigned int i; } x; x.f = f;
  unsigned int r = x.i + 0x7FFFu + ((x.i >> 16) & 1u);  // RTNE
  return (unsigned short)(r >> 16);
}

#define GLOAD_LDS16(gp, lp)                                                      \
  __builtin_amdgcn_global_load_lds(                                              \
      (const __attribute__((address_space(1))) unsigned int*)(gp),               \
      (__attribute__((address_space(3))) unsigned int*)(lp), 16, 0, 0)

// ---------------- degree histogram ----------------
__global__ __launch_bounds__(256) void hist_kernel(const int* __restrict__ esrc,
                                                   const int* __restrict__ edst,
                                                   int* __restrict__ deg_u,
                                                   int* __restrict__ deg_m, int E) {
  int e = blockIdx.x * 256 + threadIdx.x;
  if (e < E) {
    atomicAdd(&deg_u[esrc[e]], 1);
    atomicAdd(&deg_m[edst[e]], 1);
  }
}

// ---------------- exclusive scan (single workgroup) ----------------
__global__ __launch_bounds__(1024) void scan_kernel(const int* __restrict__ deg,
                                                    int* __restrict__ off, int n) {
  const int tid = threadIdx.x;
  const int lane = tid & 63;
  const int w = tid >> 6;  // 16 waves
  __shared__ int wsum[16];
  int carry = 0;
  for (int base = 0; base < n; base += 1024) {
    const int i = base + tid;
    const int v = (i < n) ? deg[i] : 0;
    int s = v;
#pragma unroll
    for (int d = 1; d < 64; d <<= 1) {
      int t = __shfl_up(s, d, 64);
      if (lane >= d) s += t;
    }
    if (lane == 63) wsum[w] = s;
    __syncthreads();
    int woff = 0, ctot = 0;
#pragma unroll
    for (int j = 0; j < 16; ++j) {
      int x = wsum[j];
      if (j < w) woff += x;
      ctot += x;
    }
    if (i < n) off[i] = carry + woff + s - v;
    carry += ctot;
    __syncthreads();
  }
  if (tid == 0) off[n] = carry;
}

__global__ __launch_bounds__(256) void copy_int_kernel(const int* __restrict__ a,
                                                       int* __restrict__ b, int n) {
  int i = blockIdx.x * 256 + threadIdx.x;
  if (i < n) b[i] = a[i];
}

__global__ __launch_bounds__(256) void csr_fill_kernel(const int* __restrict__ esrc,
                                                       const int* __restrict__ edst,
                                                       int* __restrict__ cur_m,
                                                       int* __restrict__ cur_u,
                                                       int* __restrict__ csr_m,
                                                       int* __restrict__ csr_u, int E) {
  int e = blockIdx.x * 256 + threadIdx.x;
  if (e >= E) return;
  const int s = esrc[e], d = edst[e];
  const int pm = atomicAdd(&cur_m[d], 1);
  csr_m[pm] = s;
  const int pu = atomicAdd(&cur_u[s], 1);
  csr_u[pu] = d;
}

// ---------------- conversions ----------------
__global__ __launch_bounds__(256) void conv_bf16_kernel(const float* __restrict__ in,
                                                        unsigned short* __restrict__ out,
                                                        int n4) {
  int i = blockIdx.x * 256 + threadIdx.x;
  if (i >= n4) return;
  float4 v = reinterpret_cast<const float4*>(in)[i];
  ushort4 o;
  o.x = f2b(v.x); o.y = f2b(v.y); o.z = f2b(v.z); o.w = f2b(v.w);
  reinterpret_cast<ushort4*>(out)[i] = o;
}

// write x_movie (20000x404 f32) into xmcat cols [128,532) bf16, zero cols [532,544)
__global__ __launch_bounds__(256) void conv_xmcat_kernel(const float* __restrict__ xm,
                                                         unsigned short* __restrict__ dst) {
  int i = blockIdx.x * 256 + threadIdx.x;
  if (i >= NM * (K_MU / 4)) return;
  int row = i / (K_MU / 4), c4 = (i % (K_MU / 4)) * 4;  // c4 in [0,416)
  ushort4 o;
  if (c4 < DM) {  // DM=404 is a multiple of 4
    float4 v = *reinterpret_cast<const float4*>(&xm[(size_t)row * DM + c4]);
    o.x = f2b(v.x); o.y = f2b(v.y); o.z = f2b(v.z); o.w = f2b(v.w);
  } else {
    o.x = o.y = o.z = o.w = 0;
  }
  *reinterpret_cast<ushort4*>(&dst[(size_t)row * XMW + 128 + c4]) = o;
}

// W [KxN] f32 -> Wt [N x ldwt] bf16 (transposed, K-padded with zeros)
__global__ __launch_bounds__(256) void wt_kernel(const float* __restrict__ W,
                                                 unsigned short* __restrict__ Wt,
                                                 int K, int N, int ldwt) {
  int i = blockIdx.x * 256 + threadIdx.x;
  if (i >= N * ldwt) return;
  int n = i / ldwt, k = i % ldwt;
  Wt[i] = (k < K) ? f2b(W[(size_t)k * N + n]) : (unsigned short)0;
}

// [W1; W2] concat along K -> Wt [N x ldwt] bf16, zero-padded past K1+K2
__global__ __launch_bounds__(256) void wtcat_kernel(const float* __restrict__ W1,
                                                    const float* __restrict__ W2,
                                                    unsigned short* __restrict__ Wt,
                                                    int K1, int K2, int N, int ldwt) {
  int i = blockIdx.x * 256 + threadIdx.x;
  if (i >= N * ldwt) return;
  int n = i / ldwt, k = i % ldwt;
  unsigned short v = 0;
  if (k < K1) v = f2b(W1[(size_t)k * N + n]);
  else if (k < K1 + K2) v = f2b(W2[(size_t)(k - K1) * N + n]);
  Wt[i] = v;
}

// ---------------- gather-mean (bf16 in, bf16 out, f32 accum) ----------------
template <int D>
__global__ __launch_bounds__(256) void gather_mean_kernel(const unsigned short* __restrict__ table,
                                                          const int* __restrict__ off,
                                                          const int* __restrict__ idx,
                                                          unsigned short* __restrict__ out,
                                                          int n, int ostride) {
  const int w = threadIdx.x >> 6;
  const int l = threadIdx.x & 63;
  const int node = blockIdx.x * 4 + w;
  if (node >= n) return;
  const int beg = off[node], end = off[node + 1];
  const float sc = 1.0f / fmaxf((float)(end - beg), 1.0f);
  if constexpr (D == 256) {
    const int c = l * 4;
    float a0 = 0.f, a1 = 0.f, a2 = 0.f, a3 = 0.f;
    for (int p = beg; p < end; ++p) {
      const int r = idx[p];
      ushort4 v = *reinterpret_cast<const ushort4*>(&table[(size_t)r * 256 + c]);
      a0 += b2f(v.x); a1 += b2f(v.y); a2 += b2f(v.z); a3 += b2f(v.w);
    }
    ushort4 o;
    o.x = f2b(a0 * sc); o.y = f2b(a1 * sc); o.z = f2b(a2 * sc); o.w = f2b(a3 * sc);
    *reinterpret_cast<ushort4*>(&out[(size_t)node * ostride + c]) = o;
  } else {
    const int c = l * 2;
    float a0 = 0.f, a1 = 0.f;
    for (int p = beg; p < end; ++p) {
      const int r = idx[p];
      ushort2 v = *reinterpret_cast<const ushort2*>(&table[(size_t)r * 128 + c]);
      a0 += b2f(v.x); a1 += b2f(v.y);
    }
    ushort2 o;
    o.x = f2b(a0 * sc); o.y = f2b(a1 * sc);
    *reinterpret_cast<ushort2*>(&out[(size_t)node * ostride + c]) = o;
  }
}

// ---------------- bf16 MFMA GEMM: out = op(A @ Bt^T + [elem] + [bias]) ----------------
// A: [M x lda] bf16 (uses cols 0..K); Bt: [Ntot x ldb] bf16 = W^T; K % 32 == 0.
// Tile 128x128, 4 waves each owning a 64x64 quadrant (4x4 of 16x16 mfma tiles).
template <bool ELEM, bool BIAS, bool RELU, bool OUTF32>
__global__ __launch_bounds__(256) void gemm_bf16_kernel(
    const unsigned short* __restrict__ A, int lda,
    const unsigned short* __restrict__ Bt, int ldb, int K,
    const unsigned short* __restrict__ elem, const float* __restrict__ bias,
    void* __restrict__ outv, int M, int Nt) {
  const int tid = threadIdx.x;
  const int w = tid >> 6, l = tid & 63;
  const int row0 = blockIdx.x * 128;
  const int col0 = blockIdx.y * 128;
  const int wr = w >> 1, wc = w & 1;

  __shared__ unsigned short Alds[128 * 32];
  __shared__ unsigned short Blds[128 * 32];

  f32x4 acc[4][4] = {};

  // staging addresses: 2 instrs x (16 rows, 4 lanes/row, 16B each)
  int ar0 = row0 + w * 32 + (l >> 2);
  int ar1 = ar0 + 16;
  if (ar0 >= M) ar0 = M - 1;
  if (ar1 >= M) ar1 = M - 1;
  const size_t aoff0 = (size_t)ar0 * lda + (l & 3) * 8;
  const size_t aoff1 = (size_t)ar1 * lda + (l & 3) * 8;
  const int nr0 = col0 + w * 32 + (l >> 2);
  const size_t boff0 = (size_t)nr0 * ldb + (l & 3) * 8;
  const size_t boff1 = (size_t)(nr0 + 16) * ldb + (l & 3) * 8;
  unsigned short* aldsb = &Alds[w * 1024];
  unsigned short* bldsb = &Blds[w * 1024];

  for (int k0 = 0; k0 < K; k0 += 32) {
    GLOAD_LDS16(A + aoff0 + k0, aldsb);
    GLOAD_LDS16(A + aoff1 + k0, aldsb + 512);
    GLOAD_LDS16(Bt + boff0 + k0, bldsb);
    GLOAD_LDS16(Bt + boff1 + k0, bldsb + 512);
    __syncthreads();
    bf8_t af[4], bfr[4];
#pragma unroll
    for (int mi = 0; mi < 4; ++mi)
      af[mi] = *reinterpret_cast<const bf8_t*>(&Alds[(wr * 64 + mi * 16 + (l & 15)) * 32 + (l >> 4) * 8]);
#pragma unroll
    for (int nj = 0; nj < 4; ++nj)
      bfr[nj] = *reinterpret_cast<const bf8_t*>(&Blds[(wc * 64 + nj * 16 + (l & 15)) * 32 + (l >> 4) * 8]);
#pragma unroll
    for (int mi = 0; mi < 4; ++mi)
#pragma unroll
      for (int nj = 0; nj < 4; ++nj)
        acc[mi][nj] = __builtin_amdgcn_mfma_f32_16x16x32_bf16(af[mi], bfr[nj], acc[mi][nj], 0, 0, 0);
    __syncthreads();
  }

  // epilogue: C[row0 + wr*64 + mi*16 + (l>>4)*4 + r][col0 + wc*64 + nj*16 + (l&15)]
#pragma unroll
  for (int mi = 0; mi < 4; ++mi) {
    const int rbase = row0 + wr * 64 + mi * 16 + ((l >> 4) << 2);
#pragma unroll
    for (int nj = 0; nj < 4; ++nj) {
      const int col = col0 + wc * 64 + nj * 16 + (l & 15);
      float bb = 0.0f;
      if constexpr (BIAS) bb = bias[col];
#pragma unroll
      for (int r = 0; r < 4; ++r) {
        const int row = rbase + r;
        if (row >= M) continue;
        float v = acc[mi][nj][r] + bb;
        if constexpr (ELEM) v += b2f(elem[(size_t)row * Nt + col]);
        if constexpr (RELU) v = fmaxf(v, 0.0f);
        if constexpr (OUTF32)
          reinterpret_cast<float*>(outv)[(size_t)row * Nt + col] = v;
        else
          reinterpret_cast<unsigned short*>(outv)[(size_t)row * Nt + col] = f2b(v);
      }
    }
  }
}

extern "C" void kernel_launch(void* const* d_in, const int* in_sizes, int n_in,
                              void* d_out, int out_size, void* d_ws, size_t ws_size,
                              hipStream_t stream) {
  const float* x_user  = (const float*)d_in[0];
  const float* x_movie = (const float*)d_in[1];
  const int*   esrc    = (const int*)d_in[2];
  const int*   edst    = (const int*)d_in[3];
  const float* w1_rm_l = (const float*)d_in[4];
  const float* b1_rm   = (const float*)d_in[5];
  const float* w1_rm_r = (const float*)d_in[6];
  const float* w1_mu_l = (const float*)d_in[7];
  const float* b1_mu   = (const float*)d_in[8];
  const float* w1_mu_r = (const float*)d_in[9];
  const float* w2_rm_l = (const float*)d_in[10];
  const float* b2_rm   = (const float*)d_in[11];
  const float* w2_rm_r = (const float*)d_in[12];
  const float* w2_mu_l = (const float*)d_in[13];
  const float* b2_mu   = (const float*)d_in[14];
  const float* w2_mu_r = (const float*)d_in[15];

  if (ws_size < 214240008ull) return;
  char* wsb = (char*)d_ws;
  unsigned short* xu_bf  = (unsigned short*)(wsb + 0);           // 100000x128
  unsigned short* xmcat  = (unsigned short*)(wsb + 25600000);    // 20000x544: [M1m | x_movie | 0pad]
  unsigned short* hm_bf  = (unsigned short*)(wsb + 47360000);    // 20000x256
  unsigned short* t1_bf  = (unsigned short*)(wsb + 57600000);    // 20000x256
  unsigned short* t2_bf  = (unsigned short*)(wsb + 57600000);    // 20000x128 (t1 dead)
  unsigned short* M2m_bf = (unsigned short*)(wsb + 67840000);    // 20000x128
  unsigned short* M1u_bf = (unsigned short*)(wsb + 72960000);    // 100000x256
  unsigned short* hul_bf = (unsigned short*)(wsb + 72960000);    // 100000x128 (M1u dead)
  unsigned short* M2u_bf = (unsigned short*)(wsb + 124160000);   // 100000x128
  unsigned short* hu_bf  = (unsigned short*)(wsb + 149760000);   // 100000x256
  unsigned short* wts    = (unsigned short*)(wsb + 200960000);
  unsigned short* wcat1_t = wts;            // 256x544
  unsigned short* w1mul_t = wts + 139264;   // 256x416
  unsigned short* w1mur_t = wts + 245760;   // 256x128
  unsigned short* w2rml_t = wts + 278528;   // 128x256
  unsigned short* w2rmr_t = wts + 311296;   // 128x256
  unsigned short* w2mul_t = wts + 344064;   // 128x256
  unsigned short* w2mur_t = wts + 376832;   // 128x256
  int* iw    = (int*)(wsb + 201779200);
  int* deg_m = iw;
  int* off_m = iw + 20000;
  int* cur_m = iw + 40001;
  int* deg_u = iw + 60001;
  int* off_u = iw + 160001;
  int* cur_u = iw + 260002;
  int* csr_m = iw + 360002;
  int* csr_u = iw + 1360002;

  float* out_movie = (float*)d_out;
  float* out_user  = (float*)d_out + (size_t)NM * OUTDIM;

  // ---- CSR build ----
  hipMemsetAsync(deg_m, 0, NM * sizeof(int), stream);
  hipMemsetAsync(deg_u, 0, NU * sizeof(int), stream);
  hist_kernel<<<(E_EDGES + 255) / 256, 256, 0, stream>>>(esrc, edst, deg_u, deg_m, E_EDGES);
  scan_kernel<<<1, 1024, 0, stream>>>(deg_m, off_m, NM);
  scan_kernel<<<1, 1024, 0, stream>>>(deg_u, off_u, NU);
  copy_int_kernel<<<(NM + 255) / 256, 256, 0, stream>>>(off_m, cur_m, NM);
  copy_int_kernel<<<(NU + 255) / 256, 256, 0, stream>>>(off_u, cur_u, NU);
  csr_fill_kernel<<<(E_EDGES + 255) / 256, 256, 0, stream>>>(esrc, edst, cur_m, cur_u,
                                                             csr_m, csr_u, E_EDGES);

  // ---- conversions ----
  conv_bf16_kernel<<<(NU * DU / 4 + 255) / 256, 256, 0, stream>>>(x_user, xu_bf, NU * DU / 4);
  conv_xmcat_kernel<<<(NM * (K_MU / 4) + 255) / 256, 256, 0, stream>>>(x_movie, xmcat);
  wtcat_kernel<<<(256 * XMW + 255) / 256, 256, 0, stream>>>(w1_rm_l, w1_rm_r, wcat1_t, DU, DM, 256, XMW);
  wt_kernel<<<(256 * K_MU + 255) / 256, 256, 0, stream>>>(w1_mu_l, w1mul_t, DM, 256, K_MU);
  wt_kernel<<<(256 * 128 + 255) / 256, 256, 0, stream>>>(w1_mu_r, w1mur_t, 128, 256, 128);
  wt_kernel<<<(128 * 256 + 255) / 256, 256, 0, stream>>>(w2_rm_l, w2rml_t, 256, 128, 256);
  wt_kernel<<<(128 * 256 + 255) / 256, 256, 0, stream>>>(w2_rm_r, w2rmr_t, 256, 128, 256);
  wt_kernel<<<(128 * 256 + 255) / 256, 256, 0, stream>>>(w2_mu_l, w2mul_t, 256, 128, 256);
  wt_kernel<<<(128 * 256 + 255) / 256, 256, 0, stream>>>(w2_mu_r, w2mur_t, 256, 128, 256);

  // ---- layer 1 ----
  // M1m (cols 0:128 of xmcat) = mean over csr_m of xu_bf
  gather_mean_kernel<128><<<NM / 4, 256, 0, stream>>>(xu_bf, off_m, csr_m, xmcat, NM, XMW);
  // h_movie = relu(xmcat @ wcat1 + b1_rm)
  gemm_bf16_kernel<false, true, true, false><<<dim3(157, 2), 256, 0, stream>>>(
      xmcat, XMW, wcat1_t, XMW, XMW, nullptr, b1_rm, hm_bf, NM, HIDDIM);
  // t1 = x_movie @ w1_mu_l  (view of xmcat cols 128.., K padded to 416)
  gemm_bf16_kernel<false, false, false, false><<<dim3(157, 2), 256, 0, stream>>>(
      xmcat + 128, XMW, w1mul_t, K_MU, K_MU, nullptr, nullptr, t1_bf, NM, HIDDIM);
  // M1u = mean over csr_u of t1
  gather_mean_kernel<256><<<NU / 4, 256, 0, stream>>>(t1_bf, off_u, csr_u, M1u_bf, NU, 256);
  // h_user = relu(x_user @ w1_mu_r + M1u + b1_mu)
  gemm_bf16_kernel<true, true, true, false><<<dim3(782, 2), 256, 0, stream>>>(
      xu_bf, 128, w1mur_t, 128, 128, M1u_bf, b1_mu, hu_bf, NU, HIDDIM);

  // ---- layer 2 ----
  // hul = h_user @ w2_rm_l
  gemm_bf16_kernel<false, false, false, false><<<dim3(782, 1), 256, 0, stream>>>(
      hu_bf, 256, w2rml_t, 256, 256, nullptr, nullptr, hul_bf, NU, OUTDIM);
  // M2m = mean over csr_m of hul
  gather_mean_kernel<128><<<NM / 4, 256, 0, stream>>>(hul_bf, off_m, csr_m, M2m_bf, NM, 128);
  // out_movie = h_movie @ w2_rm_r + M2m + b2_rm   (f32 out)
  gemm_bf16_kernel<true, true, false, true><<<dim3(157, 1), 256, 0, stream>>>(
      hm_bf, 256, w2rmr_t, 256, 256, M2m_bf, b2_rm, out_movie, NM, OUTDIM);
  // t2 = h_movie @ w2_mu_l
  gemm_bf16_kernel<false, false, false, false><<<dim3(157, 1), 256, 0, stream>>>(
      hm_bf, 256, w2mul_t, 256, 256, nullptr, nullptr, t2_bf, NM, OUTDIM);
  // M2u = mean over csr_u of t2
  gather_mean_kernel<128><<<NU / 4, 256, 0, stream>>>(t2_bf, off_u, csr_u, M2u_bf, NU, 128);
  // out_user = h_user @ w2_mu_r + M2u + b2_mu   (f32 out)
  gemm_bf16_kernel<true, true, false, true><<<dim3(782, 1), 256, 0, stream>>>(
      hu_bf, 256, w2mur_t, 256, 256, M2u_bf, b2_mu, out_user, NU, OUTDIM);
}

// Round 5
// 588.980 us; speedup vs baseline: 18.3005x; 1.7223x over previous
//
#include <hip/hip_runtime.h>
#include <cstddef>
#include <cstdint>

#define E_EDGES 1000000
#define NU 100000
#define NM 20000
#define DU 128
#define DM 404      // D_MOVIE
#define HIDDIM 256
#define OUTDIM 128
#define XMW 544     // concat row width: 128 + 404 + 12 pad  (17*32)

typedef short bf8_t __attribute__((ext_vector_type(8)));   // 8 bf16 (4 VGPR) MFMA A/B frag
typedef float f32x4 __attribute__((ext_vector_type(4)));   // MFMA C/D frag

__device__ __forceinline__ float b2f(unsigned short u) {
  union { unsigned int i; float f; } x; x.i = ((unsigned int)u) << 16; return x.f;
}
__device__ __forceinline__ unsigned short f2b(float f) {
  union { float f; unsigned int i; } x; x.f = f;
  unsigned int r = x.i + 0x7FFFu + ((x.i >> 16) & 1u);  // RTNE
  return (unsigned short)(r >> 16);
}

#define GLOAD_LDS16(gp, lp)                                                      \
  __builtin_amdgcn_global_load_lds(                                              \
      (const __attribute__((address_space(1))) unsigned int*)(gp),               \
      (__attribute__((address_space(3))) unsigned int*)(lp), 16, 0, 0)

// ---------------- degree histogram + per-edge rank ----------------
__global__ __launch_bounds__(256) void hist_kernel(const int* __restrict__ esrc,
                                                   const int* __restrict__ edst,
                                                   int* __restrict__ deg_u,
                                                   int* __restrict__ deg_m,
                                                   int* __restrict__ rank_u,
                                                   int* __restrict__ rank_m, int E) {
  int e = blockIdx.x * 256 + threadIdx.x;
  if (e < E) {
    rank_u[e] = atomicAdd(&deg_u[esrc[e]], 1);
    rank_m[e] = atomicAdd(&deg_m[edst[e]], 1);
  }
}

// ---------------- exclusive scans (block 0: movies, block 1: users) ----------------
__global__ __launch_bounds__(1024) void scan2_kernel(const int* __restrict__ deg_m,
                                                     int* __restrict__ off_m,
                                                     const int* __restrict__ deg_u,
                                                     int* __restrict__ off_u) {
  const int* __restrict__ deg = blockIdx.x ? deg_u : deg_m;
  int* __restrict__ off = blockIdx.x ? off_u : off_m;
  const int n = blockIdx.x ? NU : NM;
  const int tid = threadIdx.x;
  const int lane = tid & 63;
  const int w = tid >> 6;  // 16 waves
  __shared__ int wsum[16];
  int carry = 0;
  for (int base = 0; base < n; base += 16384) {
    const int i0 = base + tid * 16;
    int v[16];
    int s = 0;
    if (i0 + 16 <= n) {
#pragma unroll
      for (int q = 0; q < 4; ++q) {
        int4 t4 = *reinterpret_cast<const int4*>(&deg[i0 + q * 4]);
        v[q * 4 + 0] = t4.x; v[q * 4 + 1] = t4.y; v[q * 4 + 2] = t4.z; v[q * 4 + 3] = t4.w;
      }
    } else {
#pragma unroll
      for (int j = 0; j < 16; ++j) v[j] = (i0 + j < n) ? deg[i0 + j] : 0;
    }
#pragma unroll
    for (int j = 0; j < 16; ++j) s += v[j];
    int ws_ = s;
#pragma unroll
    for (int d = 1; d < 64; d <<= 1) {
      int t = __shfl_up(ws_, d, 64);
      if (lane >= d) ws_ += t;
    }
    if (lane == 63) wsum[w] = ws_;
    __syncthreads();
    int woff = 0, ctot = 0;
#pragma unroll
    for (int j = 0; j < 16; ++j) {
      int x = wsum[j];
      if (j < w) woff += x;
      ctot += x;
    }
    int ex = carry + woff + ws_ - s;  // exclusive prefix for this thread's chunk
    if (i0 + 16 <= n) {
      int o[16];
#pragma unroll
      for (int j = 0; j < 16; ++j) { o[j] = ex; ex += v[j]; }
#pragma unroll
      for (int q = 0; q < 4; ++q)
        *reinterpret_cast<int4*>(&off[i0 + q * 4]) =
            make_int4(o[q * 4], o[q * 4 + 1], o[q * 4 + 2], o[q * 4 + 3]);
    } else {
#pragma unroll
      for (int j = 0; j < 16; ++j) {
        if (i0 + j < n) off[i0 + j] = ex;
        ex += v[j];
      }
    }
    carry += ctot;
    __syncthreads();
  }
  if (tid == 0) off[n] = carry;
}

// ---------------- CSR fill (rank-based, no atomics) ----------------
__global__ __launch_bounds__(256) void csr_fill_kernel(const int* __restrict__ esrc,
                                                       const int* __restrict__ edst,
                                                       const int* __restrict__ rank_m,
                                                       const int* __restrict__ rank_u,
                                                       const int* __restrict__ off_m,
                                                       const int* __restrict__ off_u,
                                                       int* __restrict__ csr_m,
                                                       int* __restrict__ csr_u, int E) {
  int e = blockIdx.x * 256 + threadIdx.x;
  if (e >= E) return;
  const int s = esrc[e], d = edst[e];
  csr_m[off_m[d] + rank_m[e]] = s;
  csr_u[off_u[s] + rank_u[e]] = d;
}

// ---------------- conversions ----------------
__global__ __launch_bounds__(256) void conv_bf16_kernel(const float* __restrict__ in,
                                                        unsigned short* __restrict__ out,
                                                        int n4) {
  int i = blockIdx.x * 256 + threadIdx.x;
  if (i >= n4) return;
  float4 v = reinterpret_cast<const float4*>(in)[i];
  ushort4 o;
  o.x = f2b(v.x); o.y = f2b(v.y); o.z = f2b(v.z); o.w = f2b(v.w);
  reinterpret_cast<ushort4*>(out)[i] = o;
}

// x_movie (20000x404 f32) -> xmcat cols [128,532) bf16, zero [532,544)
__global__ __launch_bounds__(256) void conv_xmcat_kernel(const float* __restrict__ xm,
                                                         unsigned short* __restrict__ dst) {
  int i = blockIdx.x * 256 + threadIdx.x;
  if (i >= NM * 104) return;  // 416/4 = 104 float4-groups per row
  int row = i / 104, c4 = (i % 104) * 4;  // c4 in [0,416)
  ushort4 o;
  if (c4 < DM) {
    float4 v = *reinterpret_cast<const float4*>(&xm[(size_t)row * DM + c4]);
    o.x = f2b(v.x); o.y = f2b(v.y); o.z = f2b(v.z); o.w = f2b(v.w);
  } else {
    o.x = o.y = o.z = o.w = 0;
  }
  *reinterpret_cast<ushort4*>(&dst[(size_t)row * XMW + 128 + c4]) = o;
}

// ---------------- all weight transposes in one launch ----------------
// wL1  [512][544]: n<256: {k<128: w1_rm_l, k<532: w1_rm_r}; n>=256: {128<=k<532: w1_mu_l}
// w1mur[256][128]; wL2u [256][256]: n<128: w2_rm_l else w2_mu_r; w2mul [128][256]; w2rmr [128][256]
__global__ __launch_bounds__(256) void wt_all_kernel(
    const float* __restrict__ w1_rm_l, const float* __restrict__ w1_rm_r,
    const float* __restrict__ w1_mu_l, const float* __restrict__ w1_mu_r,
    const float* __restrict__ w2_rm_l, const float* __restrict__ w2_mu_r,
    const float* __restrict__ w2_mu_l, const float* __restrict__ w2_rm_r,
    unsigned short* __restrict__ wL1, unsigned short* __restrict__ w1mur,
    unsigned short* __restrict__ wL2u, unsigned short* __restrict__ w2mul,
    unsigned short* __restrict__ w2rmr) {
  int i = blockIdx.x * 256 + threadIdx.x;
  if (i < 278528) {
    int n = i / 544, k = i % 544;
    float v = 0.f;
    if (n < 256) {
      if (k < 128) v = w1_rm_l[(size_t)k * 256 + n];
      else if (k < 532) v = w1_rm_r[(size_t)(k - 128) * 256 + n];
    } else {
      if (k >= 128 && k < 532) v = w1_mu_l[(size_t)(k - 128) * 256 + (n - 256)];
    }
    wL1[i] = f2b(v);
  } else if (i < 311296) {
    int j = i - 278528; int n = j / 128, k = j % 128;
    w1mur[j] = f2b(w1_mu_r[(size_t)k * 256 + n]);
  } else if (i < 376832) {
    int j = i - 311296; int n = j / 256, k = j % 256;
    float v = (n < 128) ? w2_rm_l[(size_t)k * 128 + n] : w2_mu_r[(size_t)k * 128 + (n - 128)];
    wL2u[j] = f2b(v);
  } else if (i < 409600) {
    int j = i - 376832; int n = j / 256, k = j % 256;
    w2mul[j] = f2b(w2_mu_l[(size_t)k * 128 + n]);
  } else if (i < 442368) {
    int j = i - 409600; int n = j / 256, k = j % 256;
    w2rmr[j] = f2b(w2_rm_r[(size_t)k * 128 + n]);
  }
}

// ---------------- gather-mean (bf16 in/out, f32 accum, 2 edges in flight) ----------------
template <int D>
__global__ __launch_bounds__(256) void gather_mean_kernel(const unsigned short* __restrict__ table,
                                                          const int* __restrict__ off,
                                                          const int* __restrict__ idx,
                                                          unsigned short* __restrict__ out,
                                                          int n, int ostride) {
  const int w = threadIdx.x >> 6;
  const int l = threadIdx.x & 63;
  const int node = blockIdx.x * 4 + w;
  if (node >= n) return;
  const int beg = off[node], end = off[node + 1];
  const float sc = 1.0f / fmaxf((float)(end - beg), 1.0f);
  if constexpr (D == 256) {
    const int c = l * 4;  // 64 lanes x 8B = 512B/row
    float a0 = 0, a1 = 0, a2 = 0, a3 = 0, b0 = 0, b1 = 0, b2 = 0, b3 = 0;
    int p = beg;
    for (; p + 1 < end; p += 2) {
      const int r0 = idx[p], r1 = idx[p + 1];
      ushort4 v0 = *reinterpret_cast<const ushort4*>(&table[(size_t)r0 * 256 + c]);
      ushort4 v1 = *reinterpret_cast<const ushort4*>(&table[(size_t)r1 * 256 + c]);
      a0 += b2f(v0.x); a1 += b2f(v0.y); a2 += b2f(v0.z); a3 += b2f(v0.w);
      b0 += b2f(v1.x); b1 += b2f(v1.y); b2 += b2f(v1.z); b3 += b2f(v1.w);
    }
    if (p < end) {
      const int r0 = idx[p];
      ushort4 v0 = *reinterpret_cast<const ushort4*>(&table[(size_t)r0 * 256 + c]);
      a0 += b2f(v0.x); a1 += b2f(v0.y); a2 += b2f(v0.z); a3 += b2f(v0.w);
    }
    a0 += b0; a1 += b1; a2 += b2; a3 += b3;
    ushort4 o;
    o.x = f2b(a0 * sc); o.y = f2b(a1 * sc); o.z = f2b(a2 * sc); o.w = f2b(a3 * sc);
    *reinterpret_cast<ushort4*>(&out[(size_t)node * ostride + c]) = o;
  } else {
    const int h = l >> 5;        // edge parity within wave
    const int c = (l & 31) * 4;  // 32 lanes x 8B = 256B/row
    float a0 = 0, a1 = 0, a2 = 0, a3 = 0, b0 = 0, b1 = 0, b2 = 0, b3 = 0;
    int p = beg + h;
    for (; p + 2 < end; p += 4) {
      const int r0 = idx[p], r1 = idx[p + 2];
      ushort4 v0 = *reinterpret_cast<const ushort4*>(&table[(size_t)r0 * 128 + c]);
      ushort4 v1 = *reinterpret_cast<const ushort4*>(&table[(size_t)r1 * 128 + c]);
      a0 += b2f(v0.x); a1 += b2f(v0.y); a2 += b2f(v0.z); a3 += b2f(v0.w);
      b0 += b2f(v1.x); b1 += b2f(v1.y); b2 += b2f(v1.z); b3 += b2f(v1.w);
    }
    for (; p < end; p += 2) {
      const int r0 = idx[p];
      ushort4 v0 = *reinterpret_cast<const ushort4*>(&table[(size_t)r0 * 128 + c]);
      a0 += b2f(v0.x); a1 += b2f(v0.y); a2 += b2f(v0.z); a3 += b2f(v0.w);
    }
    a0 += b0; a1 += b1; a2 += b2; a3 += b3;
    a0 += __shfl_down(a0, 32, 64); a1 += __shfl_down(a1, 32, 64);
    a2 += __shfl_down(a2, 32, 64); a3 += __shfl_down(a3, 32, 64);
    if (h == 0) {
      ushort4 o;
      o.x = f2b(a0 * sc); o.y = f2b(a1 * sc); o.z = f2b(a2 * sc); o.w = f2b(a3 * sc);
      *reinterpret_cast<ushort4*>(&out[(size_t)node * ostride + c]) = o;
    }
  }
}

// ---------------- bf16 MFMA GEMM with fused epilogues ----------------
// Tile 128x128, 4 waves each own a 64x64 quadrant (4x4 of 16x16x32 mfma).
// MODE 0: L1 fused. cols<256 -> outA=h_movie bf16 s256, bias+relu; cols>=256 -> outB=t1 bf16 s256.
// MODE 1: h_user.  bf16 outA s256, elem(s256)+bias+relu.
// MODE 2: plain bf16 outA s128.
// MODE 3: user fused. y==0 -> outA=hul bf16 s128; y==1 -> outB=out_user f32 s128, elem(s128)+bias.
// MODE 4: f32 outA s128, elem(s128)+bias.
template <int MODE>
__global__ __launch_bounds__(256) void gemm_bf16_kernel(
    const unsigned short* __restrict__ A, int lda,
    const unsigned short* __restrict__ Bt, int ldb, int K,
    const unsigned short* __restrict__ elem, const float* __restrict__ bias,
    void* __restrict__ outA, void* __restrict__ outB, int M) {
  const int tid = threadIdx.x;
  const int w = tid >> 6, l = tid & 63;
  const int row0 = blockIdx.x * 128;
  const int col0 = blockIdx.y * 128;
  const int wr = w >> 1, wc = w & 1;

  __shared__ unsigned short Alds[128 * 32];
  __shared__ unsigned short Blds[128 * 32];

  f32x4 acc[4][4] = {};

  int ar0 = row0 + w * 32 + (l >> 2);
  int ar1 = ar0 + 16;
  if (ar0 >= M) ar0 = M - 1;
  if (ar1 >= M) ar1 = M - 1;
  const size_t aoff0 = (size_t)ar0 * lda + (l & 3) * 8;
  const size_t aoff1 = (size_t)ar1 * lda + (l & 3) * 8;
  const int nr0 = col0 + w * 32 + (l >> 2);
  const size_t boff0 = (size_t)nr0 * ldb + (l & 3) * 8;
  const size_t boff1 = (size_t)(nr0 + 16) * ldb + (l & 3) * 8;
  unsigned short* aldsb = &Alds[w * 1024];
  unsigned short* bldsb = &Blds[w * 1024];

  for (int k0 = 0; k0 < K; k0 += 32) {
    GLOAD_LDS16(A + aoff0 + k0, aldsb);
    GLOAD_LDS16(A + aoff1 + k0, aldsb + 512);
    GLOAD_LDS16(Bt + boff0 + k0, bldsb);
    GLOAD_LDS16(Bt + boff1 + k0, bldsb + 512);
    __syncthreads();
    bf8_t af[4], bfr[4];
#pragma unroll
    for (int mi = 0; mi < 4; ++mi)
      af[mi] = *reinterpret_cast<const bf8_t*>(&Alds[(wr * 64 + mi * 16 + (l & 15)) * 32 + (l >> 4) * 8]);
#pragma unroll
    for (int nj = 0; nj < 4; ++nj)
      bfr[nj] = *reinterpret_cast<const bf8_t*>(&Blds[(wc * 64 + nj * 16 + (l & 15)) * 32 + (l >> 4) * 8]);
#pragma unroll
    for (int mi = 0; mi < 4; ++mi)
#pragma unroll
      for (int nj = 0; nj < 4; ++nj)
        acc[mi][nj] = __builtin_amdgcn_mfma_f32_16x16x32_bf16(af[mi], bfr[nj], acc[mi][nj], 0, 0, 0);
    __syncthreads();
  }

  // epilogue: C[row0 + wr*64 + mi*16 + (l>>4)*4 + r][col0 + wc*64 + nj*16 + (l&15)]
#pragma unroll
  for (int mi = 0; mi < 4; ++mi) {
    const int rbase = row0 + wr * 64 + mi * 16 + ((l >> 4) << 2);
#pragma unroll
    for (int nj = 0; nj < 4; ++nj) {
      const int gcol = col0 + wc * 64 + nj * 16 + (l & 15);
      bool halfB = false;
      int col = gcol;
      if constexpr (MODE == 0) { halfB = gcol >= 256; col = halfB ? gcol - 256 : gcol; }
      if constexpr (MODE == 3) { halfB = gcol >= 128; col = halfB ? gcol - 128 : gcol; }
      float bb = 0.0f;
      if constexpr (MODE == 0) { if (!halfB) bb = bias[col]; }
      if constexpr (MODE == 1 || MODE == 4) bb = bias[col];
      if constexpr (MODE == 3) { if (halfB) bb = bias[col]; }
#pragma unroll
      for (int r = 0; r < 4; ++r) {
        const int row = rbase + r;
        if (row >= M) continue;
        float v = acc[mi][nj][r] + bb;
        if constexpr (MODE == 1) v += b2f(elem[(size_t)row * 256 + col]);
        if constexpr (MODE == 4) v += b2f(elem[(size_t)row * 128 + col]);
        if constexpr (MODE == 3) { if (halfB) v += b2f(elem[(size_t)row * 128 + col]); }
        if constexpr (MODE == 1) v = fmaxf(v, 0.0f);
        if constexpr (MODE == 0) { if (!halfB) v = fmaxf(v, 0.0f); }
        if constexpr (MODE == 0) {
          unsigned short* dst = (unsigned short*)(halfB ? outB : outA);
          dst[(size_t)row * 256 + col] = f2b(v);
        } else if constexpr (MODE == 1) {
          ((unsigned short*)outA)[(size_t)row * 256 + col] = f2b(v);
        } else if constexpr (MODE == 2) {
          ((unsigned short*)outA)[(size_t)row * 128 + col] = f2b(v);
        } else if constexpr (MODE == 3) {
          if (halfB) ((float*)outB)[(size_t)row * 128 + col] = v;
          else ((unsigned short*)outA)[(size_t)row * 128 + col] = f2b(v);
        } else {
          ((float*)outA)[(size_t)row * 128 + col] = v;
        }
      }
    }
  }
}

extern "C" void kernel_launch(void* const* d_in, const int* in_sizes, int n_in,
                              void* d_out, int out_size, void* d_ws, size_t ws_size,
                              hipStream_t stream) {
  const float* x_user  = (const float*)d_in[0];
  const float* x_movie = (const float*)d_in[1];
  const int*   esrc    = (const int*)d_in[2];
  const int*   edst    = (const int*)d_in[3];
  const float* w1_rm_l = (const float*)d_in[4];
  const float* b1_rm   = (const float*)d_in[5];
  const float* w1_rm_r = (const float*)d_in[6];
  const float* w1_mu_l = (const float*)d_in[7];
  const float* b1_mu   = (const float*)d_in[8];
  const float* w1_mu_r = (const float*)d_in[9];
  const float* w2_rm_l = (const float*)d_in[10];
  const float* b2_rm   = (const float*)d_in[11];
  const float* w2_rm_r = (const float*)d_in[12];
  const float* w2_mu_l = (const float*)d_in[13];
  const float* b2_mu   = (const float*)d_in[14];
  const float* w2_mu_r = (const float*)d_in[15];

  if (ws_size < 214240008ull) return;
  char* wsb = (char*)d_ws;
  unsigned short* xu_bf  = (unsigned short*)(wsb + 0);           // 100000x128
  unsigned short* xmcat  = (unsigned short*)(wsb + 25600000);    // 20000x544: [M1m | x_movie | 0]
  unsigned short* hm_bf  = (unsigned short*)(wsb + 47360000);    // 20000x256
  unsigned short* t1_bf  = (unsigned short*)(wsb + 57600000);    // 20000x256
  unsigned short* M2m_bf = (unsigned short*)(wsb + 57600000);    // 20000x128 (aliases t1, dead)
  unsigned short* t2_bf  = (unsigned short*)(wsb + 67840000);    // 20000x128
  unsigned short* M1u_bf = (unsigned short*)(wsb + 72960000);    // 100000x256
  unsigned short* hul_bf = (unsigned short*)(wsb + 72960000);    // 100000x128 (aliases M1u, dead)
  unsigned short* M2u_bf = (unsigned short*)(wsb + 124160000);   // 100000x128
  unsigned short* hu_bf  = (unsigned short*)(wsb + 149760000);   // 100000x256
  int* rank_m = (int*)(wsb + 149760000);                         // 1M ints (dead before hu write)
  int* rank_u = (int*)(wsb + 153760000);                         // 1M ints
  unsigned short* wts = (unsigned short*)(wsb + 200960000);
  unsigned short* wL1_t   = wts;            // 512x544
  unsigned short* w1mur_t = wts + 278528;   // 256x128
  unsigned short* wL2u_t  = wts + 311296;   // 256x256 [w2_rm_l | w2_mu_r]
  unsigned short* w2mul_t = wts + 376832;   // 128x256
  unsigned short* w2rmr_t = wts + 409600;   // 128x256
  int* iw    = (int*)(wsb + 201844736);
  int* deg_m = iw;                 // 20000
  int* deg_u = iw + 20000;         // 100000 (contiguous with deg_m for one memset)
  int* off_m = iw + 120000;        // 20001 (+pad to 140004)
  int* off_u = iw + 140004;        // 100001 (+pad to 240008)
  int* csr_m = iw + 240008;        // 1M
  int* csr_u = iw + 1240008;       // 1M

  float* out_movie = (float*)d_out;
  float* out_user  = (float*)d_out + (size_t)NM * OUTDIM;

  // ---- CSR build ----
  hipMemsetAsync(deg_m, 0, 120000 * sizeof(int), stream);  // deg_m + deg_u
  hist_kernel<<<(E_EDGES + 255) / 256, 256, 0, stream>>>(esrc, edst, deg_u, deg_m,
                                                         rank_u, rank_m, E_EDGES);
  scan2_kernel<<<2, 1024, 0, stream>>>(deg_m, off_m, deg_u, off_u);
  csr_fill_kernel<<<(E_EDGES + 255) / 256, 256, 0, stream>>>(
      esrc, edst, rank_m, rank_u, off_m, off_u, csr_m, csr_u, E_EDGES);

  // ---- conversions ----
  conv_bf16_kernel<<<(NU * DU / 4 + 255) / 256, 256, 0, stream>>>(x_user, xu_bf, NU * DU / 4);
  conv_xmcat_kernel<<<(NM * 104 + 255) / 256, 256, 0, stream>>>(x_movie, xmcat);
  wt_all_kernel<<<1728, 256, 0, stream>>>(w1_rm_l, w1_rm_r, w1_mu_l, w1_mu_r,
                                          w2_rm_l, w2_mu_r, w2_mu_l, w2_rm_r,
                                          wL1_t, w1mur_t, wL2u_t, w2mul_t, w2rmr_t);

  // ---- layer 1 ----
  // M1m -> xmcat cols [0,128)
  gather_mean_kernel<128><<<NM / 4, 256, 0, stream>>>(xu_bf, off_m, csr_m, xmcat, NM, XMW);
  // fused: h_movie = relu(xmcat@wcat1 + b1_rm); t1 = x_movie@w1_mu_l
  gemm_bf16_kernel<0><<<dim3(157, 4), 256, 0, stream>>>(
      xmcat, XMW, wL1_t, XMW, XMW, nullptr, b1_rm, hm_bf, t1_bf, NM);
  // t2 = h_movie @ w2_mu_l  (hoisted: only needs hm)
  gemm_bf16_kernel<2><<<dim3(157, 1), 256, 0, stream>>>(
      hm_bf, 256, w2mul_t, 256, 256, nullptr, nullptr, t2_bf, nullptr, NM);
  // M1u = mean over csr_u of t1
  gather_mean_kernel<256><<<NU / 4, 256, 0, stream>>>(t1_bf, off_u, csr_u, M1u_bf, NU, 256);
  // h_user = relu(x_user@w1_mu_r + M1u + b1_mu)
  gemm_bf16_kernel<1><<<dim3(782, 2), 256, 0, stream>>>(
      xu_bf, 128, w1mur_t, 128, 128, M1u_bf, b1_mu, hu_bf, nullptr, NU);

  // ---- layer 2 ----
  // M2u = mean over csr_u of t2
  gather_mean_kernel<128><<<NU / 4, 256, 0, stream>>>(t2_bf, off_u, csr_u, M2u_bf, NU, 128);
  // fused: hul = h_user@w2_rm_l ; out_user = h_user@w2_mu_r + M2u + b2_mu
  gemm_bf16_kernel<3><<<dim3(782, 2), 256, 0, stream>>>(
      hu_bf, 256, wL2u_t, 256, 256, M2u_bf, b2_mu, hul_bf, out_user, NU);
  // M2m = mean over csr_m of hul
  gather_mean_kernel<128><<<NM / 4, 256, 0, stream>>>(hul_bf, off_m, csr_m, M2m_bf, NM, 128);
  // out_movie = h_movie@w2_rm_r + M2m + b2_rm
  gemm_bf16_kernel<4><<<dim3(157, 1), 256, 0, stream>>>(
      hm_bf, 256, w2rmr_t, 256, 256, M2m_bf, b2_rm, out_movie, nullptr, NM);
}

// Round 6
// 544.738 us; speedup vs baseline: 19.7868x; 1.0812x over previous
//
#include <hip/hip_runtime.h>
#include <cstddef>
#include <cstdint>

#define E_EDGES 1000000
#define NU 100000
#define NM 20000
#define DU 128
#define DM 404      // D_MOVIE
#define HIDDIM 256
#define OUTDIM 128
#define XMW 544     // concat row width: 128 + 404 + 12 pad  (17*32)

typedef short bf8_t __attribute__((ext_vector_type(8)));   // 8 bf16 (4 VGPR) MFMA A/B frag
typedef float f32x4 __attribute__((ext_vector_type(4)));   // MFMA C/D frag
typedef unsigned short u16x8 __attribute__((ext_vector_type(8)));  // 16B bf16 vector

__device__ __forceinline__ float b2f(unsigned short u) {
  union { unsigned int i; float f; } x; x.i = ((unsigned int)u) << 16; return x.f;
}
__device__ __forceinline__ unsigned short f2b(float f) {
  union { float f; unsigned int i; } x; x.f = f;
  unsigned int r = x.i + 0x7FFFu + ((x.i >> 16) & 1u);  // RTNE
  return (unsigned short)(r >> 16);
}

#define GLOAD_LDS16(gp, lp)                                                      \
  __builtin_amdgcn_global_load_lds(                                              \
      (const __attribute__((address_space(1))) unsigned int*)(gp),               \
      (__attribute__((address_space(3))) unsigned int*)(lp), 16, 0, 0)

// ---------------- fused prep: zero degs + conversions + weight transposes ----------------
// ranges: [0,30000) zero 120000 ints (deg_m+deg_u contiguous)
//         [PR0,PR1) conv x_user -> xu_bf        (3.2M float4 groups)
//         [PR1,PR2) conv x_movie -> xmcat       (2.08M)
//         [PR2,PR3) weight transposes           (442368)
#define PR0 30000
#define PR1 3230000
#define PR2 5310000
#define PR3 5752368
__global__ __launch_bounds__(256) void prep_kernel(
    const float* __restrict__ x_user, unsigned short* __restrict__ xu_bf,
    const float* __restrict__ x_movie, unsigned short* __restrict__ xmcat,
    const float* __restrict__ w1_rm_l, const float* __restrict__ w1_rm_r,
    const float* __restrict__ w1_mu_l, const float* __restrict__ w1_mu_r,
    const float* __restrict__ w2_rm_l, const float* __restrict__ w2_mu_r,
    const float* __restrict__ w2_mu_l, const float* __restrict__ w2_rm_r,
    unsigned short* __restrict__ wL1, unsigned short* __restrict__ w1mur,
    unsigned short* __restrict__ wL2u, unsigned short* __restrict__ w2mul,
    unsigned short* __restrict__ w2rmr, int* __restrict__ degz) {
  int i = blockIdx.x * 256 + threadIdx.x;
  if (i < PR0) {
    reinterpret_cast<int4*>(degz)[i] = make_int4(0, 0, 0, 0);
  } else if (i < PR1) {
    int j = i - PR0;
    float4 v = reinterpret_cast<const float4*>(x_user)[j];
    ushort4 o;
    o.x = f2b(v.x); o.y = f2b(v.y); o.z = f2b(v.z); o.w = f2b(v.w);
    reinterpret_cast<ushort4*>(xu_bf)[j] = o;
  } else if (i < PR2) {
    int j = i - PR1;
    int row = j / 104, c4 = (j % 104) * 4;  // c4 in [0,416)
    ushort4 o;
    if (c4 < DM) {
      float4 v = *reinterpret_cast<const float4*>(&x_movie[(size_t)row * DM + c4]);
      o.x = f2b(v.x); o.y = f2b(v.y); o.z = f2b(v.z); o.w = f2b(v.w);
    } else {
      o.x = o.y = o.z = o.w = 0;
    }
    *reinterpret_cast<ushort4*>(&xmcat[(size_t)row * XMW + 128 + c4]) = o;
  } else if (i < PR3) {
    int j = i - PR2;
    if (j < 278528) {
      int n = j / 544, k = j % 544;
      float v = 0.f;
      if (n < 256) {
        if (k < 128) v = w1_rm_l[(size_t)k * 256 + n];
        else if (k < 532) v = w1_rm_r[(size_t)(k - 128) * 256 + n];
      } else {
        if (k >= 128 && k < 532) v = w1_mu_l[(size_t)(k - 128) * 256 + (n - 256)];
      }
      wL1[j] = f2b(v);
    } else if (j < 311296) {
      int q = j - 278528; int n = q / 128, k = q % 128;
      w1mur[q] = f2b(w1_mu_r[(size_t)k * 256 + n]);
    } else if (j < 376832) {
      int q = j - 311296; int n = q / 256, k = q % 256;
      float v = (n < 128) ? w2_rm_l[(size_t)k * 128 + n] : w2_mu_r[(size_t)k * 128 + (n - 128)];
      wL2u[q] = f2b(v);
    } else if (j < 409600) {
      int q = j - 376832; int n = q / 256, k = q % 256;
      w2mul[q] = f2b(w2_mu_l[(size_t)k * 128 + n]);
    } else {
      int q = j - 409600; int n = q / 256, k = q % 256;
      w2rmr[q] = f2b(w2_rm_r[(size_t)k * 128 + n]);
    }
  }
}

// ---------------- degree histogram + per-edge rank (4 edges/thread) ----------------
__global__ __launch_bounds__(256) void hist_kernel(const int* __restrict__ esrc,
                                                   const int* __restrict__ edst,
                                                   int* __restrict__ deg_u,
                                                   int* __restrict__ deg_m,
                                                   int* __restrict__ rank_u,
                                                   int* __restrict__ rank_m) {
  int e4 = blockIdx.x * 256 + threadIdx.x;
  if (e4 >= E_EDGES / 4) return;
  int4 s4 = reinterpret_cast<const int4*>(esrc)[e4];
  int4 d4 = reinterpret_cast<const int4*>(edst)[e4];
  int4 ru, rm;
  ru.x = atomicAdd(&deg_u[s4.x], 1);
  ru.y = atomicAdd(&deg_u[s4.y], 1);
  ru.z = atomicAdd(&deg_u[s4.z], 1);
  ru.w = atomicAdd(&deg_u[s4.w], 1);
  rm.x = atomicAdd(&deg_m[d4.x], 1);
  rm.y = atomicAdd(&deg_m[d4.y], 1);
  rm.z = atomicAdd(&deg_m[d4.z], 1);
  rm.w = atomicAdd(&deg_m[d4.w], 1);
  reinterpret_cast<int4*>(rank_u)[e4] = ru;
  reinterpret_cast<int4*>(rank_m)[e4] = rm;
}

// ---------------- exclusive scans (block 0: movies, block 1: users) ----------------
__global__ __launch_bounds__(1024) void scan2_kernel(const int* __restrict__ deg_m,
                                                     int* __restrict__ off_m,
                                                     const int* __restrict__ deg_u,
                                                     int* __restrict__ off_u) {
  const int* __restrict__ deg = blockIdx.x ? deg_u : deg_m;
  int* __restrict__ off = blockIdx.x ? off_u : off_m;
  const int n = blockIdx.x ? NU : NM;
  const int tid = threadIdx.x;
  const int lane = tid & 63;
  const int w = tid >> 6;  // 16 waves
  __shared__ int wsum[16];
  int carry = 0;
  for (int base = 0; base < n; base += 16384) {
    const int i0 = base + tid * 16;
    int v[16];
    int s = 0;
    if (i0 + 16 <= n) {
#pragma unroll
      for (int q = 0; q < 4; ++q) {
        int4 t4 = *reinterpret_cast<const int4*>(&deg[i0 + q * 4]);
        v[q * 4 + 0] = t4.x; v[q * 4 + 1] = t4.y; v[q * 4 + 2] = t4.z; v[q * 4 + 3] = t4.w;
      }
    } else {
#pragma unroll
      for (int j = 0; j < 16; ++j) v[j] = (i0 + j < n) ? deg[i0 + j] : 0;
    }
#pragma unroll
    for (int j = 0; j < 16; ++j) s += v[j];
    int ws_ = s;
#pragma unroll
    for (int d = 1; d < 64; d <<= 1) {
      int t = __shfl_up(ws_, d, 64);
      if (lane >= d) ws_ += t;
    }
    if (lane == 63) wsum[w] = ws_;
    __syncthreads();
    int woff = 0, ctot = 0;
#pragma unroll
    for (int j = 0; j < 16; ++j) {
      int x = wsum[j];
      if (j < w) woff += x;
      ctot += x;
    }
    int ex = carry + woff + ws_ - s;  // exclusive prefix for this thread's chunk
    if (i0 + 16 <= n) {
      int o[16];
#pragma unroll
      for (int j = 0; j < 16; ++j) { o[j] = ex; ex += v[j]; }
#pragma unroll
      for (int q = 0; q < 4; ++q)
        *reinterpret_cast<int4*>(&off[i0 + q * 4]) =
            make_int4(o[q * 4], o[q * 4 + 1], o[q * 4 + 2], o[q * 4 + 3]);
    } else {
#pragma unroll
      for (int j = 0; j < 16; ++j) {
        if (i0 + j < n) off[i0 + j] = ex;
        ex += v[j];
      }
    }
    carry += ctot;
    __syncthreads();
  }
  if (tid == 0) off[n] = carry;
}

// ---------------- CSR fill (rank-based, no atomics, 4 edges/thread) ----------------
__global__ __launch_bounds__(256) void csr_fill_kernel(const int* __restrict__ esrc,
                                                       const int* __restrict__ edst,
                                                       const int* __restrict__ rank_m,
                                                       const int* __restrict__ rank_u,
                                                       const int* __restrict__ off_m,
                                                       const int* __restrict__ off_u,
                                                       int* __restrict__ csr_m,
                                                       int* __restrict__ csr_u) {
  int e4 = blockIdx.x * 256 + threadIdx.x;
  if (e4 >= E_EDGES / 4) return;
  int4 s4 = reinterpret_cast<const int4*>(esrc)[e4];
  int4 d4 = reinterpret_cast<const int4*>(edst)[e4];
  int4 rm = reinterpret_cast<const int4*>(rank_m)[e4];
  int4 ru = reinterpret_cast<const int4*>(rank_u)[e4];
  csr_m[off_m[d4.x] + rm.x] = s4.x;
  csr_m[off_m[d4.y] + rm.y] = s4.y;
  csr_m[off_m[d4.z] + rm.z] = s4.z;
  csr_m[off_m[d4.w] + rm.w] = s4.w;
  csr_u[off_u[s4.x] + ru.x] = d4.x;
  csr_u[off_u[s4.y] + ru.y] = d4.y;
  csr_u[off_u[s4.z] + ru.z] = d4.z;
  csr_u[off_u[s4.w] + ru.w] = d4.w;
}

// ---------------- gather-mean: each D/8-lane group owns one node ----------------
// 16B/lane loads; no cross-lane reduction; 2 edges in flight per group.
template <int D>
__global__ __launch_bounds__(256) void gather_mean_kernel(
    const unsigned short* __restrict__ table, const int* __restrict__ off,
    const int* __restrict__ idx, unsigned short* __restrict__ out, int n, int ostride) {
  constexpr int LPN = D / 8;       // lanes per node: 32 (D=256) / 16 (D=128)
  constexpr int NPB = 256 / LPN;   // nodes per block: 8 / 16
  const int t = threadIdx.x;
  const int g = t / LPN;
  const int cl = (t % LPN) * 8;
  const int node = blockIdx.x * NPB + g;
  if (node >= n) return;
  const int beg = off[node], end = off[node + 1];
  const float sc = 1.0f / fmaxf((float)(end - beg), 1.0f);
  float a[8] = {0, 0, 0, 0, 0, 0, 0, 0}, b[8] = {0, 0, 0, 0, 0, 0, 0, 0};
  int p = beg;
  for (; p + 1 < end; p += 2) {
    const int r0 = idx[p], r1 = idx[p + 1];
    u16x8 v0 = *reinterpret_cast<const u16x8*>(&table[(size_t)r0 * D + cl]);
    u16x8 v1 = *reinterpret_cast<const u16x8*>(&table[(size_t)r1 * D + cl]);
#pragma unroll
    for (int j = 0; j < 8; ++j) { a[j] += b2f(v0[j]); b[j] += b2f(v1[j]); }
  }
  if (p < end) {
    const int r0 = idx[p];
    u16x8 v0 = *reinterpret_cast<const u16x8*>(&table[(size_t)r0 * D + cl]);
#pragma unroll
    for (int j = 0; j < 8; ++j) a[j] += b2f(v0[j]);
  }
  u16x8 o;
#pragma unroll
  for (int j = 0; j < 8; ++j) o[j] = f2b((a[j] + b[j]) * sc);
  *reinterpret_cast<u16x8*>(&out[(size_t)node * ostride + cl]) = o;
}

// ---------------- bf16 MFMA GEMM with fused epilogues ----------------
// Tile 128x128, 4 waves each own a 64x64 quadrant (4x4 of 16x16x32 mfma).
// MODE 0: L1 fused. cols<256 -> outA=h_movie bf16 s256, bias+relu; cols>=256 -> outB=t1 bf16 s256.
// MODE 1: h_user.  bf16 outA s256, elem(s256)+bias+relu.
// MODE 2: plain bf16 outA s128.
// MODE 3: user fused. y==0 -> outA=hul bf16 s128; y==1 -> outB=out_user f32 s128, elem(s128)+bias.
// MODE 4: f32 outA s128, elem(s128)+bias.
template <int MODE>
__global__ __launch_bounds__(256) void gemm_bf16_kernel(
    const unsigned short* __restrict__ A, int lda,
    const unsigned short* __restrict__ Bt, int ldb, int K,
    const unsigned short* __restrict__ elem, const float* __restrict__ bias,
    void* __restrict__ outA, void* __restrict__ outB, int M) {
  const int tid = threadIdx.x;
  const int w = tid >> 6, l = tid & 63;
  const int row0 = blockIdx.x * 128;
  const int col0 = blockIdx.y * 128;
  const int wr = w >> 1, wc = w & 1;

  __shared__ unsigned short Alds[128 * 32];
  __shared__ unsigned short Blds[128 * 32];

  f32x4 acc[4][4] = {};

  int ar0 = row0 + w * 32 + (l >> 2);
  int ar1 = ar0 + 16;
  if (ar0 >= M) ar0 = M - 1;
  if (ar1 >= M) ar1 = M - 1;
  const size_t aoff0 = (size_t)ar0 * lda + (l & 3) * 8;
  const size_t aoff1 = (size_t)ar1 * lda + (l & 3) * 8;
  const int nr0 = col0 + w * 32 + (l >> 2);
  const size_t boff0 = (size_t)nr0 * ldb + (l & 3) * 8;
  const size_t boff1 = (size_t)(nr0 + 16) * ldb + (l & 3) * 8;
  unsigned short* aldsb = &Alds[w * 1024];
  unsigned short* bldsb = &Blds[w * 1024];

  for (int k0 = 0; k0 < K; k0 += 32) {
    GLOAD_LDS16(A + aoff0 + k0, aldsb);
    GLOAD_LDS16(A + aoff1 + k0, aldsb + 512);
    GLOAD_LDS16(Bt + boff0 + k0, bldsb);
    GLOAD_LDS16(Bt + boff1 + k0, bldsb + 512);
    __syncthreads();
    bf8_t af[4], bfr[4];
#pragma unroll
    for (int mi = 0; mi < 4; ++mi)
      af[mi] = *reinterpret_cast<const bf8_t*>(&Alds[(wr * 64 + mi * 16 + (l & 15)) * 32 + (l >> 4) * 8]);
#pragma unroll
    for (int nj = 0; nj < 4; ++nj)
      bfr[nj] = *reinterpret_cast<const bf8_t*>(&Blds[(wc * 64 + nj * 16 + (l & 15)) * 32 + (l >> 4) * 8]);
#pragma unroll
    for (int mi = 0; mi < 4; ++mi)
#pragma unroll
      for (int nj = 0; nj < 4; ++nj)
        acc[mi][nj] = __builtin_amdgcn_mfma_f32_16x16x32_bf16(af[mi], bfr[nj], acc[mi][nj], 0, 0, 0);
    __syncthreads();
  }

  // epilogue: C[row0 + wr*64 + mi*16 + (l>>4)*4 + r][col0 + wc*64 + nj*16 + (l&15)]
#pragma unroll
  for (int mi = 0; mi < 4; ++mi) {
    const int rbase = row0 + wr * 64 + mi * 16 + ((l >> 4) << 2);
#pragma unroll
    for (int nj = 0; nj < 4; ++nj) {
      const int gcol = col0 + wc * 64 + nj * 16 + (l & 15);
      bool halfB = false;
      int col = gcol;
      if constexpr (MODE == 0) { halfB = gcol >= 256; col = halfB ? gcol - 256 : gcol; }
      if constexpr (MODE == 3) { halfB = gcol >= 128; col = halfB ? gcol - 128 : gcol; }
      float bb = 0.0f;
      if constexpr (MODE == 0) { if (!halfB) bb = bias[col]; }
      if constexpr (MODE == 1 || MODE == 4) bb = bias[col];
      if constexpr (MODE == 3) { if (halfB) bb = bias[col]; }
#pragma unroll
      for (int r = 0; r < 4; ++r) {
        const int row = rbase + r;
        if (row >= M) continue;
        float v = acc[mi][nj][r] + bb;
        if constexpr (MODE == 1) v += b2f(elem[(size_t)row * 256 + col]);
        if constexpr (MODE == 4) v += b2f(elem[(size_t)row * 128 + col]);
        if constexpr (MODE == 3) { if (halfB) v += b2f(elem[(size_t)row * 128 + col]); }
        if constexpr (MODE == 1) v = fmaxf(v, 0.0f);
        if constexpr (MODE == 0) { if (!halfB) v = fmaxf(v, 0.0f); }
        if constexpr (MODE == 0) {
          unsigned short* dst = (unsigned short*)(halfB ? outB : outA);
          dst[(size_t)row * 256 + col] = f2b(v);
        } else if constexpr (MODE == 1) {
          ((unsigned short*)outA)[(size_t)row * 256 + col] = f2b(v);
        } else if constexpr (MODE == 2) {
          ((unsigned short*)outA)[(size_t)row * 128 + col] = f2b(v);
        } else if constexpr (MODE == 3) {
          if (halfB) ((float*)outB)[(size_t)row * 128 + col] = v;
          else ((unsigned short*)outA)[(size_t)row * 128 + col] = f2b(v);
        } else {
          ((float*)outA)[(size_t)row * 128 + col] = v;
        }
      }
    }
  }
}

extern "C" void kernel_launch(void* const* d_in, const int* in_sizes, int n_in,
                              void* d_out, int out_size, void* d_ws, size_t ws_size,
                              hipStream_t stream) {
  const float* x_user  = (const float*)d_in[0];
  const float* x_movie = (const float*)d_in[1];
  const int*   esrc    = (const int*)d_in[2];
  const int*   edst    = (const int*)d_in[3];
  const float* w1_rm_l = (const float*)d_in[4];
  const float* b1_rm   = (const float*)d_in[5];
  const float* w1_rm_r = (const float*)d_in[6];
  const float* w1_mu_l = (const float*)d_in[7];
  const float* b1_mu   = (const float*)d_in[8];
  const float* w1_mu_r = (const float*)d_in[9];
  const float* w2_rm_l = (const float*)d_in[10];
  const float* b2_rm   = (const float*)d_in[11];
  const float* w2_rm_r = (const float*)d_in[12];
  const float* w2_mu_l = (const float*)d_in[13];
  const float* b2_mu   = (const float*)d_in[14];
  const float* w2_mu_r = (const float*)d_in[15];

  if (ws_size < 214240008ull) return;
  char* wsb = (char*)d_ws;
  unsigned short* xu_bf  = (unsigned short*)(wsb + 0);           // 100000x128
  unsigned short* xmcat  = (unsigned short*)(wsb + 25600000);    // 20000x544: [M1m | x_movie | 0]
  unsigned short* hm_bf  = (unsigned short*)(wsb + 47360000);    // 20000x256
  unsigned short* t1_bf  = (unsigned short*)(wsb + 57600000);    // 20000x256
  unsigned short* M2m_bf = (unsigned short*)(wsb + 57600000);    // 20000x128 (aliases t1, dead)
  unsigned short* t2_bf  = (unsigned short*)(wsb + 67840000);    // 20000x128
  unsigned short* M1u_bf = (unsigned short*)(wsb + 72960000);    // 100000x256
  unsigned short* hul_bf = (unsigned short*)(wsb + 72960000);    // 100000x128 (aliases M1u, dead)
  unsigned short* M2u_bf = (unsigned short*)(wsb + 124160000);   // 100000x128
  unsigned short* hu_bf  = (unsigned short*)(wsb + 149760000);   // 100000x256
  int* rank_m = (int*)(wsb + 149760000);                         // 1M ints (dead before hu write)
  int* rank_u = (int*)(wsb + 153760000);                         // 1M ints
  unsigned short* wts = (unsigned short*)(wsb + 200960000);
  unsigned short* wL1_t   = wts;            // 512x544
  unsigned short* w1mur_t = wts + 278528;   // 256x128
  unsigned short* wL2u_t  = wts + 311296;   // 256x256 [w2_rm_l | w2_mu_r]
  unsigned short* w2mul_t = wts + 376832;   // 128x256
  unsigned short* w2rmr_t = wts + 409600;   // 128x256
  int* iw    = (int*)(wsb + 201844736);
  int* deg_m = iw;                 // 20000
  int* deg_u = iw + 20000;         // 100000 (contiguous with deg_m: one zero range)
  int* off_m = iw + 120000;        // 20001 (+pad to 140004)
  int* off_u = iw + 140004;        // 100001 (+pad to 240008)
  int* csr_m = iw + 240008;        // 1M
  int* csr_u = iw + 1240008;       // 1M

  float* out_movie = (float*)d_out;
  float* out_user  = (float*)d_out + (size_t)NM * OUTDIM;

  // ---- prep: zero degs + conversions + weight transposes (one launch) ----
  prep_kernel<<<(PR3 + 255) / 256, 256, 0, stream>>>(
      x_user, xu_bf, x_movie, xmcat,
      w1_rm_l, w1_rm_r, w1_mu_l, w1_mu_r, w2_rm_l, w2_mu_r, w2_mu_l, w2_rm_r,
      wL1_t, w1mur_t, wL2u_t, w2mul_t, w2rmr_t, deg_m);

  // ---- CSR build ----
  hist_kernel<<<(E_EDGES / 4 + 255) / 256, 256, 0, stream>>>(esrc, edst, deg_u, deg_m,
                                                             rank_u, rank_m);
  scan2_kernel<<<2, 1024, 0, stream>>>(deg_m, off_m, deg_u, off_u);
  csr_fill_kernel<<<(E_EDGES / 4 + 255) / 256, 256, 0, stream>>>(
      esrc, edst, rank_m, rank_u, off_m, off_u, csr_m, csr_u);

  // ---- layer 1 ----
  // M1m -> xmcat cols [0,128)
  gather_mean_kernel<128><<<(NM + 15) / 16, 256, 0, stream>>>(xu_bf, off_m, csr_m, xmcat, NM, XMW);
  // fused: h_movie = relu(xmcat@wcat1 + b1_rm); t1 = x_movie@w1_mu_l
  gemm_bf16_kernel<0><<<dim3(157, 4), 256, 0, stream>>>(
      xmcat, XMW, wL1_t, XMW, XMW, nullptr, b1_rm, hm_bf, t1_bf, NM);
  // t2 = h_movie @ w2_mu_l  (hoisted: only needs hm)
  gemm_bf16_kernel<2><<<dim3(157, 1), 256, 0, stream>>>(
      hm_bf, 256, w2mul_t, 256, 256, nullptr, nullptr, t2_bf, nullptr, NM);
  // M1u = mean over csr_u of t1
  gather_mean_kernel<256><<<(NU + 7) / 8, 256, 0, stream>>>(t1_bf, off_u, csr_u, M1u_bf, NU, 256);
  // h_user = relu(x_user@w1_mu_r + M1u + b1_mu)
  gemm_bf16_kernel<1><<<dim3(782, 2), 256, 0, stream>>>(
      xu_bf, 128, w1mur_t, 128, 128, M1u_bf, b1_mu, hu_bf, nullptr, NU);

  // ---- layer 2 ----
  // M2u = mean over csr_u of t2
  gather_mean_kernel<128><<<(NU + 15) / 16, 256, 0, stream>>>(t2_bf, off_u, csr_u, M2u_bf, NU, 128);
  // fused: hul = h_user@w2_rm_l ; out_user = h_user@w2_mu_r + M2u + b2_mu
  gemm_bf16_kernel<3><<<dim3(782, 2), 256, 0, stream>>>(
      hu_bf, 256, wL2u_t, 256, 256, M2u_bf, b2_mu, hul_bf, out_user, NU);
  // M2m = mean over csr_m of hul
  gather_mean_kernel<128><<<(NM + 15) / 16, 256, 0, stream>>>(hul_bf, off_m, csr_m, M2m_bf, NM, 128);
  // out_movie = h_movie@w2_rm_r + M2m + b2_rm
  gemm_bf16_kernel<4><<<dim3(157, 1), 256, 0, stream>>>(
      hm_bf, 256, w2rmr_t, 256, 256, M2m_bf, b2_rm, out_movie, nullptr, NM);
}

// Round 7
// 541.955 us; speedup vs baseline: 19.8885x; 1.0051x over previous
//
#include <hip/hip_runtime.h>
#include <cstddef>
#include <cstdint>

#define E_EDGES 1000000
#define NU 100000
#define NM 20000
#define DU 128
#define DM 404      // D_MOVIE
#define HIDDIM 256
#define OUTDIM 128
#define XMW 544     // concat row width: 128 + 404 + 12 pad  (17*32)

typedef short bf8_t __attribute__((ext_vector_type(8)));   // 8 bf16 (4 VGPR) MFMA A/B frag
typedef float f32x4 __attribute__((ext_vector_type(4)));   // MFMA C/D frag
typedef unsigned short u16x8 __attribute__((ext_vector_type(8)));  // 16B bf16 vector

__device__ __forceinline__ float b2f(unsigned short u) {
  union { unsigned int i; float f; } x; x.i = ((unsigned int)u) << 16; return x.f;
}
__device__ __forceinline__ unsigned short f2b(float f) {
  union { float f; unsigned int i; } x; x.f = f;
  unsigned int r = x.i + 0x7FFFu + ((x.i >> 16) & 1u);  // RTNE
  return (unsigned short)(r >> 16);
}

#define GLOAD_LDS16(gp, lp)                                                      \
  __builtin_amdgcn_global_load_lds(                                              \
      (const __attribute__((address_space(1))) unsigned int*)(gp),               \
      (__attribute__((address_space(3))) unsigned int*)(lp), 16, 0, 0)

// ================= fused hist (blocks [0,HISTB)) + prep (rest) =================
// prep ranges (item index j): [0,PRA) x_user conv; [PRA,PRB) xmcat conv; [PRB,PRC) weights
#define HISTB 977
#define PRA 3200000
#define PRB 5280000
#define PRC 5722368
__global__ __launch_bounds__(256) void hist_prep_kernel(
    const int* __restrict__ esrc, const int* __restrict__ edst,
    int* __restrict__ deg_u, int* __restrict__ deg_m,
    int* __restrict__ rank_u, int* __restrict__ rank_m,
    const float* __restrict__ x_user, unsigned short* __restrict__ xu_bf,
    const float* __restrict__ x_movie, unsigned short* __restrict__ xmcat,
    const float* __restrict__ w1_rm_l, const float* __restrict__ w1_rm_r,
    const float* __restrict__ w1_mu_l, const float* __restrict__ w1_mu_r,
    const float* __restrict__ w2_rm_l, const float* __restrict__ w2_mu_r,
    const float* __restrict__ w2_mu_l, const float* __restrict__ w2_rm_r,
    unsigned short* __restrict__ wL1, unsigned short* __restrict__ w1mur,
    unsigned short* __restrict__ wL2u, unsigned short* __restrict__ w2mul,
    unsigned short* __restrict__ w2rmr) {
  if (blockIdx.x < HISTB) {
    int e4 = blockIdx.x * 256 + threadIdx.x;
    if (e4 >= E_EDGES / 4) return;
    int4 s4 = reinterpret_cast<const int4*>(esrc)[e4];
    int4 d4 = reinterpret_cast<const int4*>(edst)[e4];
    int4 ru, rm;
    ru.x = atomicAdd(&deg_u[s4.x], 1);
    ru.y = atomicAdd(&deg_u[s4.y], 1);
    ru.z = atomicAdd(&deg_u[s4.z], 1);
    ru.w = atomicAdd(&deg_u[s4.w], 1);
    rm.x = atomicAdd(&deg_m[d4.x], 1);
    rm.y = atomicAdd(&deg_m[d4.y], 1);
    rm.z = atomicAdd(&deg_m[d4.z], 1);
    rm.w = atomicAdd(&deg_m[d4.w], 1);
    reinterpret_cast<int4*>(rank_u)[e4] = ru;
    reinterpret_cast<int4*>(rank_m)[e4] = rm;
    return;
  }
  int j = (blockIdx.x - HISTB) * 256 + threadIdx.x;
  if (j < PRA) {
    float4 v = reinterpret_cast<const float4*>(x_user)[j];
    ushort4 o;
    o.x = f2b(v.x); o.y = f2b(v.y); o.z = f2b(v.z); o.w = f2b(v.w);
    reinterpret_cast<ushort4*>(xu_bf)[j] = o;
  } else if (j < PRB) {
    int q = j - PRA;
    int row = q / 104, c4 = (q % 104) * 4;  // c4 in [0,416)
    ushort4 o;
    if (c4 < DM) {
      float4 v = *reinterpret_cast<const float4*>(&x_movie[(size_t)row * DM + c4]);
      o.x = f2b(v.x); o.y = f2b(v.y); o.z = f2b(v.z); o.w = f2b(v.w);
    } else {
      o.x = o.y = o.z = o.w = 0;
    }
    *reinterpret_cast<ushort4*>(&xmcat[(size_t)row * XMW + 128 + c4]) = o;
  } else if (j < PRC) {
    int q = j - PRB;
    if (q < 278528) {
      int n = q / 544, k = q % 544;
      float v = 0.f;
      if (n < 256) {
        if (k < 128) v = w1_rm_l[(size_t)k * 256 + n];
        else if (k < 532) v = w1_rm_r[(size_t)(k - 128) * 256 + n];
      } else {
        if (k >= 128 && k < 532) v = w1_mu_l[(size_t)(k - 128) * 256 + (n - 256)];
      }
      wL1[q] = f2b(v);
    } else if (q < 311296) {
      int p = q - 278528; int n = p / 128, k = p % 128;
      w1mur[p] = f2b(w1_mu_r[(size_t)k * 256 + n]);
    } else if (q < 376832) {
      int p = q - 311296; int n = p / 256, k = p % 256;
      float v = (n < 128) ? w2_rm_l[(size_t)k * 128 + n] : w2_mu_r[(size_t)k * 128 + (n - 128)];
      wL2u[p] = f2b(v);
    } else if (q < 409600) {
      int p = q - 376832; int n = p / 256, k = p % 256;
      w2mul[p] = f2b(w2_mu_l[(size_t)k * 128 + n]);
    } else {
      int p = q - 409600; int n = p / 256, k = p % 256;
      w2rmr[p] = f2b(w2_rm_r[(size_t)k * 128 + n]);
    }
  }
}

// ================= exclusive scans (block 0: movies, block 1: users) =================
__global__ __launch_bounds__(1024) void scan2_kernel(const int* __restrict__ deg_m,
                                                     int* __restrict__ off_m,
                                                     const int* __restrict__ deg_u,
                                                     int* __restrict__ off_u) {
  const int* __restrict__ deg = blockIdx.x ? deg_u : deg_m;
  int* __restrict__ off = blockIdx.x ? off_u : off_m;
  const int n = blockIdx.x ? NU : NM;
  const int tid = threadIdx.x;
  const int lane = tid & 63;
  const int w = tid >> 6;  // 16 waves
  __shared__ int wsum[16];
  int carry = 0;
  for (int base = 0; base < n; base += 16384) {
    const int i0 = base + tid * 16;
    int v[16];
    int s = 0;
    if (i0 + 16 <= n) {
#pragma unroll
      for (int q = 0; q < 4; ++q) {
        int4 t4 = *reinterpret_cast<const int4*>(&deg[i0 + q * 4]);
        v[q * 4 + 0] = t4.x; v[q * 4 + 1] = t4.y; v[q * 4 + 2] = t4.z; v[q * 4 + 3] = t4.w;
      }
    } else {
#pragma unroll
      for (int j = 0; j < 16; ++j) v[j] = (i0 + j < n) ? deg[i0 + j] : 0;
    }
#pragma unroll
    for (int j = 0; j < 16; ++j) s += v[j];
    int ws_ = s;
#pragma unroll
    for (int d = 1; d < 64; d <<= 1) {
      int t = __shfl_up(ws_, d, 64);
      if (lane >= d) ws_ += t;
    }
    if (lane == 63) wsum[w] = ws_;
    __syncthreads();
    int woff = 0, ctot = 0;
#pragma unroll
    for (int j = 0; j < 16; ++j) {
      int x = wsum[j];
      if (j < w) woff += x;
      ctot += x;
    }
    int ex = carry + woff + ws_ - s;  // exclusive prefix for this thread's chunk
    if (i0 + 16 <= n) {
      int o[16];
#pragma unroll
      for (int j = 0; j < 16; ++j) { o[j] = ex; ex += v[j]; }
#pragma unroll
      for (int q = 0; q < 4; ++q)
        *reinterpret_cast<int4*>(&off[i0 + q * 4]) =
            make_int4(o[q * 4], o[q * 4 + 1], o[q * 4 + 2], o[q * 4 + 3]);
    } else {
#pragma unroll
      for (int j = 0; j < 16; ++j) {
        if (i0 + j < n) off[i0 + j] = ex;
        ex += v[j];
      }
    }
    carry += ctot;
    __syncthreads();
  }
  if (tid == 0) off[n] = carry;
}

// ================= shared GEMM core =================
// Tile 128x128, 4 waves each own a 64x64 quadrant (4x4 of 16x16x32 mfma).
// MODE 0: bias+relu, bf16 out s256 (h_movie)
// MODE 1: elem(s256)+bias+relu, bf16 out s256 (h_user)
// MODE 2: plain bf16 out s128 (t2)
// MODE 3: split: gcol<128 -> outA bf16 s128 (hul); gcol>=128 -> outB f32 s128 elem+bias (out_user)
// MODE 4: f32 out s128, elem(s128)+bias (out_movie)
// MODE 5: plain bf16 out s256 (t1, fused into fill)
template <int MODE>
__device__ __forceinline__ void gemm_core(
    const unsigned short* __restrict__ A, int lda,
    const unsigned short* __restrict__ Bt, int ldb, int K,
    const unsigned short* __restrict__ elem, const float* __restrict__ bias,
    void* __restrict__ outA, void* __restrict__ outB, int M, int bx, int by,
    unsigned short* Alds, unsigned short* Blds) {
  const int tid = threadIdx.x;
  const int w = tid >> 6, l = tid & 63;
  const int row0 = bx * 128;
  const int col0 = by * 128;
  const int wr = w >> 1, wc = w & 1;

  f32x4 acc[4][4] = {};

  int ar0 = row0 + w * 32 + (l >> 2);
  int ar1 = ar0 + 16;
  if (ar0 >= M) ar0 = M - 1;
  if (ar1 >= M) ar1 = M - 1;
  const size_t aoff0 = (size_t)ar0 * lda + (l & 3) * 8;
  const size_t aoff1 = (size_t)ar1 * lda + (l & 3) * 8;
  const int nr0 = col0 + w * 32 + (l >> 2);
  const size_t boff0 = (size_t)nr0 * ldb + (l & 3) * 8;
  const size_t boff1 = (size_t)(nr0 + 16) * ldb + (l & 3) * 8;
  unsigned short* aldsb = &Alds[w * 1024];
  unsigned short* bldsb = &Blds[w * 1024];

  for (int k0 = 0; k0 < K; k0 += 32) {
    GLOAD_LDS16(A + aoff0 + k0, aldsb);
    GLOAD_LDS16(A + aoff1 + k0, aldsb + 512);
    GLOAD_LDS16(Bt + boff0 + k0, bldsb);
    GLOAD_LDS16(Bt + boff1 + k0, bldsb + 512);
    __syncthreads();
    bf8_t af[4], bfr[4];
#pragma unroll
    for (int mi = 0; mi < 4; ++mi)
      af[mi] = *reinterpret_cast<const bf8_t*>(&Alds[(wr * 64 + mi * 16 + (l & 15)) * 32 + (l >> 4) * 8]);
#pragma unroll
    for (int nj = 0; nj < 4; ++nj)
      bfr[nj] = *reinterpret_cast<const bf8_t*>(&Blds[(wc * 64 + nj * 16 + (l & 15)) * 32 + (l >> 4) * 8]);
#pragma unroll
    for (int mi = 0; mi < 4; ++mi)
#pragma unroll
      for (int nj = 0; nj < 4; ++nj)
        acc[mi][nj] = __builtin_amdgcn_mfma_f32_16x16x32_bf16(af[mi], bfr[nj], acc[mi][nj], 0, 0, 0);
    __syncthreads();
  }

  // epilogue: C[row0 + wr*64 + mi*16 + (l>>4)*4 + r][col0 + wc*64 + nj*16 + (l&15)]
#pragma unroll
  for (int mi = 0; mi < 4; ++mi) {
    const int rbase = row0 + wr * 64 + mi * 16 + ((l >> 4) << 2);
#pragma unroll
    for (int nj = 0; nj < 4; ++nj) {
      const int gcol = col0 + wc * 64 + nj * 16 + (l & 15);
      bool halfB = false;
      int col = gcol;
      if constexpr (MODE == 3) { halfB = gcol >= 128; col = halfB ? gcol - 128 : gcol; }
      float bb = 0.0f;
      if constexpr (MODE == 0 || MODE == 1 || MODE == 4) bb = bias[col];
      if constexpr (MODE == 3) { if (halfB) bb = bias[col]; }
#pragma unroll
      for (int r = 0; r < 4; ++r) {
        const int row = rbase + r;
        if (row >= M) continue;
        float v = acc[mi][nj][r] + bb;
        if constexpr (MODE == 1) v += b2f(elem[(size_t)row * 256 + col]);
        if constexpr (MODE == 4) v += b2f(elem[(size_t)row * 128 + col]);
        if constexpr (MODE == 3) { if (halfB) v += b2f(elem[(size_t)row * 128 + col]); }
        if constexpr (MODE == 0 || MODE == 1) v = fmaxf(v, 0.0f);
        if constexpr (MODE == 0 || MODE == 1 || MODE == 5) {
          ((unsigned short*)outA)[(size_t)row * 256 + col] = f2b(v);
        } else if constexpr (MODE == 2) {
          ((unsigned short*)outA)[(size_t)row * 128 + col] = f2b(v);
        } else if constexpr (MODE == 3) {
          if (halfB) ((float*)outB)[(size_t)row * 128 + col] = v;
          else ((unsigned short*)outA)[(size_t)row * 128 + col] = f2b(v);
        } else {
          ((float*)outA)[(size_t)row * 128 + col] = v;
        }
      }
    }
  }
}

template <int MODE>
__global__ __launch_bounds__(256) void gemm_bf16_kernel(
    const unsigned short* __restrict__ A, int lda,
    const unsigned short* __restrict__ Bt, int ldb, int K,
    const unsigned short* __restrict__ elem, const float* __restrict__ bias,
    void* __restrict__ outA, void* __restrict__ outB, int M) {
  __shared__ unsigned short Alds[128 * 32];
  __shared__ unsigned short Blds[128 * 32];
  gemm_core<MODE>(A, lda, Bt, ldb, K, elem, bias, outA, outB, M,
                  blockIdx.x, blockIdx.y, Alds, Blds);
}

// ================= fused: CSR fill (blocks [0,FILLB)) + t1 GEMM (rest) =================
#define FILLB 977
__global__ __launch_bounds__(256) void fill_t1_kernel(
    const int* __restrict__ esrc, const int* __restrict__ edst,
    const int* __restrict__ rank_m, const int* __restrict__ rank_u,
    const int* __restrict__ off_m, const int* __restrict__ off_u,
    int* __restrict__ csr_m, int* __restrict__ csr_u,
    const unsigned short* __restrict__ A, const unsigned short* __restrict__ Bt,
    unsigned short* __restrict__ t1) {
  __shared__ unsigned short Alds[128 * 32];
  __shared__ unsigned short Blds[128 * 32];
  if (blockIdx.x < FILLB) {
    int e4 = blockIdx.x * 256 + threadIdx.x;
    if (e4 >= E_EDGES / 4) return;
    int4 s4 = reinterpret_cast<const int4*>(esrc)[e4];
    int4 d4 = reinterpret_cast<const int4*>(edst)[e4];
    int4 rm = reinterpret_cast<const int4*>(rank_m)[e4];
    int4 ru = reinterpret_cast<const int4*>(rank_u)[e4];
    csr_m[off_m[d4.x] + rm.x] = s4.x;
    csr_m[off_m[d4.y] + rm.y] = s4.y;
    csr_m[off_m[d4.z] + rm.z] = s4.z;
    csr_m[off_m[d4.w] + rm.w] = s4.w;
    csr_u[off_u[s4.x] + ru.x] = d4.x;
    csr_u[off_u[s4.y] + ru.y] = d4.y;
    csr_u[off_u[s4.z] + ru.z] = d4.z;
    csr_u[off_u[s4.w] + ru.w] = d4.w;
    return;
  }
  // t1 = x_movie @ w1_mu_l : A = xmcat+128 (lda 544, K=416), Bt = wL1 rows 256.. offset 128
  const int bi = blockIdx.x - FILLB;           // 0..313
  gemm_core<5>(A, XMW, Bt, XMW, 416, nullptr, nullptr, t1, nullptr, NM,
               bi % 157, bi / 157, Alds, Blds);
}

// ================= gather-mean: each D/8-lane group owns one node =================
// 16B/lane loads; no cross-lane reduction; 4 loads in flight per group.
template <int D>
__global__ __launch_bounds__(256) void gather_mean_kernel(
    const unsigned short* __restrict__ table, const int* __restrict__ off,
    const int* __restrict__ idx, unsigned short* __restrict__ out, int n, int ostride) {
  constexpr int LPN = D / 8;       // lanes per node: 32 (D=256) / 16 (D=128)
  constexpr int NPB = 256 / LPN;   // nodes per block: 8 / 16
  const int t = threadIdx.x;
  const int g = t / LPN;
  const int cl = (t % LPN) * 8;
  const int node = blockIdx.x * NPB + g;
  if (node >= n) return;
  const int beg = off[node], end = off[node + 1];
  const float sc = 1.0f / fmaxf((float)(end - beg), 1.0f);
  float a[8] = {0, 0, 0, 0, 0, 0, 0, 0}, b[8] = {0, 0, 0, 0, 0, 0, 0, 0};
  int p = beg;
  for (; p + 3 < end; p += 4) {
    const int r0 = idx[p], r1 = idx[p + 1], r2 = idx[p + 2], r3 = idx[p + 3];
    u16x8 v0 = *reinterpret_cast<const u16x8*>(&table[(size_t)r0 * D + cl]);
    u16x8 v1 = *reinterpret_cast<const u16x8*>(&table[(size_t)r1 * D + cl]);
    u16x8 v2 = *reinterpret_cast<const u16x8*>(&table[(size_t)r2 * D + cl]);
    u16x8 v3 = *reinterpret_cast<const u16x8*>(&table[(size_t)r3 * D + cl]);
#pragma unroll
    for (int j = 0; j < 8; ++j) { a[j] += b2f(v0[j]); b[j] += b2f(v1[j]); }
#pragma unroll
    for (int j = 0; j < 8; ++j) { a[j] += b2f(v2[j]); b[j] += b2f(v3[j]); }
  }
  for (; p < end; ++p) {
    const int r0 = idx[p];
    u16x8 v0 = *reinterpret_cast<const u16x8*>(&table[(size_t)r0 * D + cl]);
#pragma unroll
    for (int j = 0; j < 8; ++j) a[j] += b2f(v0[j]);
  }
  u16x8 o;
#pragma unroll
  for (int j = 0; j < 8; ++j) o[j] = f2b((a[j] + b[j]) * sc);
  *reinterpret_cast<u16x8*>(&out[(size_t)node * ostride + cl]) = o;
}

extern "C" void kernel_launch(void* const* d_in, const int* in_sizes, int n_in,
                              void* d_out, int out_size, void* d_ws, size_t ws_size,
                              hipStream_t stream) {
  const float* x_user  = (const float*)d_in[0];
  const float* x_movie = (const float*)d_in[1];
  const int*   esrc    = (const int*)d_in[2];
  const int*   edst    = (const int*)d_in[3];
  const float* w1_rm_l = (const float*)d_in[4];
  const float* b1_rm   = (const float*)d_in[5];
  const float* w1_rm_r = (const float*)d_in[6];
  const float* w1_mu_l = (const float*)d_in[7];
  const float* b1_mu   = (const float*)d_in[8];
  const float* w1_mu_r = (const float*)d_in[9];
  const float* w2_rm_l = (const float*)d_in[10];
  const float* b2_rm   = (const float*)d_in[11];
  const float* w2_rm_r = (const float*)d_in[12];
  const float* w2_mu_l = (const float*)d_in[13];
  const float* b2_mu   = (const float*)d_in[14];
  const float* w2_mu_r = (const float*)d_in[15];

  if (ws_size < 214240008ull) return;
  char* wsb = (char*)d_ws;
  unsigned short* xu_bf  = (unsigned short*)(wsb + 0);           // 100000x128
  unsigned short* xmcat  = (unsigned short*)(wsb + 25600000);    // 20000x544: [M1m | x_movie | 0]
  unsigned short* hm_bf  = (unsigned short*)(wsb + 47360000);    // 20000x256
  unsigned short* t1_bf  = (unsigned short*)(wsb + 57600000);    // 20000x256
  unsigned short* M2m_bf = (unsigned short*)(wsb + 57600000);    // 20000x128 (aliases t1, dead)
  unsigned short* t2_bf  = (unsigned short*)(wsb + 67840000);    // 20000x128
  unsigned short* M1u_bf = (unsigned short*)(wsb + 72960000);    // 100000x256
  unsigned short* hul_bf = (unsigned short*)(wsb + 72960000);    // 100000x128 (aliases M1u, dead)
  unsigned short* M2u_bf = (unsigned short*)(wsb + 124160000);   // 100000x128
  unsigned short* hu_bf  = (unsigned short*)(wsb + 149760000);   // 100000x256
  int* rank_m = (int*)(wsb + 149760000);                         // 1M ints (dead before hu write)
  int* rank_u = (int*)(wsb + 153760000);                         // 1M ints
  unsigned short* wts = (unsigned short*)(wsb + 200960000);
  unsigned short* wL1_t   = wts;            // 512x544
  unsigned short* w1mur_t = wts + 278528;   // 256x128
  unsigned short* wL2u_t  = wts + 311296;   // 256x256 [w2_rm_l | w2_mu_r]
  unsigned short* w2mul_t = wts + 376832;   // 128x256
  unsigned short* w2rmr_t = wts + 409600;   // 128x256
  int* iw    = (int*)(wsb + 201844736);
  int* deg_m = iw;                 // 20000
  int* deg_u = iw + 20000;         // 100000 (contiguous with deg_m: one memset)
  int* off_m = iw + 120000;        // 20001 (+pad to 140004)
  int* off_u = iw + 140004;        // 100001 (+pad to 240008)
  int* csr_m = iw + 240008;        // 1M
  int* csr_u = iw + 1240008;       // 1M

  float* out_movie = (float*)d_out;
  float* out_user  = (float*)d_out + (size_t)NM * OUTDIM;

  // ---- zero degree arrays (small), then fused hist + prep ----
  hipMemsetAsync(deg_m, 0, 120000 * sizeof(int), stream);
  hist_prep_kernel<<<HISTB + (PRC + 255) / 256, 256, 0, stream>>>(
      esrc, edst, deg_u, deg_m, rank_u, rank_m,
      x_user, xu_bf, x_movie, xmcat,
      w1_rm_l, w1_rm_r, w1_mu_l, w1_mu_r, w2_rm_l, w2_mu_r, w2_mu_l, w2_rm_r,
      wL1_t, w1mur_t, wL2u_t, w2mul_t, w2rmr_t);

  // ---- scans ----
  scan2_kernel<<<2, 1024, 0, stream>>>(deg_m, off_m, deg_u, off_u);

  // ---- fused: CSR fill + t1 = x_movie @ w1_mu_l ----
  fill_t1_kernel<<<FILLB + 314, 256, 0, stream>>>(
      esrc, edst, rank_m, rank_u, off_m, off_u, csr_m, csr_u,
      xmcat + 128, wL1_t + 256 * XMW + 128, t1_bf);

  // ---- layer 1 ----
  // M1m -> xmcat cols [0,128)
  gather_mean_kernel<128><<<(NM + 15) / 16, 256, 0, stream>>>(xu_bf, off_m, csr_m, xmcat, NM, XMW);
  // M1u = mean over csr_u of t1
  gather_mean_kernel<256><<<(NU + 7) / 8, 256, 0, stream>>>(t1_bf, off_u, csr_u, M1u_bf, NU, 256);
  // h_movie = relu(xmcat @ wcat1 + b1_rm)
  gemm_bf16_kernel<0><<<dim3(157, 2), 256, 0, stream>>>(
      xmcat, XMW, wL1_t, XMW, XMW, nullptr, b1_rm, hm_bf, nullptr, NM);
  // t2 = h_movie @ w2_mu_l
  gemm_bf16_kernel<2><<<dim3(157, 1), 256, 0, stream>>>(
      hm_bf, 256, w2mul_t, 256, 256, nullptr, nullptr, t2_bf, nullptr, NM);
  // h_user = relu(x_user@w1_mu_r + M1u + b1_mu)
  gemm_bf16_kernel<1><<<dim3(782, 2), 256, 0, stream>>>(
      xu_bf, 128, w1mur_t, 128, 128, M1u_bf, b1_mu, hu_bf, nullptr, NU);

  // ---- layer 2 ----
  // M2u = mean over csr_u of t2
  gather_mean_kernel<128><<<(NU + 15) / 16, 256, 0, stream>>>(t2_bf, off_u, csr_u, M2u_bf, NU, 128);
  // fused: hul = h_user@w2_rm_l ; out_user = h_user@w2_mu_r + M2u + b2_mu
  gemm_bf16_kernel<3><<<dim3(782, 2), 256, 0, stream>>>(
      hu_bf, 256, wL2u_t, 256, 256, M2u_bf, b2_mu, hul_bf, out_user, NU);
  // M2m = mean over csr_m of hul
  gather_mean_kernel<128><<<(NM + 15) / 16, 256, 0, stream>>>(hul_bf, off_m, csr_m, M2m_bf, NM, 128);
  // out_movie = h_movie@w2_rm_r + M2m + b2_rm
  gemm_bf16_kernel<4><<<dim3(157, 1), 256, 0, stream>>>(
      hm_bf, 256, w2rmr_t, 256, 256, M2m_bf, b2_rm, out_movie, nullptr, NM);
}

// Round 8
// 475.592 us; speedup vs baseline: 22.6636x; 1.1395x over previous
//
#include <hip/hip_runtime.h>
#include <cstddef>
#include <cstdint>

#define E_EDGES 1000000
#define NU 100000
#define NM 20000
#define DU 128
#define DM 404      // D_MOVIE
#define HIDDIM 256
#define OUTDIM 128
#define XMW 544     // concat row width: 128 + 404 + 12 pad  (17*32)

typedef short bf8_t __attribute__((ext_vector_type(8)));   // 8 bf16 (4 VGPR) MFMA A/B frag
typedef float f32x4 __attribute__((ext_vector_type(4)));   // MFMA C/D frag
typedef unsigned short u16x8 __attribute__((ext_vector_type(8)));  // 16B bf16 vector

__device__ __forceinline__ float b2f(unsigned short u) {
  union { unsigned int i; float f; } x; x.i = ((unsigned int)u) << 16; return x.f;
}
__device__ __forceinline__ unsigned short f2b(float f) {
  union { float f; unsigned int i; } x; x.f = f;
  unsigned int r = x.i + 0x7FFFu + ((x.i >> 16) & 1u);  // RTNE
  return (unsigned short)(r >> 16);
}

#define GLOAD_LDS16(gp, lp)                                                      \
  __builtin_amdgcn_global_load_lds(                                              \
      (const __attribute__((address_space(1))) unsigned int*)(gp),               \
      (__attribute__((address_space(3))) unsigned int*)(lp), 16, 0, 0)

// ================= fused hist (blocks [0,HISTB)) + prep (rest) =================
#define HISTB 977
#define PRA 3200000
#define PRB 5280000
#define PRC 5722368
__global__ __launch_bounds__(256) void hist_prep_kernel(
    const int* __restrict__ esrc, const int* __restrict__ edst,
    int* __restrict__ deg_u, int* __restrict__ deg_m,
    int* __restrict__ rank_u, int* __restrict__ rank_m,
    const float* __restrict__ x_user, unsigned short* __restrict__ xu_bf,
    const float* __restrict__ x_movie, unsigned short* __restrict__ xmcat,
    const float* __restrict__ w1_rm_l, const float* __restrict__ w1_rm_r,
    const float* __restrict__ w1_mu_l, const float* __restrict__ w1_mu_r,
    const float* __restrict__ w2_rm_l, const float* __restrict__ w2_mu_r,
    const float* __restrict__ w2_mu_l, const float* __restrict__ w2_rm_r,
    unsigned short* __restrict__ wL1, unsigned short* __restrict__ w1mur,
    unsigned short* __restrict__ wL2u, unsigned short* __restrict__ w2mul,
    unsigned short* __restrict__ w2rmr) {
  if (blockIdx.x < HISTB) {
    int e4 = blockIdx.x * 256 + threadIdx.x;
    if (e4 >= E_EDGES / 4) return;
    int4 s4 = reinterpret_cast<const int4*>(esrc)[e4];
    int4 d4 = reinterpret_cast<const int4*>(edst)[e4];
    int4 ru, rm;
    ru.x = atomicAdd(&deg_u[s4.x], 1);
    ru.y = atomicAdd(&deg_u[s4.y], 1);
    ru.z = atomicAdd(&deg_u[s4.z], 1);
    ru.w = atomicAdd(&deg_u[s4.w], 1);
    rm.x = atomicAdd(&deg_m[d4.x], 1);
    rm.y = atomicAdd(&deg_m[d4.y], 1);
    rm.z = atomicAdd(&deg_m[d4.z], 1);
    rm.w = atomicAdd(&deg_m[d4.w], 1);
    reinterpret_cast<int4*>(rank_u)[e4] = ru;
    reinterpret_cast<int4*>(rank_m)[e4] = rm;
    return;
  }
  int j = (blockIdx.x - HISTB) * 256 + threadIdx.x;
  if (j < PRA) {
    float4 v = reinterpret_cast<const float4*>(x_user)[j];
    ushort4 o;
    o.x = f2b(v.x); o.y = f2b(v.y); o.z = f2b(v.z); o.w = f2b(v.w);
    reinterpret_cast<ushort4*>(xu_bf)[j] = o;
  } else if (j < PRB) {
    int q = j - PRA;
    int row = q / 104, c4 = (q % 104) * 4;  // c4 in [0,416)
    ushort4 o;
    if (c4 < DM) {
      float4 v = *reinterpret_cast<const float4*>(&x_movie[(size_t)row * DM + c4]);
      o.x = f2b(v.x); o.y = f2b(v.y); o.z = f2b(v.z); o.w = f2b(v.w);
    } else {
      o.x = o.y = o.z = o.w = 0;
    }
    *reinterpret_cast<ushort4*>(&xmcat[(size_t)row * XMW + 128 + c4]) = o;
  } else if (j < PRC) {
    int q = j - PRB;
    if (q < 278528) {
      int n = q / 544, k = q % 544;
      float v = 0.f;
      if (n < 256) {
        if (k < 128) v = w1_rm_l[(size_t)k * 256 + n];
        else if (k < 532) v = w1_rm_r[(size_t)(k - 128) * 256 + n];
      } else {
        if (k >= 128 && k < 532) v = w1_mu_l[(size_t)(k - 128) * 256 + (n - 256)];
      }
      wL1[q] = f2b(v);
    } else if (q < 311296) {
      int p = q - 278528; int n = p / 128, k = p % 128;
      w1mur[p] = f2b(w1_mu_r[(size_t)k * 256 + n]);
    } else if (q < 376832) {
      int p = q - 311296; int n = p / 256, k = p % 256;
      float v = (n < 128) ? w2_rm_l[(size_t)k * 128 + n] : w2_mu_r[(size_t)k * 128 + (n - 128)];
      wL2u[p] = f2b(v);
    } else if (q < 409600) {
      int p = q - 376832; int n = p / 256, k = p % 256;
      w2mul[p] = f2b(w2_mu_l[(size_t)k * 128 + n]);
    } else {
      int p = q - 409600; int n = p / 256, k = p % 256;
      w2rmr[p] = f2b(w2_rm_r[(size_t)k * 128 + n]);
    }
  }
}

// ================= exclusive scans (block 0: movies, block 1: users) =================
__global__ __launch_bounds__(1024) void scan2_kernel(const int* __restrict__ deg_m,
                                                     int* __restrict__ off_m,
                                                     const int* __restrict__ deg_u,
                                                     int* __restrict__ off_u) {
  const int* __restrict__ deg = blockIdx.x ? deg_u : deg_m;
  int* __restrict__ off = blockIdx.x ? off_u : off_m;
  const int n = blockIdx.x ? NU : NM;
  const int tid = threadIdx.x;
  const int lane = tid & 63;
  const int w = tid >> 6;  // 16 waves
  __shared__ int wsum[16];
  int carry = 0;
  for (int base = 0; base < n; base += 16384) {
    const int i0 = base + tid * 16;
    int v[16];
    int s = 0;
    if (i0 + 16 <= n) {
#pragma unroll
      for (int q = 0; q < 4; ++q) {
        int4 t4 = *reinterpret_cast<const int4*>(&deg[i0 + q * 4]);
        v[q * 4 + 0] = t4.x; v[q * 4 + 1] = t4.y; v[q * 4 + 2] = t4.z; v[q * 4 + 3] = t4.w;
      }
    } else {
#pragma unroll
      for (int j = 0; j < 16; ++j) v[j] = (i0 + j < n) ? deg[i0 + j] : 0;
    }
#pragma unroll
    for (int j = 0; j < 16; ++j) s += v[j];
    int ws_ = s;
#pragma unroll
    for (int d = 1; d < 64; d <<= 1) {
      int t = __shfl_up(ws_, d, 64);
      if (lane >= d) ws_ += t;
    }
    if (lane == 63) wsum[w] = ws_;
    __syncthreads();
    int woff = 0, ctot = 0;
#pragma unroll
    for (int j = 0; j < 16; ++j) {
      int x = wsum[j];
      if (j < w) woff += x;
      ctot += x;
    }
    int ex = carry + woff + ws_ - s;
    if (i0 + 16 <= n) {
      int o[16];
#pragma unroll
      for (int j = 0; j < 16; ++j) { o[j] = ex; ex += v[j]; }
#pragma unroll
      for (int q = 0; q < 4; ++q)
        *reinterpret_cast<int4*>(&off[i0 + q * 4]) =
            make_int4(o[q * 4], o[q * 4 + 1], o[q * 4 + 2], o[q * 4 + 3]);
    } else {
#pragma unroll
      for (int j = 0; j < 16; ++j) {
        if (i0 + j < n) off[i0 + j] = ex;
        ex += v[j];
      }
    }
    carry += ctot;
    __syncthreads();
  }
  if (tid == 0) off[n] = carry;
}

// ================= shared GEMM core =================
// MODE 0: bias+relu, bf16 out s256       MODE 1: elem(s256)+bias+relu, bf16 out s256
// MODE 2: plain bf16 out s128            MODE 4: f32 out s128, elem(s128)+bias
// MODE 5: plain bf16 out s256
template <int MODE>
__device__ __forceinline__ void gemm_core(
    const unsigned short* __restrict__ A, int lda,
    const unsigned short* __restrict__ Bt, int ldb, int K,
    const unsigned short* __restrict__ elem, const float* __restrict__ bias,
    void* __restrict__ outA, int M, int bx, int by,
    unsigned short* Alds, unsigned short* Blds) {
  const int tid = threadIdx.x;
  const int w = tid >> 6, l = tid & 63;
  const int row0 = bx * 128;
  const int col0 = by * 128;
  const int wr = w >> 1, wc = w & 1;

  f32x4 acc[4][4] = {};

  int ar0 = row0 + w * 32 + (l >> 2);
  int ar1 = ar0 + 16;
  if (ar0 >= M) ar0 = M - 1;
  if (ar1 >= M) ar1 = M - 1;
  const size_t aoff0 = (size_t)ar0 * lda + (l & 3) * 8;
  const size_t aoff1 = (size_t)ar1 * lda + (l & 3) * 8;
  const int nr0 = col0 + w * 32 + (l >> 2);
  const size_t boff0 = (size_t)nr0 * ldb + (l & 3) * 8;
  const size_t boff1 = (size_t)(nr0 + 16) * ldb + (l & 3) * 8;
  unsigned short* aldsb = &Alds[w * 1024];
  unsigned short* bldsb = &Blds[w * 1024];

  for (int k0 = 0; k0 < K; k0 += 32) {
    GLOAD_LDS16(A + aoff0 + k0, aldsb);
    GLOAD_LDS16(A + aoff1 + k0, aldsb + 512);
    GLOAD_LDS16(Bt + boff0 + k0, bldsb);
    GLOAD_LDS16(Bt + boff1 + k0, bldsb + 512);
    __syncthreads();
    bf8_t af[4], bfr[4];
#pragma unroll
    for (int mi = 0; mi < 4; ++mi)
      af[mi] = *reinterpret_cast<const bf8_t*>(&Alds[(wr * 64 + mi * 16 + (l & 15)) * 32 + (l >> 4) * 8]);
#pragma unroll
    for (int nj = 0; nj < 4; ++nj)
      bfr[nj] = *reinterpret_cast<const bf8_t*>(&Blds[(wc * 64 + nj * 16 + (l & 15)) * 32 + (l >> 4) * 8]);
#pragma unroll
    for (int mi = 0; mi < 4; ++mi)
#pragma unroll
      for (int nj = 0; nj < 4; ++nj)
        acc[mi][nj] = __builtin_amdgcn_mfma_f32_16x16x32_bf16(af[mi], bfr[nj], acc[mi][nj], 0, 0, 0);
    __syncthreads();
  }

#pragma unroll
  for (int mi = 0; mi < 4; ++mi) {
    const int rbase = row0 + wr * 64 + mi * 16 + ((l >> 4) << 2);
#pragma unroll
    for (int nj = 0; nj < 4; ++nj) {
      const int col = col0 + wc * 64 + nj * 16 + (l & 15);
      float bb = 0.0f;
      if constexpr (MODE == 0 || MODE == 1 || MODE == 4) bb = bias[col];
#pragma unroll
      for (int r = 0; r < 4; ++r) {
        const int row = rbase + r;
        if (row >= M) continue;
        float v = acc[mi][nj][r] + bb;
        if constexpr (MODE == 1) v += b2f(elem[(size_t)row * 256 + col]);
        if constexpr (MODE == 4) v += b2f(elem[(size_t)row * 128 + col]);
        if constexpr (MODE == 0 || MODE == 1) v = fmaxf(v, 0.0f);
        if constexpr (MODE == 0 || MODE == 1 || MODE == 5) {
          ((unsigned short*)outA)[(size_t)row * 256 + col] = f2b(v);
        } else if constexpr (MODE == 2) {
          ((unsigned short*)outA)[(size_t)row * 128 + col] = f2b(v);
        } else {
          ((float*)outA)[(size_t)row * 128 + col] = v;
        }
      }
    }
  }
}

// ================= fused: CSR fill (blocks [0,FILLB)) + t1 GEMM (rest) =================
#define FILLB 977
__global__ __launch_bounds__(256) void fill_t1_kernel(
    const int* __restrict__ esrc, const int* __restrict__ edst,
    const int* __restrict__ rank_m, const int* __restrict__ rank_u,
    const int* __restrict__ off_m, const int* __restrict__ off_u,
    int* __restrict__ csr_m, int* __restrict__ csr_u,
    const unsigned short* __restrict__ A, const unsigned short* __restrict__ Bt,
    unsigned short* __restrict__ t1) {
  __shared__ unsigned short Alds[128 * 32];
  __shared__ unsigned short Blds[128 * 32];
  if (blockIdx.x < FILLB) {
    int e4 = blockIdx.x * 256 + threadIdx.x;
    if (e4 >= E_EDGES / 4) return;
    int4 s4 = reinterpret_cast<const int4*>(esrc)[e4];
    int4 d4 = reinterpret_cast<const int4*>(edst)[e4];
    int4 rm = reinterpret_cast<const int4*>(rank_m)[e4];
    int4 ru = reinterpret_cast<const int4*>(rank_u)[e4];
    csr_m[off_m[d4.x] + rm.x] = s4.x;
    csr_m[off_m[d4.y] + rm.y] = s4.y;
    csr_m[off_m[d4.z] + rm.z] = s4.z;
    csr_m[off_m[d4.w] + rm.w] = s4.w;
    csr_u[off_u[s4.x] + ru.x] = d4.x;
    csr_u[off_u[s4.y] + ru.y] = d4.y;
    csr_u[off_u[s4.z] + ru.z] = d4.z;
    csr_u[off_u[s4.w] + ru.w] = d4.w;
    return;
  }
  const int bi = blockIdx.x - FILLB;  // 0..313
  gemm_core<5>(A, XMW, Bt, XMW, 416, nullptr, nullptr, t1, NM,
               bi % 157, bi / 157, Alds, Blds);
}

// ================= gather core: each D/8-lane group owns one node =================
template <int D>
__device__ __forceinline__ void gather_core(
    const unsigned short* __restrict__ table, const int* __restrict__ off,
    const int* __restrict__ idx, unsigned short* __restrict__ out,
    int n, int ostride, int bi) {
  constexpr int LPN = D / 8;       // lanes per node: 32 (D=256) / 16 (D=128)
  constexpr int NPB = 256 / LPN;   // nodes per block: 8 / 16
  const int t = threadIdx.x;
  const int g = t / LPN;
  const int cl = (t % LPN) * 8;
  const int node = bi * NPB + g;
  if (node >= n) return;
  const int beg = off[node], end = off[node + 1];
  const float sc = 1.0f / fmaxf((float)(end - beg), 1.0f);
  float a[8] = {0, 0, 0, 0, 0, 0, 0, 0}, b[8] = {0, 0, 0, 0, 0, 0, 0, 0};
  int p = beg;
  for (; p + 3 < end; p += 4) {
    const int r0 = idx[p], r1 = idx[p + 1], r2 = idx[p + 2], r3 = idx[p + 3];
    u16x8 v0 = *reinterpret_cast<const u16x8*>(&table[(size_t)r0 * D + cl]);
    u16x8 v1 = *reinterpret_cast<const u16x8*>(&table[(size_t)r1 * D + cl]);
    u16x8 v2 = *reinterpret_cast<const u16x8*>(&table[(size_t)r2 * D + cl]);
    u16x8 v3 = *reinterpret_cast<const u16x8*>(&table[(size_t)r3 * D + cl]);
#pragma unroll
    for (int j = 0; j < 8; ++j) { a[j] += b2f(v0[j]); b[j] += b2f(v1[j]); }
#pragma unroll
    for (int j = 0; j < 8; ++j) { a[j] += b2f(v2[j]); b[j] += b2f(v3[j]); }
  }
  for (; p < end; ++p) {
    const int r0 = idx[p];
    u16x8 v0 = *reinterpret_cast<const u16x8*>(&table[(size_t)r0 * D + cl]);
#pragma unroll
    for (int j = 0; j < 8; ++j) a[j] += b2f(v0[j]);
  }
  u16x8 o;
#pragma unroll
  for (int j = 0; j < 8; ++j) o[j] = f2b((a[j] + b[j]) * sc);
  *reinterpret_cast<u16x8*>(&out[(size_t)node * ostride + cl]) = o;
}

// gatherA: blocks [0,12500) -> M1u (D=256, t1, csr_u); rest 1250 -> M1m (D=128, xu, csr_m -> xmcat)
__global__ __launch_bounds__(256) void gatherA_kernel(
    const unsigned short* __restrict__ t1, const int* __restrict__ off_u,
    const int* __restrict__ csr_u, unsigned short* __restrict__ M1u,
    const unsigned short* __restrict__ xu, const int* __restrict__ off_m,
    const int* __restrict__ csr_m, unsigned short* __restrict__ xmcat) {
  if (blockIdx.x < 12500)
    gather_core<256>(t1, off_u, csr_u, M1u, NU, 256, blockIdx.x);
  else
    gather_core<128>(xu, off_m, csr_m, xmcat, NM, XMW, blockIdx.x - 12500);
}

// gatherB: blocks [0,6250) -> M2u (D=128, t2, csr_u); rest 1250 -> M2m (D=128, hul, csr_m)
__global__ __launch_bounds__(256) void gatherB_kernel(
    const unsigned short* __restrict__ t2, const int* __restrict__ off_u,
    const int* __restrict__ csr_u, unsigned short* __restrict__ M2u,
    const unsigned short* __restrict__ hul, const int* __restrict__ off_m,
    const int* __restrict__ csr_m, unsigned short* __restrict__ M2m) {
  if (blockIdx.x < 6250)
    gather_core<128>(t2, off_u, csr_u, M2u, NU, 128, blockIdx.x);
  else
    gather_core<128>(hul, off_m, csr_m, M2m, NM, 128, blockIdx.x - 6250);
}

// gemmA: blocks [0,314) mode0 h_movie; rest 1564 mode1 h_user
__global__ __launch_bounds__(256) void gemmA_kernel(
    const unsigned short* __restrict__ xmcat, const unsigned short* __restrict__ wL1,
    const float* __restrict__ b1_rm, unsigned short* __restrict__ hm,
    const unsigned short* __restrict__ xu, const unsigned short* __restrict__ w1mur,
    const unsigned short* __restrict__ M1u, const float* __restrict__ b1_mu,
    unsigned short* __restrict__ hu) {
  __shared__ unsigned short Alds[128 * 32];
  __shared__ unsigned short Blds[128 * 32];
  if (blockIdx.x < 314) {
    int bi = blockIdx.x;
    gemm_core<0>(xmcat, XMW, wL1, XMW, XMW, nullptr, b1_rm, hm, NM,
                 bi % 157, bi / 157, Alds, Blds);
  } else {
    int bi = blockIdx.x - 314;
    gemm_core<1>(xu, 128, w1mur, 128, 128, M1u, b1_mu, hu, NU,
                 bi % 782, bi / 782, Alds, Blds);
  }
}

// gemmB: blocks [0,782) hul = hu@w2rml; rest 157 t2 = hm@w2mul  (both mode2)
__global__ __launch_bounds__(256) void gemmB_kernel(
    const unsigned short* __restrict__ hu, const unsigned short* __restrict__ w2rml,
    unsigned short* __restrict__ hul,
    const unsigned short* __restrict__ hm, const unsigned short* __restrict__ w2mul,
    unsigned short* __restrict__ t2) {
  __shared__ unsigned short Alds[128 * 32];
  __shared__ unsigned short Blds[128 * 32];
  if (blockIdx.x < 782) {
    gemm_core<2>(hu, 256, w2rml, 256, 256, nullptr, nullptr, hul, NU,
                 blockIdx.x, 0, Alds, Blds);
  } else {
    gemm_core<2>(hm, 256, w2mul, 256, 256, nullptr, nullptr, t2, NM,
                 blockIdx.x - 782, 0, Alds, Blds);
  }
}

// gemmC: blocks [0,782) out_user = hu@w2mur + M2u + b2_mu; rest 157 out_movie (both mode4)
__global__ __launch_bounds__(256) void gemmC_kernel(
    const unsigned short* __restrict__ hu, const unsigned short* __restrict__ w2mur,
    const unsigned short* __restrict__ M2u, const float* __restrict__ b2_mu,
    float* __restrict__ out_user,
    const unsigned short* __restrict__ hm, const unsigned short* __restrict__ w2rmr,
    const unsigned short* __restrict__ M2m, const float* __restrict__ b2_rm,
    float* __restrict__ out_movie) {
  __shared__ unsigned short Alds[128 * 32];
  __shared__ unsigned short Blds[128 * 32];
  if (blockIdx.x < 782) {
    gemm_core<4>(hu, 256, w2mur, 256, 256, M2u, b2_mu, out_user, NU,
                 blockIdx.x, 0, Alds, Blds);
  } else {
    gemm_core<4>(hm, 256, w2rmr, 256, 256, M2m, b2_rm, out_movie, NM,
                 blockIdx.x - 782, 0, Alds, Blds);
  }
}

extern "C" void kernel_launch(void* const* d_in, const int* in_sizes, int n_in,
                              void* d_out, int out_size, void* d_ws, size_t ws_size,
                              hipStream_t stream) {
  const float* x_user  = (const float*)d_in[0];
  const float* x_movie = (const float*)d_in[1];
  const int*   esrc    = (const int*)d_in[2];
  const int*   edst    = (const int*)d_in[3];
  const float* w1_rm_l = (const float*)d_in[4];
  const float* b1_rm   = (const float*)d_in[5];
  const float* w1_rm_r = (const float*)d_in[6];
  const float* w1_mu_l = (const float*)d_in[7];
  const float* b1_mu   = (const float*)d_in[8];
  const float* w1_mu_r = (const float*)d_in[9];
  const float* w2_rm_l = (const float*)d_in[10];
  const float* b2_rm   = (const float*)d_in[11];
  const float* w2_rm_r = (const float*)d_in[12];
  const float* w2_mu_l = (const float*)d_in[13];
  const float* b2_mu   = (const float*)d_in[14];
  const float* w2_mu_r = (const float*)d_in[15];

  if (ws_size < 214240008ull) return;
  char* wsb = (char*)d_ws;
  unsigned short* xu_bf  = (unsigned short*)(wsb + 0);           // 100000x128
  unsigned short* xmcat  = (unsigned short*)(wsb + 25600000);    // 20000x544: [M1m | x_movie | 0]
  unsigned short* hm_bf  = (unsigned short*)(wsb + 47360000);    // 20000x256
  unsigned short* t1_bf  = (unsigned short*)(wsb + 57600000);    // 20000x256
  unsigned short* M2m_bf = (unsigned short*)(wsb + 57600000);    // 20000x128 (aliases t1, dead)
  unsigned short* t2_bf  = (unsigned short*)(wsb + 67840000);    // 20000x128
  unsigned short* M1u_bf = (unsigned short*)(wsb + 72960000);    // 100000x256
  unsigned short* hul_bf = (unsigned short*)(wsb + 72960000);    // 100000x128 (aliases M1u, dead)
  unsigned short* M2u_bf = (unsigned short*)(wsb + 124160000);   // 100000x128
  unsigned short* hu_bf  = (unsigned short*)(wsb + 149760000);   // 100000x256
  int* rank_m = (int*)(wsb + 149760000);                         // 1M ints (dead before hu write)
  int* rank_u = (int*)(wsb + 153760000);                         // 1M ints
  unsigned short* wts = (unsigned short*)(wsb + 200960000);
  unsigned short* wL1_t   = wts;            // 512x544
  unsigned short* w1mur_t = wts + 278528;   // 256x128
  unsigned short* wL2u_t  = wts + 311296;   // 256x256 [w2_rm_l | w2_mu_r]
  unsigned short* w2mul_t = wts + 376832;   // 128x256
  unsigned short* w2rmr_t = wts + 409600;   // 128x256
  int* iw    = (int*)(wsb + 201844736);
  int* deg_m = iw;                 // 20000
  int* deg_u = iw + 20000;         // 100000 (contiguous with deg_m: one memset)
  int* off_m = iw + 120000;        // 20001 (+pad to 140004)
  int* off_u = iw + 140004;        // 100001 (+pad to 240008)
  int* csr_m = iw + 240008;        // 1M
  int* csr_u = iw + 1240008;       // 1M

  float* out_movie = (float*)d_out;
  float* out_user  = (float*)d_out + (size_t)NM * OUTDIM;

  // 1) zero degree arrays, 2) fused hist + prep
  hipMemsetAsync(deg_m, 0, 120000 * sizeof(int), stream);
  hist_prep_kernel<<<HISTB + (PRC + 255) / 256, 256, 0, stream>>>(
      esrc, edst, deg_u, deg_m, rank_u, rank_m,
      x_user, xu_bf, x_movie, xmcat,
      w1_rm_l, w1_rm_r, w1_mu_l, w1_mu_r, w2_rm_l, w2_mu_r, w2_mu_l, w2_rm_r,
      wL1_t, w1mur_t, wL2u_t, w2mul_t, w2rmr_t);

  // 3) scans
  scan2_kernel<<<2, 1024, 0, stream>>>(deg_m, off_m, deg_u, off_u);

  // 4) fused: CSR fill + t1 = x_movie @ w1_mu_l
  fill_t1_kernel<<<FILLB + 314, 256, 0, stream>>>(
      esrc, edst, rank_m, rank_u, off_m, off_u, csr_m, csr_u,
      xmcat + 128, wL1_t + 256 * XMW + 128, t1_bf);

  // 5) gatherA: M1u (t1 -> M1u) || M1m (xu -> xmcat[:,0:128))
  gatherA_kernel<<<12500 + 1250, 256, 0, stream>>>(
      t1_bf, off_u, csr_u, M1u_bf, xu_bf, off_m, csr_m, xmcat);

  // 6) gemmA: h_movie || h_user
  gemmA_kernel<<<314 + 1564, 256, 0, stream>>>(
      xmcat, wL1_t, b1_rm, hm_bf, xu_bf, w1mur_t, M1u_bf, b1_mu, hu_bf);

  // 7) gemmB: hul = hu@w2rml || t2 = hm@w2mul
  gemmB_kernel<<<782 + 157, 256, 0, stream>>>(
      hu_bf, wL2u_t, hul_bf, hm_bf, w2mul_t, t2_bf);

  // 8) gatherB: M2u (t2, csr_u) || M2m (hul, csr_m)
  gatherB_kernel<<<6250 + 1250, 256, 0, stream>>>(
      t2_bf, off_u, csr_u, M2u_bf, hul_bf, off_m, csr_m, M2m_bf);

  // 9) gemmC: out_user || out_movie
  gemmC_kernel<<<782 + 157, 256, 0, stream>>>(
      hu_bf, wL2u_t + 128 * 256, M2u_bf, b2_mu, out_user,
      hm_bf, w2rmr_t, M2m_bf, b2_rm, out_movie);
}

// Round 9
// 463.108 us; speedup vs baseline: 23.2746x; 1.0270x over previous
//
#include <hip/hip_runtime.h>
#include <cstddef>
#include <cstdint>

#define E_EDGES 1000000
#define NU 100000
#define NM 20000
#define DU 128
#define DM 404      // D_MOVIE
#define HIDDIM 256
#define OUTDIM 128
#define XMW 544     // concat row width: 128 + 404 + 12 pad  (17*32)

typedef short bf8_t __attribute__((ext_vector_type(8)));   // 8 bf16 (4 VGPR) MFMA A/B frag
typedef float f32x4 __attribute__((ext_vector_type(4)));   // MFMA C/D frag
typedef unsigned short u16x8 __attribute__((ext_vector_type(8)));  // 16B bf16 vector

__device__ __forceinline__ float b2f(unsigned short u) {
  union { unsigned int i; float f; } x; x.i = ((unsigned int)u) << 16; return x.f;
}
__device__ __forceinline__ unsigned short f2b(float f) {
  union { float f; unsigned int i; } x; x.f = f;
  unsigned int r = x.i + 0x7FFFu + ((x.i >> 16) & 1u);  // RTNE
  return (unsigned short)(r >> 16);
}

#define GLOAD_LDS16(gp, lp)                                                      \
  __builtin_amdgcn_global_load_lds(                                              \
      (const __attribute__((address_space(1))) unsigned int*)(gp),               \
      (__attribute__((address_space(3))) unsigned int*)(lp), 16, 0, 0)

// ================= hist: degree histogram + per-edge rank (4 edges/thread) =================
#define HISTB 977
__global__ __launch_bounds__(256) void hist_kernel(
    const int* __restrict__ esrc, const int* __restrict__ edst,
    int* __restrict__ deg_u, int* __restrict__ deg_m,
    int* __restrict__ rank_u, int* __restrict__ rank_m) {
  int e4 = blockIdx.x * 256 + threadIdx.x;
  if (e4 >= E_EDGES / 4) return;
  int4 s4 = reinterpret_cast<const int4*>(esrc)[e4];
  int4 d4 = reinterpret_cast<const int4*>(edst)[e4];
  int4 ru, rm;
  ru.x = atomicAdd(&deg_u[s4.x], 1);
  ru.y = atomicAdd(&deg_u[s4.y], 1);
  ru.z = atomicAdd(&deg_u[s4.z], 1);
  ru.w = atomicAdd(&deg_u[s4.w], 1);
  rm.x = atomicAdd(&deg_m[d4.x], 1);
  rm.y = atomicAdd(&deg_m[d4.y], 1);
  rm.z = atomicAdd(&deg_m[d4.z], 1);
  rm.w = atomicAdd(&deg_m[d4.w], 1);
  reinterpret_cast<int4*>(rank_u)[e4] = ru;
  reinterpret_cast<int4*>(rank_m)[e4] = rm;
}

// ================= scan core (256 threads, 16 items/thread) =================
__device__ __forceinline__ void scan_core_256(const int* __restrict__ deg,
                                              int* __restrict__ off, int n,
                                              int* wsum) {
  const int tid = threadIdx.x;
  const int lane = tid & 63;
  const int w = tid >> 6;  // 4 waves
  int carry = 0;
  for (int base = 0; base < n; base += 4096) {
    const int i0 = base + tid * 16;
    int v[16];
    int s = 0;
    if (i0 + 16 <= n) {
#pragma unroll
      for (int q = 0; q < 4; ++q) {
        int4 t4 = *reinterpret_cast<const int4*>(&deg[i0 + q * 4]);
        v[q * 4 + 0] = t4.x; v[q * 4 + 1] = t4.y; v[q * 4 + 2] = t4.z; v[q * 4 + 3] = t4.w;
      }
    } else {
#pragma unroll
      for (int j = 0; j < 16; ++j) v[j] = (i0 + j < n) ? deg[i0 + j] : 0;
    }
#pragma unroll
    for (int j = 0; j < 16; ++j) s += v[j];
    int ws_ = s;
#pragma unroll
    for (int d = 1; d < 64; d <<= 1) {
      int t = __shfl_up(ws_, d, 64);
      if (lane >= d) ws_ += t;
    }
    if (lane == 63) wsum[w] = ws_;
    __syncthreads();
    int woff = 0, ctot = 0;
#pragma unroll
    for (int j = 0; j < 4; ++j) {
      int x = wsum[j];
      if (j < w) woff += x;
      ctot += x;
    }
    int ex = carry + woff + ws_ - s;
    if (i0 + 16 <= n) {
      int o[16];
#pragma unroll
      for (int j = 0; j < 16; ++j) { o[j] = ex; ex += v[j]; }
#pragma unroll
      for (int q = 0; q < 4; ++q)
        *reinterpret_cast<int4*>(&off[i0 + q * 4]) =
            make_int4(o[q * 4], o[q * 4 + 1], o[q * 4 + 2], o[q * 4 + 3]);
    } else {
#pragma unroll
      for (int j = 0; j < 16; ++j) {
        if (i0 + j < n) off[i0 + j] = ex;
        ex += v[j];
      }
    }
    carry += ctot;
    __syncthreads();
  }
  if (tid == 0) off[n] = carry;
}

// ================= scanprep: blocks 0,1 = scans; blocks >=2 = prep =================
#define PRA 3200000
#define PRB 5280000
#define PRC 5722368
__global__ __launch_bounds__(256) void scanprep_kernel(
    const int* __restrict__ deg_m, int* __restrict__ off_m,
    const int* __restrict__ deg_u, int* __restrict__ off_u,
    const float* __restrict__ x_user, unsigned short* __restrict__ xu_bf,
    const float* __restrict__ x_movie, unsigned short* __restrict__ xmcat,
    const float* __restrict__ w1_rm_l, const float* __restrict__ w1_rm_r,
    const float* __restrict__ w1_mu_l, const float* __restrict__ w1_mu_r,
    const float* __restrict__ w2_rm_l, const float* __restrict__ w2_mu_r,
    const float* __restrict__ w2_mu_l, const float* __restrict__ w2_rm_r,
    unsigned short* __restrict__ wL1, unsigned short* __restrict__ w1mur,
    unsigned short* __restrict__ wL2u, unsigned short* __restrict__ w2mul,
    unsigned short* __restrict__ w2rmr) {
  __shared__ int wsum[4];
  if (blockIdx.x == 0) { scan_core_256(deg_m, off_m, NM, wsum); return; }
  if (blockIdx.x == 1) { scan_core_256(deg_u, off_u, NU, wsum); return; }
  int j = (blockIdx.x - 2) * 256 + threadIdx.x;
  if (j < PRA) {
    float4 v = reinterpret_cast<const float4*>(x_user)[j];
    ushort4 o;
    o.x = f2b(v.x); o.y = f2b(v.y); o.z = f2b(v.z); o.w = f2b(v.w);
    reinterpret_cast<ushort4*>(xu_bf)[j] = o;
  } else if (j < PRB) {
    int q = j - PRA;
    int row = q / 104, c4 = (q % 104) * 4;  // c4 in [0,416)
    ushort4 o;
    if (c4 < DM) {
      float4 v = *reinterpret_cast<const float4*>(&x_movie[(size_t)row * DM + c4]);
      o.x = f2b(v.x); o.y = f2b(v.y); o.z = f2b(v.z); o.w = f2b(v.w);
    } else {
      o.x = o.y = o.z = o.w = 0;
    }
    *reinterpret_cast<ushort4*>(&xmcat[(size_t)row * XMW + 128 + c4]) = o;
  } else if (j < PRC) {
    int q = j - PRB;
    if (q < 278528) {
      int n = q / 544, k = q % 544;
      float v = 0.f;
      if (n < 256) {
        if (k < 128) v = w1_rm_l[(size_t)k * 256 + n];
        else if (k < 532) v = w1_rm_r[(size_t)(k - 128) * 256 + n];
      } else {
        if (k >= 128 && k < 532) v = w1_mu_l[(size_t)(k - 128) * 256 + (n - 256)];
      }
      wL1[q] = f2b(v);
    } else if (q < 311296) {
      int p = q - 278528; int n = p / 128, k = p % 128;
      w1mur[p] = f2b(w1_mu_r[(size_t)k * 256 + n]);
    } else if (q < 376832) {
      int p = q - 311296; int n = p / 256, k = p % 256;
      float v = (n < 128) ? w2_rm_l[(size_t)k * 128 + n] : w2_mu_r[(size_t)k * 128 + (n - 128)];
      wL2u[p] = f2b(v);
    } else if (q < 409600) {
      int p = q - 376832; int n = p / 256, k = p % 256;
      w2mul[p] = f2b(w2_mu_l[(size_t)k * 128 + n]);
    } else {
      int p = q - 409600; int n = p / 256, k = p % 256;
      w2rmr[p] = f2b(w2_rm_r[(size_t)k * 128 + n]);
    }
  }
}

// ================= shared GEMM core =================
// MODE 0: bias+relu, bf16 out s256       MODE 1: elem(s256)+bias+relu, bf16 out s256
// MODE 2: plain bf16 out s128            MODE 5: plain bf16 out s256
// MODE 6: f32 out s128 = acc + bias
template <int MODE>
__device__ __forceinline__ void gemm_core(
    const unsigned short* __restrict__ A, int lda,
    const unsigned short* __restrict__ Bt, int ldb, int K,
    const unsigned short* __restrict__ elem, const float* __restrict__ bias,
    void* __restrict__ outA, int M, int bx, int by,
    unsigned short* Alds, unsigned short* Blds) {
  const int tid = threadIdx.x;
  const int w = tid >> 6, l = tid & 63;
  const int row0 = bx * 128;
  const int col0 = by * 128;
  const int wr = w >> 1, wc = w & 1;

  f32x4 acc[4][4] = {};

  int ar0 = row0 + w * 32 + (l >> 2);
  int ar1 = ar0 + 16;
  if (ar0 >= M) ar0 = M - 1;
  if (ar1 >= M) ar1 = M - 1;
  const size_t aoff0 = (size_t)ar0 * lda + (l & 3) * 8;
  const size_t aoff1 = (size_t)ar1 * lda + (l & 3) * 8;
  const int nr0 = col0 + w * 32 + (l >> 2);
  const size_t boff0 = (size_t)nr0 * ldb + (l & 3) * 8;
  const size_t boff1 = (size_t)(nr0 + 16) * ldb + (l & 3) * 8;
  unsigned short* aldsb = &Alds[w * 1024];
  unsigned short* bldsb = &Blds[w * 1024];

  for (int k0 = 0; k0 < K; k0 += 32) {
    GLOAD_LDS16(A + aoff0 + k0, aldsb);
    GLOAD_LDS16(A + aoff1 + k0, aldsb + 512);
    GLOAD_LDS16(Bt + boff0 + k0, bldsb);
    GLOAD_LDS16(Bt + boff1 + k0, bldsb + 512);
    __syncthreads();
    bf8_t af[4], bfr[4];
#pragma unroll
    for (int mi = 0; mi < 4; ++mi)
      af[mi] = *reinterpret_cast<const bf8_t*>(&Alds[(wr * 64 + mi * 16 + (l & 15)) * 32 + (l >> 4) * 8]);
#pragma unroll
    for (int nj = 0; nj < 4; ++nj)
      bfr[nj] = *reinterpret_cast<const bf8_t*>(&Blds[(wc * 64 + nj * 16 + (l & 15)) * 32 + (l >> 4) * 8]);
#pragma unroll
    for (int mi = 0; mi < 4; ++mi)
#pragma unroll
      for (int nj = 0; nj < 4; ++nj)
        acc[mi][nj] = __builtin_amdgcn_mfma_f32_16x16x32_bf16(af[mi], bfr[nj], acc[mi][nj], 0, 0, 0);
    __syncthreads();
  }

#pragma unroll
  for (int mi = 0; mi < 4; ++mi) {
    const int rbase = row0 + wr * 64 + mi * 16 + ((l >> 4) << 2);
#pragma unroll
    for (int nj = 0; nj < 4; ++nj) {
      const int col = col0 + wc * 64 + nj * 16 + (l & 15);
      float bb = 0.0f;
      if constexpr (MODE == 0 || MODE == 1 || MODE == 6) bb = bias[col];
#pragma unroll
      for (int r = 0; r < 4; ++r) {
        const int row = rbase + r;
        if (row >= M) continue;
        float v = acc[mi][nj][r] + bb;
        if constexpr (MODE == 1) v += b2f(elem[(size_t)row * 256 + col]);
        if constexpr (MODE == 0 || MODE == 1) v = fmaxf(v, 0.0f);
        if constexpr (MODE == 0 || MODE == 1 || MODE == 5) {
          ((unsigned short*)outA)[(size_t)row * 256 + col] = f2b(v);
        } else if constexpr (MODE == 2) {
          ((unsigned short*)outA)[(size_t)row * 128 + col] = f2b(v);
        } else {
          ((float*)outA)[(size_t)row * 128 + col] = v;
        }
      }
    }
  }
}

// ================= fused: CSR fill (blocks [0,FILLB)) + t1 GEMM (rest) =================
#define FILLB 977
__global__ __launch_bounds__(256) void fill_t1_kernel(
    const int* __restrict__ esrc, const int* __restrict__ edst,
    const int* __restrict__ rank_m, const int* __restrict__ rank_u,
    const int* __restrict__ off_m, const int* __restrict__ off_u,
    int* __restrict__ csr_m, int* __restrict__ csr_u,
    const unsigned short* __restrict__ A, const unsigned short* __restrict__ Bt,
    unsigned short* __restrict__ t1) {
  __shared__ unsigned short Alds[128 * 32];
  __shared__ unsigned short Blds[128 * 32];
  if (blockIdx.x < FILLB) {
    int e4 = blockIdx.x * 256 + threadIdx.x;
    if (e4 >= E_EDGES / 4) return;
    int4 s4 = reinterpret_cast<const int4*>(esrc)[e4];
    int4 d4 = reinterpret_cast<const int4*>(edst)[e4];
    int4 rm = reinterpret_cast<const int4*>(rank_m)[e4];
    int4 ru = reinterpret_cast<const int4*>(rank_u)[e4];
    csr_m[off_m[d4.x] + rm.x] = s4.x;
    csr_m[off_m[d4.y] + rm.y] = s4.y;
    csr_m[off_m[d4.z] + rm.z] = s4.z;
    csr_m[off_m[d4.w] + rm.w] = s4.w;
    csr_u[off_u[s4.x] + ru.x] = d4.x;
    csr_u[off_u[s4.y] + ru.y] = d4.y;
    csr_u[off_u[s4.z] + ru.z] = d4.z;
    csr_u[off_u[s4.w] + ru.w] = d4.w;
    return;
  }
  const int bi = blockIdx.x - FILLB;  // 0..313
  gemm_core<5>(A, XMW, Bt, XMW, 416, nullptr, nullptr, t1, NM,
               bi % 157, bi / 157, Alds, Blds);
}

// ================= gather core (bf16 out) =================
template <int D>
__device__ __forceinline__ void gather_core(
    const unsigned short* __restrict__ table, const int* __restrict__ off,
    const int* __restrict__ idx, unsigned short* __restrict__ out,
    int n, int ostride, int bi) {
  constexpr int LPN = D / 8;
  constexpr int NPB = 256 / LPN;
  const int t = threadIdx.x;
  const int g = t / LPN;
  const int cl = (t % LPN) * 8;
  const int node = bi * NPB + g;
  if (node >= n) return;
  const int beg = off[node], end = off[node + 1];
  const float sc = 1.0f / fmaxf((float)(end - beg), 1.0f);
  float a[8] = {0, 0, 0, 0, 0, 0, 0, 0}, b[8] = {0, 0, 0, 0, 0, 0, 0, 0};
  int p = beg;
  for (; p + 3 < end; p += 4) {
    const int r0 = idx[p], r1 = idx[p + 1], r2 = idx[p + 2], r3 = idx[p + 3];
    u16x8 v0 = *reinterpret_cast<const u16x8*>(&table[(size_t)r0 * D + cl]);
    u16x8 v1 = *reinterpret_cast<const u16x8*>(&table[(size_t)r1 * D + cl]);
    u16x8 v2 = *reinterpret_cast<const u16x8*>(&table[(size_t)r2 * D + cl]);
    u16x8 v3 = *reinterpret_cast<const u16x8*>(&table[(size_t)r3 * D + cl]);
#pragma unroll
    for (int j = 0; j < 8; ++j) { a[j] += b2f(v0[j]); b[j] += b2f(v1[j]); }
#pragma unroll
    for (int j = 0; j < 8; ++j) { a[j] += b2f(v2[j]); b[j] += b2f(v3[j]); }
  }
  for (; p < end; ++p) {
    const int r0 = idx[p];
    u16x8 v0 = *reinterpret_cast<const u16x8*>(&table[(size_t)r0 * D + cl]);
#pragma unroll
    for (int j = 0; j < 8; ++j) a[j] += b2f(v0[j]);
  }
  u16x8 o;
#pragma unroll
  for (int j = 0; j < 8; ++j) o[j] = f2b((a[j] + b[j]) * sc);
  *reinterpret_cast<u16x8*>(&out[(size_t)node * ostride + cl]) = o;
}

// ================= gather-add (D=128, f32 += mean into out) =================
__device__ __forceinline__ void gather_add_f32_128(
    const unsigned short* __restrict__ table, const int* __restrict__ off,
    const int* __restrict__ idx, float* __restrict__ out, int n, int bi) {
  const int t = threadIdx.x;
  const int g = t >> 4;          // 16 nodes/block
  const int cl = (t & 15) * 8;   // 8 floats/lane
  const int node = bi * 16 + g;
  if (node >= n) return;
  const int beg = off[node], end = off[node + 1];
  const float sc = 1.0f / fmaxf((float)(end - beg), 1.0f);
  float a[8] = {0, 0, 0, 0, 0, 0, 0, 0}, b[8] = {0, 0, 0, 0, 0, 0, 0, 0};
  int p = beg;
  for (; p + 3 < end; p += 4) {
    const int r0 = idx[p], r1 = idx[p + 1], r2 = idx[p + 2], r3 = idx[p + 3];
    u16x8 v0 = *reinterpret_cast<const u16x8*>(&table[(size_t)r0 * 128 + cl]);
    u16x8 v1 = *reinterpret_cast<const u16x8*>(&table[(size_t)r1 * 128 + cl]);
    u16x8 v2 = *reinterpret_cast<const u16x8*>(&table[(size_t)r2 * 128 + cl]);
    u16x8 v3 = *reinterpret_cast<const u16x8*>(&table[(size_t)r3 * 128 + cl]);
#pragma unroll
    for (int j = 0; j < 8; ++j) { a[j] += b2f(v0[j]); b[j] += b2f(v1[j]); }
#pragma unroll
    for (int j = 0; j < 8; ++j) { a[j] += b2f(v2[j]); b[j] += b2f(v3[j]); }
  }
  for (; p < end; ++p) {
    const int r0 = idx[p];
    u16x8 v0 = *reinterpret_cast<const u16x8*>(&table[(size_t)r0 * 128 + cl]);
#pragma unroll
    for (int j = 0; j < 8; ++j) a[j] += b2f(v0[j]);
  }
  float* dst = &out[(size_t)node * 128 + cl];
  float4 o0 = *reinterpret_cast<const float4*>(dst);
  float4 o1 = *reinterpret_cast<const float4*>(dst + 4);
  o0.x += (a[0] + b[0]) * sc; o0.y += (a[1] + b[1]) * sc;
  o0.z += (a[2] + b[2]) * sc; o0.w += (a[3] + b[3]) * sc;
  o1.x += (a[4] + b[4]) * sc; o1.y += (a[5] + b[5]) * sc;
  o1.z += (a[6] + b[6]) * sc; o1.w += (a[7] + b[7]) * sc;
  *reinterpret_cast<float4*>(dst) = o0;
  *reinterpret_cast<float4*>(dst + 4) = o1;
}

// gatherA: blocks [0,12500) -> M1u (D=256); rest 1250 -> M1m (D=128 -> xmcat)
__global__ __launch_bounds__(256) void gatherA_kernel(
    const unsigned short* __restrict__ t1, const int* __restrict__ off_u,
    const int* __restrict__ csr_u, unsigned short* __restrict__ M1u,
    const unsigned short* __restrict__ xu, const int* __restrict__ off_m,
    const int* __restrict__ csr_m, unsigned short* __restrict__ xmcat) {
  if (blockIdx.x < 12500)
    gather_core<256>(t1, off_u, csr_u, M1u, NU, 256, blockIdx.x);
  else
    gather_core<128>(xu, off_m, csr_m, xmcat, NM, XMW, blockIdx.x - 12500);
}

// gemmA: blocks [0,314) mode0 h_movie; rest 1564 mode1 h_user
__global__ __launch_bounds__(256) void gemmA_kernel(
    const unsigned short* __restrict__ xmcat, const unsigned short* __restrict__ wL1,
    const float* __restrict__ b1_rm, unsigned short* __restrict__ hm,
    const unsigned short* __restrict__ xu, const unsigned short* __restrict__ w1mur,
    const unsigned short* __restrict__ M1u, const float* __restrict__ b1_mu,
    unsigned short* __restrict__ hu) {
  __shared__ unsigned short Alds[128 * 32];
  __shared__ unsigned short Blds[128 * 32];
  if (blockIdx.x < 314) {
    int bi = blockIdx.x;
    gemm_core<0>(xmcat, XMW, wL1, XMW, XMW, nullptr, b1_rm, hm, NM,
                 bi % 157, bi / 157, Alds, Blds);
  } else {
    int bi = blockIdx.x - 314;
    gemm_core<1>(xu, 128, w1mur, 128, 128, M1u, b1_mu, hu, NU,
                 bi % 782, bi / 782, Alds, Blds);
  }
}

// gemmB2: [0,782) hul; [782,939) t2; [939,1721) pre_user -> out_user; [1721,1878) pre_movie
__global__ __launch_bounds__(256) void gemmB2_kernel(
    const unsigned short* __restrict__ hu, const unsigned short* __restrict__ w2rml,
    unsigned short* __restrict__ hul,
    const unsigned short* __restrict__ hm, const unsigned short* __restrict__ w2mul,
    unsigned short* __restrict__ t2,
    const unsigned short* __restrict__ w2mur, const float* __restrict__ b2_mu,
    float* __restrict__ out_user,
    const unsigned short* __restrict__ w2rmr, const float* __restrict__ b2_rm,
    float* __restrict__ out_movie) {
  __shared__ unsigned short Alds[128 * 32];
  __shared__ unsigned short Blds[128 * 32];
  if (blockIdx.x < 782) {
    gemm_core<2>(hu, 256, w2rml, 256, 256, nullptr, nullptr, hul, NU,
                 blockIdx.x, 0, Alds, Blds);
  } else if (blockIdx.x < 939) {
    gemm_core<2>(hm, 256, w2mul, 256, 256, nullptr, nullptr, t2, NM,
                 blockIdx.x - 782, 0, Alds, Blds);
  } else if (blockIdx.x < 1721) {
    gemm_core<6>(hu, 256, w2mur, 256, 256, nullptr, b2_mu, out_user, NU,
                 blockIdx.x - 939, 0, Alds, Blds);
  } else {
    gemm_core<6>(hm, 256, w2rmr, 256, 256, nullptr, b2_rm, out_movie, NM,
                 blockIdx.x - 1721, 0, Alds, Blds);
  }
}

// gatherBC: blocks [0,6250) M2u-mean += out_user; rest 1250: M2m-mean += out_movie
__global__ __launch_bounds__(256) void gatherBC_kernel(
    const unsigned short* __restrict__ t2, const int* __restrict__ off_u,
    const int* __restrict__ csr_u, float* __restrict__ out_user,
    const unsigned short* __restrict__ hul, const int* __restrict__ off_m,
    const int* __restrict__ csr_m, float* __restrict__ out_movie) {
  if (blockIdx.x < 6250)
    gather_add_f32_128(t2, off_u, csr_u, out_user, NU, blockIdx.x);
  else
    gather_add_f32_128(hul, off_m, csr_m, out_movie, NM, blockIdx.x - 6250);
}

extern "C" void kernel_launch(void* const* d_in, const int* in_sizes, int n_in,
                              void* d_out, int out_size, void* d_ws, size_t ws_size,
                              hipStream_t stream) {
  const float* x_user  = (const float*)d_in[0];
  const float* x_movie = (const float*)d_in[1];
  const int*   esrc    = (const int*)d_in[2];
  const int*   edst    = (const int*)d_in[3];
  const float* w1_rm_l = (const float*)d_in[4];
  const float* b1_rm   = (const float*)d_in[5];
  const float* w1_rm_r = (const float*)d_in[6];
  const float* w1_mu_l = (const float*)d_in[7];
  const float* b1_mu   = (const float*)d_in[8];
  const float* w1_mu_r = (const float*)d_in[9];
  const float* w2_rm_l = (const float*)d_in[10];
  const float* b2_rm   = (const float*)d_in[11];
  const float* w2_rm_r = (const float*)d_in[12];
  const float* w2_mu_l = (const float*)d_in[13];
  const float* b2_mu   = (const float*)d_in[14];
  const float* w2_mu_r = (const float*)d_in[15];

  if (ws_size < 214240008ull) return;
  char* wsb = (char*)d_ws;
  unsigned short* xu_bf  = (unsigned short*)(wsb + 0);           // 100000x128
  unsigned short* xmcat  = (unsigned short*)(wsb + 25600000);    // 20000x544
  unsigned short* hm_bf  = (unsigned short*)(wsb + 47360000);    // 20000x256
  unsigned short* t1_bf  = (unsigned short*)(wsb + 57600000);    // 20000x256
  unsigned short* t2_bf  = (unsigned short*)(wsb + 67840000);    // 20000x128
  unsigned short* M1u_bf = (unsigned short*)(wsb + 72960000);    // 100000x256
  unsigned short* hul_bf = (unsigned short*)(wsb + 72960000);    // 100000x128 (aliases M1u, dead)
  unsigned short* hu_bf  = (unsigned short*)(wsb + 149760000);   // 100000x256
  int* rank_m = (int*)(wsb + 149760000);                         // 1M ints (dead before hu write)
  int* rank_u = (int*)(wsb + 153760000);                         // 1M ints
  unsigned short* wts = (unsigned short*)(wsb + 200960000);
  unsigned short* wL1_t   = wts;            // 512x544
  unsigned short* w1mur_t = wts + 278528;   // 256x128
  unsigned short* wL2u_t  = wts + 311296;   // 256x256 [w2_rm_l | w2_mu_r]
  unsigned short* w2mul_t = wts + 376832;   // 128x256
  unsigned short* w2rmr_t = wts + 409600;   // 128x256
  int* iw    = (int*)(wsb + 201844736);
  int* deg_m = iw;                 // 20000
  int* deg_u = iw + 20000;         // 100000 (contiguous: one memset)
  int* off_m = iw + 120000;        // 20001 (+pad)
  int* off_u = iw + 140004;        // 100001 (+pad)
  int* csr_m = iw + 240008;        // 1M
  int* csr_u = iw + 1240008;       // 1M

  float* out_movie = (float*)d_out;
  float* out_user  = (float*)d_out + (size_t)NM * OUTDIM;

  // 1) zero degrees; 2) hist (atomic-bound)
  hipMemsetAsync(deg_m, 0, 120000 * sizeof(int), stream);
  hist_kernel<<<HISTB, 256, 0, stream>>>(esrc, edst, deg_u, deg_m, rank_u, rank_m);

  // 3) scans (2 blocks) || prep conversions+transposes (rest)
  scanprep_kernel<<<2 + (PRC + 255) / 256, 256, 0, stream>>>(
      deg_m, off_m, deg_u, off_u,
      x_user, xu_bf, x_movie, xmcat,
      w1_rm_l, w1_rm_r, w1_mu_l, w1_mu_r, w2_rm_l, w2_mu_r, w2_mu_l, w2_rm_r,
      wL1_t, w1mur_t, wL2u_t, w2mul_t, w2rmr_t);

  // 4) CSR fill || t1 = x_movie @ w1_mu_l
  fill_t1_kernel<<<FILLB + 314, 256, 0, stream>>>(
      esrc, edst, rank_m, rank_u, off_m, off_u, csr_m, csr_u,
      xmcat + 128, wL1_t + 256 * XMW + 128, t1_bf);

  // 5) gatherA: M1u || M1m
  gatherA_kernel<<<12500 + 1250, 256, 0, stream>>>(
      t1_bf, off_u, csr_u, M1u_bf, xu_bf, off_m, csr_m, xmcat);

  // 6) gemmA: h_movie || h_user
  gemmA_kernel<<<314 + 1564, 256, 0, stream>>>(
      xmcat, wL1_t, b1_rm, hm_bf, xu_bf, w1mur_t, M1u_bf, b1_mu, hu_bf);

  // 7) gemmB2: hul || t2 || pre_user || pre_movie
  gemmB2_kernel<<<1878, 256, 0, stream>>>(
      hu_bf, wL2u_t, hul_bf, hm_bf, w2mul_t, t2_bf,
      wL2u_t + 128 * 256, b2_mu, out_user, w2rmr_t, b2_rm, out_movie);

  // 8) gatherBC: += mean into outputs (f32, exclusive per node)
  gatherBC_kernel<<<6250 + 1250, 256, 0, stream>>>(
      t2_bf, off_u, csr_u, out_user, hul_bf, off_m, csr_m, out_movie);
}

// Round 10
// 448.923 us; speedup vs baseline: 24.0100x; 1.0316x over previous
//
#include <hip/hip_runtime.h>
#include <cstddef>
#include <cstdint>

#define E_EDGES 1000000
#define NU 100000
#define NM 20000
#define DU 128
#define DM 404      // D_MOVIE
#define HIDDIM 256
#define OUTDIM 128
#define XMW 544     // concat row width: 128 + 404 + 12 pad  (17*32)

typedef short bf8_t __attribute__((ext_vector_type(8)));   // 8 bf16 (4 VGPR) MFMA A/B frag
typedef float f32x4 __attribute__((ext_vector_type(4)));   // MFMA C/D frag
typedef unsigned short u16x8 __attribute__((ext_vector_type(8)));  // 16B bf16 vector

__device__ __forceinline__ float b2f(unsigned short u) {
  union { unsigned int i; float f; } x; x.i = ((unsigned int)u) << 16; return x.f;
}
__device__ __forceinline__ unsigned short f2b(float f) {
  union { float f; unsigned int i; } x; x.f = f;
  unsigned int r = x.i + 0x7FFFu + ((x.i >> 16) & 1u);  // RTNE
  return (unsigned short)(r >> 16);
}

#define GLOAD_LDS16(gp, lp)                                                      \
  __builtin_amdgcn_global_load_lds(                                              \
      (const __attribute__((address_space(1))) unsigned int*)(gp),               \
      (__attribute__((address_space(3))) unsigned int*)(lp), 16, 0, 0)

// ================= hist: degree histogram + per-edge rank (4 edges/thread) =================
#define HISTB 977
__global__ __launch_bounds__(256) void hist_kernel(
    const int* __restrict__ esrc, const int* __restrict__ edst,
    int* __restrict__ deg_u, int* __restrict__ deg_m,
    int* __restrict__ rank_u, int* __restrict__ rank_m) {
  int e4 = blockIdx.x * 256 + threadIdx.x;
  if (e4 >= E_EDGES / 4) return;
  int4 s4 = reinterpret_cast<const int4*>(esrc)[e4];
  int4 d4 = reinterpret_cast<const int4*>(edst)[e4];
  int4 ru, rm;
  ru.x = atomicAdd(&deg_u[s4.x], 1);
  ru.y = atomicAdd(&deg_u[s4.y], 1);
  ru.z = atomicAdd(&deg_u[s4.z], 1);
  ru.w = atomicAdd(&deg_u[s4.w], 1);
  rm.x = atomicAdd(&deg_m[d4.x], 1);
  rm.y = atomicAdd(&deg_m[d4.y], 1);
  rm.z = atomicAdd(&deg_m[d4.z], 1);
  rm.w = atomicAdd(&deg_m[d4.w], 1);
  reinterpret_cast<int4*>(rank_u)[e4] = ru;
  reinterpret_cast<int4*>(rank_m)[e4] = rm;
}

// ================= scan core (256 threads, 16 items/thread) =================
__device__ __forceinline__ void scan_core_256(const int* __restrict__ deg,
                                              int* __restrict__ off, int n,
                                              int* wsum) {
  const int tid = threadIdx.x;
  const int lane = tid & 63;
  const int w = tid >> 6;  // 4 waves
  int carry = 0;
  for (int base = 0; base < n; base += 4096) {
    const int i0 = base + tid * 16;
    int v[16];
    int s = 0;
    if (i0 + 16 <= n) {
#pragma unroll
      for (int q = 0; q < 4; ++q) {
        int4 t4 = *reinterpret_cast<const int4*>(&deg[i0 + q * 4]);
        v[q * 4 + 0] = t4.x; v[q * 4 + 1] = t4.y; v[q * 4 + 2] = t4.z; v[q * 4 + 3] = t4.w;
      }
    } else {
#pragma unroll
      for (int j = 0; j < 16; ++j) v[j] = (i0 + j < n) ? deg[i0 + j] : 0;
    }
#pragma unroll
    for (int j = 0; j < 16; ++j) s += v[j];
    int ws_ = s;
#pragma unroll
    for (int d = 1; d < 64; d <<= 1) {
      int t = __shfl_up(ws_, d, 64);
      if (lane >= d) ws_ += t;
    }
    if (lane == 63) wsum[w] = ws_;
    __syncthreads();
    int woff = 0, ctot = 0;
#pragma unroll
    for (int j = 0; j < 4; ++j) {
      int x = wsum[j];
      if (j < w) woff += x;
      ctot += x;
    }
    int ex = carry + woff + ws_ - s;
    if (i0 + 16 <= n) {
      int o[16];
#pragma unroll
      for (int j = 0; j < 16; ++j) { o[j] = ex; ex += v[j]; }
#pragma unroll
      for (int q = 0; q < 4; ++q)
        *reinterpret_cast<int4*>(&off[i0 + q * 4]) =
            make_int4(o[q * 4], o[q * 4 + 1], o[q * 4 + 2], o[q * 4 + 3]);
    } else {
#pragma unroll
      for (int j = 0; j < 16; ++j) {
        if (i0 + j < n) off[i0 + j] = ex;
        ex += v[j];
      }
    }
    carry += ctot;
    __syncthreads();
  }
  if (tid == 0) off[n] = carry;
}

// ================= scanprep: blocks 0,1 = scans; blocks >=2 = prep =================
#define PRA 3200000
#define PRB 5280000
#define PRC 5722368
__global__ __launch_bounds__(256) void scanprep_kernel(
    const int* __restrict__ deg_m, int* __restrict__ off_m,
    const int* __restrict__ deg_u, int* __restrict__ off_u,
    const float* __restrict__ x_user, unsigned short* __restrict__ xu_bf,
    const float* __restrict__ x_movie, unsigned short* __restrict__ xmcat,
    const float* __restrict__ w1_rm_l, const float* __restrict__ w1_rm_r,
    const float* __restrict__ w1_mu_l, const float* __restrict__ w1_mu_r,
    const float* __restrict__ w2_rm_l, const float* __restrict__ w2_mu_r,
    const float* __restrict__ w2_mu_l, const float* __restrict__ w2_rm_r,
    unsigned short* __restrict__ wL1, unsigned short* __restrict__ w1mur,
    unsigned short* __restrict__ wL2u, unsigned short* __restrict__ w2mul,
    unsigned short* __restrict__ w2rmr) {
  __shared__ int wsum[4];
  if (blockIdx.x == 0) { scan_core_256(deg_m, off_m, NM, wsum); return; }
  if (blockIdx.x == 1) { scan_core_256(deg_u, off_u, NU, wsum); return; }
  int j = (blockIdx.x - 2) * 256 + threadIdx.x;
  if (j < PRA) {
    float4 v = reinterpret_cast<const float4*>(x_user)[j];
    ushort4 o;
    o.x = f2b(v.x); o.y = f2b(v.y); o.z = f2b(v.z); o.w = f2b(v.w);
    reinterpret_cast<ushort4*>(xu_bf)[j] = o;
  } else if (j < PRB) {
    int q = j - PRA;
    int row = q / 104, c4 = (q % 104) * 4;  // c4 in [0,416)
    ushort4 o;
    if (c4 < DM) {
      float4 v = *reinterpret_cast<const float4*>(&x_movie[(size_t)row * DM + c4]);
      o.x = f2b(v.x); o.y = f2b(v.y); o.z = f2b(v.z); o.w = f2b(v.w);
    } else {
      o.x = o.y = o.z = o.w = 0;
    }
    *reinterpret_cast<ushort4*>(&xmcat[(size_t)row * XMW + 128 + c4]) = o;
  } else if (j < PRC) {
    int q = j - PRB;
    if (q < 278528) {
      int n = q / 544, k = q % 544;
      float v = 0.f;
      if (n < 256) {
        if (k < 128) v = w1_rm_l[(size_t)k * 256 + n];
        else if (k < 532) v = w1_rm_r[(size_t)(k - 128) * 256 + n];
      } else {
        if (k >= 128 && k < 532) v = w1_mu_l[(size_t)(k - 128) * 256 + (n - 256)];
      }
      wL1[q] = f2b(v);
    } else if (q < 311296) {
      int p = q - 278528; int n = p / 128, k = p % 128;
      w1mur[p] = f2b(w1_mu_r[(size_t)k * 256 + n]);
    } else if (q < 376832) {
      int p = q - 311296; int n = p / 256, k = p % 256;
      float v = (n < 128) ? w2_rm_l[(size_t)k * 128 + n] : w2_mu_r[(size_t)k * 128 + (n - 128)];
      wL2u[p] = f2b(v);
    } else if (q < 409600) {
      int p = q - 376832; int n = p / 256, k = p % 256;
      w2mul[p] = f2b(w2_mu_l[(size_t)k * 128 + n]);
    } else {
      int p = q - 409600; int n = p / 256, k = p % 256;
      w2rmr[p] = f2b(w2_rm_r[(size_t)k * 128 + n]);
    }
  }
}

// ================= shared GEMM core =================
// MODE 0: bias+relu, bf16 out s256       MODE 1: elem(s256)+bias+relu, bf16 out s256
// MODE 2: plain bf16 out s128            MODE 5: plain bf16 out s256
// MODE 6: f32 out s128 = acc + bias
template <int MODE>
__device__ __forceinline__ void gemm_core(
    const unsigned short* __restrict__ A, int lda,
    const unsigned short* __restrict__ Bt, int ldb, int K,
    const unsigned short* __restrict__ elem, const float* __restrict__ bias,
    void* __restrict__ outA, int M, int bx, int by,
    unsigned short* Alds, unsigned short* Blds) {
  const int tid = threadIdx.x;
  const int w = tid >> 6, l = tid & 63;
  const int row0 = bx * 128;
  const int col0 = by * 128;
  const int wr = w >> 1, wc = w & 1;

  f32x4 acc[4][4] = {};

  int ar0 = row0 + w * 32 + (l >> 2);
  int ar1 = ar0 + 16;
  if (ar0 >= M) ar0 = M - 1;
  if (ar1 >= M) ar1 = M - 1;
  const size_t aoff0 = (size_t)ar0 * lda + (l & 3) * 8;
  const size_t aoff1 = (size_t)ar1 * lda + (l & 3) * 8;
  const int nr0 = col0 + w * 32 + (l >> 2);
  const size_t boff0 = (size_t)nr0 * ldb + (l & 3) * 8;
  const size_t boff1 = (size_t)(nr0 + 16) * ldb + (l & 3) * 8;
  unsigned short* aldsb = &Alds[w * 1024];
  unsigned short* bldsb = &Blds[w * 1024];

  for (int k0 = 0; k0 < K; k0 += 32) {
    GLOAD_LDS16(A + aoff0 + k0, aldsb);
    GLOAD_LDS16(A + aoff1 + k0, aldsb + 512);
    GLOAD_LDS16(Bt + boff0 + k0, bldsb);
    GLOAD_LDS16(Bt + boff1 + k0, bldsb + 512);
    __syncthreads();
    bf8_t af[4], bfr[4];
#pragma unroll
    for (int mi = 0; mi < 4; ++mi)
      af[mi] = *reinterpret_cast<const bf8_t*>(&Alds[(wr * 64 + mi * 16 + (l & 15)) * 32 + (l >> 4) * 8]);
#pragma unroll
    for (int nj = 0; nj < 4; ++nj)
      bfr[nj] = *reinterpret_cast<const bf8_t*>(&Blds[(wc * 64 + nj * 16 + (l & 15)) * 32 + (l >> 4) * 8]);
#pragma unroll
    for (int mi = 0; mi < 4; ++mi)
#pragma unroll
      for (int nj = 0; nj < 4; ++nj)
        acc[mi][nj] = __builtin_amdgcn_mfma_f32_16x16x32_bf16(af[mi], bfr[nj], acc[mi][nj], 0, 0, 0);
    __syncthreads();
  }

#pragma unroll
  for (int mi = 0; mi < 4; ++mi) {
    const int rbase = row0 + wr * 64 + mi * 16 + ((l >> 4) << 2);
#pragma unroll
    for (int nj = 0; nj < 4; ++nj) {
      const int col = col0 + wc * 64 + nj * 16 + (l & 15);
      float bb = 0.0f;
      if constexpr (MODE == 0 || MODE == 1 || MODE == 6) bb = bias[col];
#pragma unroll
      for (int r = 0; r < 4; ++r) {
        const int row = rbase + r;
        if (row >= M) continue;
        float v = acc[mi][nj][r] + bb;
        if constexpr (MODE == 1) v += b2f(elem[(size_t)row * 256 + col]);
        if constexpr (MODE == 0 || MODE == 1) v = fmaxf(v, 0.0f);
        if constexpr (MODE == 0 || MODE == 1 || MODE == 5) {
          ((unsigned short*)outA)[(size_t)row * 256 + col] = f2b(v);
        } else if constexpr (MODE == 2) {
          ((unsigned short*)outA)[(size_t)row * 128 + col] = f2b(v);
        } else {
          ((float*)outA)[(size_t)row * 128 + col] = v;
        }
      }
    }
  }
}

// ================= fused: CSR fill (blocks [0,FILLB)) + t1 GEMM (rest) =================
#define FILLB 977
__global__ __launch_bounds__(256) void fill_t1_kernel(
    const int* __restrict__ esrc, const int* __restrict__ edst,
    const int* __restrict__ rank_m, const int* __restrict__ rank_u,
    const int* __restrict__ off_m, const int* __restrict__ off_u,
    int* __restrict__ csr_m, int* __restrict__ csr_u,
    const unsigned short* __restrict__ A, const unsigned short* __restrict__ Bt,
    unsigned short* __restrict__ t1) {
  __shared__ unsigned short Alds[128 * 32];
  __shared__ unsigned short Blds[128 * 32];
  if (blockIdx.x < FILLB) {
    int e4 = blockIdx.x * 256 + threadIdx.x;
    if (e4 >= E_EDGES / 4) return;
    int4 s4 = reinterpret_cast<const int4*>(esrc)[e4];
    int4 d4 = reinterpret_cast<const int4*>(edst)[e4];
    int4 rm = reinterpret_cast<const int4*>(rank_m)[e4];
    int4 ru = reinterpret_cast<const int4*>(rank_u)[e4];
    csr_m[off_m[d4.x] + rm.x] = s4.x;
    csr_m[off_m[d4.y] + rm.y] = s4.y;
    csr_m[off_m[d4.z] + rm.z] = s4.z;
    csr_m[off_m[d4.w] + rm.w] = s4.w;
    csr_u[off_u[s4.x] + ru.x] = d4.x;
    csr_u[off_u[s4.y] + ru.y] = d4.y;
    csr_u[off_u[s4.z] + ru.z] = d4.z;
    csr_u[off_u[s4.w] + ru.w] = d4.w;
    return;
  }
  const int bi = blockIdx.x - FILLB;  // 0..313
  gemm_core<5>(A, XMW, Bt, XMW, 416, nullptr, nullptr, t1, NM,
               bi % 157, bi / 157, Alds, Blds);
}

// ================= gather core (full row, bf16 out) =================
template <int D>
__device__ __forceinline__ void gather_core(
    const unsigned short* __restrict__ table, const int* __restrict__ off,
    const int* __restrict__ idx, unsigned short* __restrict__ out,
    int n, int ostride, int bi) {
  constexpr int LPN = D / 8;
  constexpr int NPB = 256 / LPN;
  const int t = threadIdx.x;
  const int g = t / LPN;
  const int cl = (t % LPN) * 8;
  const int node = bi * NPB + g;
  if (node >= n) return;
  const int beg = off[node], end = off[node + 1];
  const float sc = 1.0f / fmaxf((float)(end - beg), 1.0f);
  float a[8] = {0, 0, 0, 0, 0, 0, 0, 0}, b[8] = {0, 0, 0, 0, 0, 0, 0, 0};
  int p = beg;
  for (; p + 3 < end; p += 4) {
    const int r0 = idx[p], r1 = idx[p + 1], r2 = idx[p + 2], r3 = idx[p + 3];
    u16x8 v0 = *reinterpret_cast<const u16x8*>(&table[(size_t)r0 * D + cl]);
    u16x8 v1 = *reinterpret_cast<const u16x8*>(&table[(size_t)r1 * D + cl]);
    u16x8 v2 = *reinterpret_cast<const u16x8*>(&table[(size_t)r2 * D + cl]);
    u16x8 v3 = *reinterpret_cast<const u16x8*>(&table[(size_t)r3 * D + cl]);
#pragma unroll
    for (int j = 0; j < 8; ++j) { a[j] += b2f(v0[j]); b[j] += b2f(v1[j]); }
#pragma unroll
    for (int j = 0; j < 8; ++j) { a[j] += b2f(v2[j]); b[j] += b2f(v3[j]); }
  }
  for (; p < end; ++p) {
    const int r0 = idx[p];
    u16x8 v0 = *reinterpret_cast<const u16x8*>(&table[(size_t)r0 * D + cl]);
#pragma unroll
    for (int j = 0; j < 8; ++j) a[j] += b2f(v0[j]);
  }
  u16x8 o;
#pragma unroll
  for (int j = 0; j < 8; ++j) o[j] = f2b((a[j] + b[j]) * sc);
  *reinterpret_cast<u16x8*>(&out[(size_t)node * ostride + cl]) = o;
}

// ================= gather slice (64 cols = 128B/row, bf16 out) =================
// 8 lanes/node, 32 nodes/block. Table slice (tstride rows x 128B) stays L2-resident.
__device__ __forceinline__ void gather_slice64(
    const unsigned short* __restrict__ table, int tstride,
    const int* __restrict__ off, const int* __restrict__ idx,
    unsigned short* __restrict__ out, int ostride, int n, int col0, int bi) {
  const int t = threadIdx.x;
  const int g = t >> 3;
  const int cl = col0 + (t & 7) * 8;
  const int node = bi * 32 + g;
  if (node >= n) return;
  const int beg = off[node], end = off[node + 1];
  const float sc = 1.0f / fmaxf((float)(end - beg), 1.0f);
  float a[8] = {0, 0, 0, 0, 0, 0, 0, 0}, b[8] = {0, 0, 0, 0, 0, 0, 0, 0};
  int p = beg;
  for (; p + 3 < end; p += 4) {
    const int r0 = idx[p], r1 = idx[p + 1], r2 = idx[p + 2], r3 = idx[p + 3];
    u16x8 v0 = *reinterpret_cast<const u16x8*>(&table[(size_t)r0 * tstride + cl]);
    u16x8 v1 = *reinterpret_cast<const u16x8*>(&table[(size_t)r1 * tstride + cl]);
    u16x8 v2 = *reinterpret_cast<const u16x8*>(&table[(size_t)r2 * tstride + cl]);
    u16x8 v3 = *reinterpret_cast<const u16x8*>(&table[(size_t)r3 * tstride + cl]);
#pragma unroll
    for (int j = 0; j < 8; ++j) { a[j] += b2f(v0[j]); b[j] += b2f(v1[j]); }
#pragma unroll
    for (int j = 0; j < 8; ++j) { a[j] += b2f(v2[j]); b[j] += b2f(v3[j]); }
  }
  for (; p < end; ++p) {
    const int r0 = idx[p];
    u16x8 v0 = *reinterpret_cast<const u16x8*>(&table[(size_t)r0 * tstride + cl]);
#pragma unroll
    for (int j = 0; j < 8; ++j) a[j] += b2f(v0[j]);
  }
  u16x8 o;
#pragma unroll
  for (int j = 0; j < 8; ++j) o[j] = f2b((a[j] + b[j]) * sc);
  *reinterpret_cast<u16x8*>(&out[(size_t)node * ostride + cl]) = o;
}

// ================= gather-add slice (64 cols, f32 += mean) =================
__device__ __forceinline__ void gather_add_slice64(
    const unsigned short* __restrict__ table, int tstride,
    const int* __restrict__ off, const int* __restrict__ idx,
    float* __restrict__ out, int ostride, int n, int col0, int bi) {
  const int t = threadIdx.x;
  const int g = t >> 3;
  const int cl = col0 + (t & 7) * 8;
  const int node = bi * 32 + g;
  if (node >= n) return;
  const int beg = off[node], end = off[node + 1];
  const float sc = 1.0f / fmaxf((float)(end - beg), 1.0f);
  float a[8] = {0, 0, 0, 0, 0, 0, 0, 0}, b[8] = {0, 0, 0, 0, 0, 0, 0, 0};
  int p = beg;
  for (; p + 3 < end; p += 4) {
    const int r0 = idx[p], r1 = idx[p + 1], r2 = idx[p + 2], r3 = idx[p + 3];
    u16x8 v0 = *reinterpret_cast<const u16x8*>(&table[(size_t)r0 * tstride + cl]);
    u16x8 v1 = *reinterpret_cast<const u16x8*>(&table[(size_t)r1 * tstride + cl]);
    u16x8 v2 = *reinterpret_cast<const u16x8*>(&table[(size_t)r2 * tstride + cl]);
    u16x8 v3 = *reinterpret_cast<const u16x8*>(&table[(size_t)r3 * tstride + cl]);
#pragma unroll
    for (int j = 0; j < 8; ++j) { a[j] += b2f(v0[j]); b[j] += b2f(v1[j]); }
#pragma unroll
    for (int j = 0; j < 8; ++j) { a[j] += b2f(v2[j]); b[j] += b2f(v3[j]); }
  }
  for (; p < end; ++p) {
    const int r0 = idx[p];
    u16x8 v0 = *reinterpret_cast<const u16x8*>(&table[(size_t)r0 * tstride + cl]);
#pragma unroll
    for (int j = 0; j < 8; ++j) a[j] += b2f(v0[j]);
  }
  float* dst = &out[(size_t)node * ostride + cl];
  float4 o0 = *reinterpret_cast<const float4*>(dst);
  float4 o1 = *reinterpret_cast<const float4*>(dst + 4);
  o0.x += (a[0] + b[0]) * sc; o0.y += (a[1] + b[1]) * sc;
  o0.z += (a[2] + b[2]) * sc; o0.w += (a[3] + b[3]) * sc;
  o1.x += (a[4] + b[4]) * sc; o1.y += (a[5] + b[5]) * sc;
  o1.z += (a[6] + b[6]) * sc; o1.w += (a[7] + b[7]) * sc;
  *reinterpret_cast<float4*>(dst) = o0;
  *reinterpret_cast<float4*>(dst + 4) = o1;
}

// ================= gather-add full 128 (f32 += mean), 16 nodes/block =================
__device__ __forceinline__ void gather_add_f32_128(
    const unsigned short* __restrict__ table, const int* __restrict__ off,
    const int* __restrict__ idx, float* __restrict__ out, int n, int bi) {
  const int t = threadIdx.x;
  const int g = t >> 4;
  const int cl = (t & 15) * 8;
  const int node = bi * 16 + g;
  if (node >= n) return;
  const int beg = off[node], end = off[node + 1];
  const float sc = 1.0f / fmaxf((float)(end - beg), 1.0f);
  float a[8] = {0, 0, 0, 0, 0, 0, 0, 0}, b[8] = {0, 0, 0, 0, 0, 0, 0, 0};
  int p = beg;
  for (; p + 3 < end; p += 4) {
    const int r0 = idx[p], r1 = idx[p + 1], r2 = idx[p + 2], r3 = idx[p + 3];
    u16x8 v0 = *reinterpret_cast<const u16x8*>(&table[(size_t)r0 * 128 + cl]);
    u16x8 v1 = *reinterpret_cast<const u16x8*>(&table[(size_t)r1 * 128 + cl]);
    u16x8 v2 = *reinterpret_cast<const u16x8*>(&table[(size_t)r2 * 128 + cl]);
    u16x8 v3 = *reinterpret_cast<const u16x8*>(&table[(size_t)r3 * 128 + cl]);
#pragma unroll
    for (int j = 0; j < 8; ++j) { a[j] += b2f(v0[j]); b[j] += b2f(v1[j]); }
#pragma unroll
    for (int j = 0; j < 8; ++j) { a[j] += b2f(v2[j]); b[j] += b2f(v3[j]); }
  }
  for (; p < end; ++p) {
    const int r0 = idx[p];
    u16x8 v0 = *reinterpret_cast<const u16x8*>(&table[(size_t)r0 * 128 + cl]);
#pragma unroll
    for (int j = 0; j < 8; ++j) a[j] += b2f(v0[j]);
  }
  float* dst = &out[(size_t)node * 128 + cl];
  float4 o0 = *reinterpret_cast<const float4*>(dst);
  float4 o1 = *reinterpret_cast<const float4*>(dst + 4);
  o0.x += (a[0] + b[0]) * sc; o0.y += (a[1] + b[1]) * sc;
  o0.z += (a[2] + b[2]) * sc; o0.w += (a[3] + b[3]) * sc;
  o1.x += (a[4] + b[4]) * sc; o1.y += (a[5] + b[5]) * sc;
  o1.z += (a[6] + b[6]) * sc; o1.w += (a[7] + b[7]) * sc;
  *reinterpret_cast<float4*>(dst) = o0;
  *reinterpret_cast<float4*>(dst + 4) = o1;
}

// gatherA: blocks [0,12500): M1u sliced (4 slices x 3125, t1-slice 2.56MB L2-resident);
//          rest 1250: M1m full-width (xu -> xmcat)
__global__ __launch_bounds__(256) void gatherA_kernel(
    const unsigned short* __restrict__ t1, const int* __restrict__ off_u,
    const int* __restrict__ csr_u, unsigned short* __restrict__ M1u,
    const unsigned short* __restrict__ xu, const int* __restrict__ off_m,
    const int* __restrict__ csr_m, unsigned short* __restrict__ xmcat) {
  if (blockIdx.x < 12500) {
    const int s = blockIdx.x / 3125;
    const int bi = blockIdx.x % 3125;
    gather_slice64(t1, 256, off_u, csr_u, M1u, 256, NU, s * 64, bi);
  } else {
    gather_core<128>(xu, off_m, csr_m, xmcat, NM, XMW, blockIdx.x - 12500);
  }
}

// gemmA: blocks [0,314) mode0 h_movie; rest 1564 mode1 h_user
__global__ __launch_bounds__(256) void gemmA_kernel(
    const unsigned short* __restrict__ xmcat, const unsigned short* __restrict__ wL1,
    const float* __restrict__ b1_rm, unsigned short* __restrict__ hm,
    const unsigned short* __restrict__ xu, const unsigned short* __restrict__ w1mur,
    const unsigned short* __restrict__ M1u, const float* __restrict__ b1_mu,
    unsigned short* __restrict__ hu) {
  __shared__ unsigned short Alds[128 * 32];
  __shared__ unsigned short Blds[128 * 32];
  if (blockIdx.x < 314) {
    int bi = blockIdx.x;
    gemm_core<0>(xmcat, XMW, wL1, XMW, XMW, nullptr, b1_rm, hm, NM,
                 bi % 157, bi / 157, Alds, Blds);
  } else {
    int bi = blockIdx.x - 314;
    gemm_core<1>(xu, 128, w1mur, 128, 128, M1u, b1_mu, hu, NU,
                 bi % 782, bi / 782, Alds, Blds);
  }
}

// gemmB2: [0,782) hul; [782,939) t2; [939,1721) pre_user -> out_user; [1721,1878) pre_movie
__global__ __launch_bounds__(256) void gemmB2_kernel(
    const unsigned short* __restrict__ hu, const unsigned short* __restrict__ w2rml,
    unsigned short* __restrict__ hul,
    const unsigned short* __restrict__ hm, const unsigned short* __restrict__ w2mul,
    unsigned short* __restrict__ t2,
    const unsigned short* __restrict__ w2mur, const float* __restrict__ b2_mu,
    float* __restrict__ out_user,
    const unsigned short* __restrict__ w2rmr, const float* __restrict__ b2_rm,
    float* __restrict__ out_movie) {
  __shared__ unsigned short Alds[128 * 32];
  __shared__ unsigned short Blds[128 * 32];
  if (blockIdx.x < 782) {
    gemm_core<2>(hu, 256, w2rml, 256, 256, nullptr, nullptr, hul, NU,
                 blockIdx.x, 0, Alds, Blds);
  } else if (blockIdx.x < 939) {
    gemm_core<2>(hm, 256, w2mul, 256, 256, nullptr, nullptr, t2, NM,
                 blockIdx.x - 782, 0, Alds, Blds);
  } else if (blockIdx.x < 1721) {
    gemm_core<6>(hu, 256, w2mur, 256, 256, nullptr, b2_mu, out_user, NU,
                 blockIdx.x - 939, 0, Alds, Blds);
  } else {
    gemm_core<6>(hm, 256, w2rmr, 256, 256, nullptr, b2_rm, out_movie, NM,
                 blockIdx.x - 1721, 0, Alds, Blds);
  }
}

// gatherBC: blocks [0,6250): M2u sliced (2 slices x 3125, t2-slice 2.56MB) += out_user;
//           rest 1250: M2m full-width += out_movie
__global__ __launch_bounds__(256) void gatherBC_kernel(
    const unsigned short* __restrict__ t2, const int* __restrict__ off_u,
    const int* __restrict__ csr_u, float* __restrict__ out_user,
    const unsigned short* __restrict__ hul, const int* __restrict__ off_m,
    const int* __restrict__ csr_m, float* __restrict__ out_movie) {
  if (blockIdx.x < 6250) {
    const int s = blockIdx.x / 3125;
    const int bi = blockIdx.x % 3125;
    gather_add_slice64(t2, 128, off_u, csr_u, out_user, 128, NU, s * 64, bi);
  } else {
    gather_add_f32_128(hul, off_m, csr_m, out_movie, NM, blockIdx.x - 6250);
  }
}

extern "C" void kernel_launch(void* const* d_in, const int* in_sizes, int n_in,
                              void* d_out, int out_size, void* d_ws, size_t ws_size,
                              hipStream_t stream) {
  const float* x_user  = (const float*)d_in[0];
  const float* x_movie = (const float*)d_in[1];
  const int*   esrc    = (const int*)d_in[2];
  const int*   edst    = (const int*)d_in[3];
  const float* w1_rm_l = (const float*)d_in[4];
  const float* b1_rm   = (const float*)d_in[5];
  const float* w1_rm_r = (const float*)d_in[6];
  const float* w1_mu_l = (const float*)d_in[7];
  const float* b1_mu   = (const float*)d_in[8];
  const float* w1_mu_r = (const float*)d_in[9];
  const float* w2_rm_l = (const float*)d_in[10];
  const float* b2_rm   = (const float*)d_in[11];
  const float* w2_rm_r = (const float*)d_in[12];
  const float* w2_mu_l = (const float*)d_in[13];
  const float* b2_mu   = (const float*)d_in[14];
  const float* w2_mu_r = (const float*)d_in[15];

  if (ws_size < 214240008ull) return;
  char* wsb = (char*)d_ws;
  unsigned short* xu_bf  = (unsigned short*)(wsb + 0);           // 100000x128
  unsigned short* xmcat  = (unsigned short*)(wsb + 25600000);    // 20000x544
  unsigned short* hm_bf  = (unsigned short*)(wsb + 47360000);    // 20000x256
  unsigned short* t1_bf  = (unsigned short*)(wsb + 57600000);    // 20000x256
  unsigned short* t2_bf  = (unsigned short*)(wsb + 67840000);    // 20000x128
  unsigned short* M1u_bf = (unsigned short*)(wsb + 72960000);    // 100000x256
  unsigned short* hul_bf = (unsigned short*)(wsb + 72960000);    // 100000x128 (aliases M1u, dead)
  unsigned short* hu_bf  = (unsigned short*)(wsb + 149760000);   // 100000x256
  int* rank_m = (int*)(wsb + 149760000);                         // 1M ints (dead before hu write)
  int* rank_u = (int*)(wsb + 153760000);                         // 1M ints
  unsigned short* wts = (unsigned short*)(wsb + 200960000);
  unsigned short* wL1_t   = wts;            // 512x544
  unsigned short* w1mur_t = wts + 278528;   // 256x128
  unsigned short* wL2u_t  = wts + 311296;   // 256x256 [w2_rm_l | w2_mu_r]
  unsigned short* w2mul_t = wts + 376832;   // 128x256
  unsigned short* w2rmr_t = wts + 409600;   // 128x256
  int* iw    = (int*)(wsb + 201844736);
  int* deg_m = iw;                 // 20000
  int* deg_u = iw + 20000;         // 100000 (contiguous: one memset)
  int* off_m = iw + 120000;        // 20001 (+pad)
  int* off_u = iw + 140004;        // 100001 (+pad)
  int* csr_m = iw + 240008;        // 1M
  int* csr_u = iw + 1240008;       // 1M

  float* out_movie = (float*)d_out;
  float* out_user  = (float*)d_out + (size_t)NM * OUTDIM;

  // 1) zero degrees; 2) hist (atomic-bound)
  hipMemsetAsync(deg_m, 0, 120000 * sizeof(int), stream);
  hist_kernel<<<HISTB, 256, 0, stream>>>(esrc, edst, deg_u, deg_m, rank_u, rank_m);

  // 3) scans (2 blocks) || prep conversions+transposes (rest)
  scanprep_kernel<<<2 + (PRC + 255) / 256, 256, 0, stream>>>(
      deg_m, off_m, deg_u, off_u,
      x_user, xu_bf, x_movie, xmcat,
      w1_rm_l, w1_rm_r, w1_mu_l, w1_mu_r, w2_rm_l, w2_mu_r, w2_mu_l, w2_rm_r,
      wL1_t, w1mur_t, wL2u_t, w2mul_t, w2rmr_t);

  // 4) CSR fill || t1 = x_movie @ w1_mu_l
  fill_t1_kernel<<<FILLB + 314, 256, 0, stream>>>(
      esrc, edst, rank_m, rank_u, off_m, off_u, csr_m, csr_u,
      xmcat + 128, wL1_t + 256 * XMW + 128, t1_bf);

  // 5) gatherA: M1u sliced (L2-resident slices) || M1m
  gatherA_kernel<<<12500 + 1250, 256, 0, stream>>>(
      t1_bf, off_u, csr_u, M1u_bf, xu_bf, off_m, csr_m, xmcat);

  // 6) gemmA: h_movie || h_user
  gemmA_kernel<<<314 + 1564, 256, 0, stream>>>(
      xmcat, wL1_t, b1_rm, hm_bf, xu_bf, w1mur_t, M1u_bf, b1_mu, hu_bf);

  // 7) gemmB2: hul || t2 || pre_user || pre_movie
  gemmB2_kernel<<<1878, 256, 0, stream>>>(
      hu_bf, wL2u_t, hul_bf, hm_bf, w2mul_t, t2_bf,
      wL2u_t + 128 * 256, b2_mu, out_user, w2rmr_t, b2_rm, out_movie);

  // 8) gatherBC: += mean into outputs (f32, exclusive per node)
  gatherBC_kernel<<<6250 + 1250, 256, 0, stream>>>(
      t2_bf, off_u, csr_u, out_user, hul_bf, off_m, csr_m, out_movie);
}

// Round 11
// 403.189 us; speedup vs baseline: 26.7335x; 1.1134x over previous
//
#include <hip/hip_runtime.h>
#include <cstddef>
#include <cstdint>

#define E_EDGES 1000000
#define NU 100000
#define NM 20000
#define DU 128
#define DM 404      // D_MOVIE
#define HIDDIM 256
#define OUTDIM 128
#define XMW 544     // concat row width: 128 + 404 + 12 pad  (17*32)

// CSR build (bucketed counting sort, no global atomics)
#define NBLK 64          // edge chunks
#define EPB 15625        // edges per chunk (1M/64 exact)
#define NBKT_M 313       // movie buckets of 64 ids (last: 32)
#define NBKT_U 196       // user buckets of 512 ids (last: 160)

typedef short bf8_t __attribute__((ext_vector_type(8)));   // 8 bf16 (4 VGPR) MFMA A/B frag
typedef float f32x4 __attribute__((ext_vector_type(4)));   // MFMA C/D frag
typedef unsigned short u16x8 __attribute__((ext_vector_type(8)));  // 16B bf16 vector

__device__ __forceinline__ float b2f(unsigned short u) {
  union { unsigned int i; float f; } x; x.i = ((unsigned int)u) << 16; return x.f;
}
__device__ __forceinline__ unsigned short f2b(float f) {
  union { float f; unsigned int i; } x; x.f = f;
  unsigned int r = x.i + 0x7FFFu + ((x.i >> 16) & 1u);  // RTNE
  return (unsigned short)(r >> 16);
}

#define GLOAD_LDS16(gp, lp)                                                      \
  __builtin_amdgcn_global_load_lds(                                              \
      (const __attribute__((address_space(1))) unsigned int*)(gp),               \
      (__attribute__((address_space(3))) unsigned int*)(lp), 16, 0, 0)

// ================= passA: bucket counts (blocks 0..127) + prep (rest) =================
#define PRA 3200000
#define PRB 5280000
#define PRC 5722368
__global__ __launch_bounds__(256) void passA_kernel(
    const int* __restrict__ esrc, const int* __restrict__ edst,
    int* __restrict__ cnt_m, int* __restrict__ cnt_u,
    const float* __restrict__ x_user, unsigned short* __restrict__ xu_bf,
    const float* __restrict__ x_movie, unsigned short* __restrict__ xmcat,
    const float* __restrict__ w1_rm_l, const float* __restrict__ w1_rm_r,
    const float* __restrict__ w1_mu_l, const float* __restrict__ w1_mu_r,
    const float* __restrict__ w2_rm_l, const float* __restrict__ w2_mu_r,
    const float* __restrict__ w2_mu_l, const float* __restrict__ w2_rm_r,
    unsigned short* __restrict__ wL1, unsigned short* __restrict__ w1mur,
    unsigned short* __restrict__ wL2u, unsigned short* __restrict__ w2mul,
    unsigned short* __restrict__ w2rmr) {
  __shared__ int hist[NBKT_M];  // 313 >= 196
  const int bx = blockIdx.x;
  if (bx < NBLK) {
    // movie-side bucket count for chunk bx
    for (int i = threadIdx.x; i < NBKT_M; i += 256) hist[i] = 0;
    __syncthreads();
    const int base = bx * EPB, end = base + EPB;
    for (int i = base + threadIdx.x; i < end; i += 256)
      atomicAdd(&hist[edst[i] >> 6], 1);
    __syncthreads();
    for (int i = threadIdx.x; i < NBKT_M; i += 256)
      cnt_m[bx * NBKT_M + i] = hist[i];
    return;
  }
  if (bx < 2 * NBLK) {
    const int b = bx - NBLK;
    for (int i = threadIdx.x; i < NBKT_U; i += 256) hist[i] = 0;
    __syncthreads();
    const int base = b * EPB, end = base + EPB;
    for (int i = base + threadIdx.x; i < end; i += 256)
      atomicAdd(&hist[esrc[i] >> 9], 1);
    __syncthreads();
    for (int i = threadIdx.x; i < NBKT_U; i += 256)
      cnt_u[b * NBKT_U + i] = hist[i];
    return;
  }
  int j = (bx - 2 * NBLK) * 256 + threadIdx.x;
  if (j < PRA) {
    float4 v = reinterpret_cast<const float4*>(x_user)[j];
    ushort4 o;
    o.x = f2b(v.x); o.y = f2b(v.y); o.z = f2b(v.z); o.w = f2b(v.w);
    reinterpret_cast<ushort4*>(xu_bf)[j] = o;
  } else if (j < PRB) {
    int q = j - PRA;
    int row = q / 104, c4 = (q % 104) * 4;  // c4 in [0,416)
    ushort4 o;
    if (c4 < DM) {
      float4 v = *reinterpret_cast<const float4*>(&x_movie[(size_t)row * DM + c4]);
      o.x = f2b(v.x); o.y = f2b(v.y); o.z = f2b(v.z); o.w = f2b(v.w);
    } else {
      o.x = o.y = o.z = o.w = 0;
    }
    *reinterpret_cast<ushort4*>(&xmcat[(size_t)row * XMW + 128 + c4]) = o;
  } else if (j < PRC) {
    int q = j - PRB;
    if (q < 278528) {
      int n = q / 544, k = q % 544;
      float v = 0.f;
      if (n < 256) {
        if (k < 128) v = w1_rm_l[(size_t)k * 256 + n];
        else if (k < 532) v = w1_rm_r[(size_t)(k - 128) * 256 + n];
      } else {
        if (k >= 128 && k < 532) v = w1_mu_l[(size_t)(k - 128) * 256 + (n - 256)];
      }
      wL1[q] = f2b(v);
    } else if (q < 311296) {
      int p = q - 278528; int n = p / 128, k = p % 128;
      w1mur[p] = f2b(w1_mu_r[(size_t)k * 256 + n]);
    } else if (q < 376832) {
      int p = q - 311296; int n = p / 256, k = p % 256;
      float v = (n < 128) ? w2_rm_l[(size_t)k * 128 + n] : w2_mu_r[(size_t)k * 128 + (n - 128)];
      wL2u[p] = f2b(v);
    } else if (q < 409600) {
      int p = q - 376832; int n = p / 256, k = p % 256;
      w2mul[p] = f2b(w2_mu_l[(size_t)k * 128 + n]);
    } else {
      int p = q - 409600; int n = p / 256, k = p % 256;
      w2rmr[p] = f2b(w2_rm_r[(size_t)k * 128 + n]);
    }
  }
}

// ================= scanAB: block 0 = movie side, block 1 = user side =================
// base[b][B] = bo[B] + sum_{b'<b} cnt[b'][B];  bo = exclusive scan of bucket totals
__global__ __launch_bounds__(256) void scanAB_kernel(
    int* __restrict__ cnt_m, int* __restrict__ base_m, int* __restrict__ bo_m,
    int* __restrict__ cnt_u, int* __restrict__ base_u, int* __restrict__ bo_u) {
  const int NB = blockIdx.x ? NBKT_U : NBKT_M;
  const int* cnt = blockIdx.x ? cnt_u : cnt_m;
  int* basep = blockIdx.x ? base_u : base_m;
  int* bo = blockIdx.x ? bo_u : bo_m;
  __shared__ int tot[NBKT_M];
  for (int B = threadIdx.x; B < NB; B += 256) {
    int s = 0;
    for (int b = 0; b < NBLK; ++b) {
      int c = cnt[b * NB + B];
      basep[b * NB + B] = s;  // within-bucket prefix (chunk-major)
      s += c;
    }
    tot[B] = s;
  }
  __syncthreads();
  if (threadIdx.x < 64) {
    const int lane = threadIdx.x;
    int carry = 0;
    for (int c0 = 0; c0 < NB; c0 += 64) {
      int v = (c0 + lane < NB) ? tot[c0 + lane] : 0;
      int s = v;
#pragma unroll
      for (int d = 1; d < 64; d <<= 1) {
        int t = __shfl_up(s, d, 64);
        if (lane >= d) s += t;
      }
      if (c0 + lane < NB) bo[c0 + lane] = carry + s - v;
      carry += __shfl(s, 63, 64);
    }
    if (lane == 0) bo[NB] = carry;
  }
  __syncthreads();
  for (int B = threadIdx.x; B < NB; B += 256) {
    const int b0 = bo[B];
    for (int b = 0; b < NBLK; ++b) basep[b * NB + B] += b0;
  }
}

// ================= shared GEMM core =================
// MODE 0: bias+relu, bf16 out s256       MODE 1: elem(s256)+bias+relu, bf16 out s256
// MODE 2: plain bf16 out s128            MODE 5: plain bf16 out s256
// MODE 6: f32 out s128 = acc + bias
template <int MODE>
__device__ __forceinline__ void gemm_core(
    const unsigned short* __restrict__ A, int lda,
    const unsigned short* __restrict__ Bt, int ldb, int K,
    const unsigned short* __restrict__ elem, const float* __restrict__ bias,
    void* __restrict__ outA, int M, int bx, int by,
    unsigned short* Alds, unsigned short* Blds) {
  const int tid = threadIdx.x;
  const int w = tid >> 6, l = tid & 63;
  const int row0 = bx * 128;
  const int col0 = by * 128;
  const int wr = w >> 1, wc = w & 1;

  f32x4 acc[4][4] = {};

  int ar0 = row0 + w * 32 + (l >> 2);
  int ar1 = ar0 + 16;
  if (ar0 >= M) ar0 = M - 1;
  if (ar1 >= M) ar1 = M - 1;
  const size_t aoff0 = (size_t)ar0 * lda + (l & 3) * 8;
  const size_t aoff1 = (size_t)ar1 * lda + (l & 3) * 8;
  const int nr0 = col0 + w * 32 + (l >> 2);
  const size_t boff0 = (size_t)nr0 * ldb + (l & 3) * 8;
  const size_t boff1 = (size_t)(nr0 + 16) * ldb + (l & 3) * 8;
  unsigned short* aldsb = &Alds[w * 1024];
  unsigned short* bldsb = &Blds[w * 1024];

  for (int k0 = 0; k0 < K; k0 += 32) {
    GLOAD_LDS16(A + aoff0 + k0, aldsb);
    GLOAD_LDS16(A + aoff1 + k0, aldsb + 512);
    GLOAD_LDS16(Bt + boff0 + k0, bldsb);
    GLOAD_LDS16(Bt + boff1 + k0, bldsb + 512);
    __syncthreads();
    bf8_t af[4], bfr[4];
#pragma unroll
    for (int mi = 0; mi < 4; ++mi)
      af[mi] = *reinterpret_cast<const bf8_t*>(&Alds[(wr * 64 + mi * 16 + (l & 15)) * 32 + (l >> 4) * 8]);
#pragma unroll
    for (int nj = 0; nj < 4; ++nj)
      bfr[nj] = *reinterpret_cast<const bf8_t*>(&Blds[(wc * 64 + nj * 16 + (l & 15)) * 32 + (l >> 4) * 8]);
#pragma unroll
    for (int mi = 0; mi < 4; ++mi)
#pragma unroll
      for (int nj = 0; nj < 4; ++nj)
        acc[mi][nj] = __builtin_amdgcn_mfma_f32_16x16x32_bf16(af[mi], bfr[nj], acc[mi][nj], 0, 0, 0);
    __syncthreads();
  }

#pragma unroll
  for (int mi = 0; mi < 4; ++mi) {
    const int rbase = row0 + wr * 64 + mi * 16 + ((l >> 4) << 2);
#pragma unroll
    for (int nj = 0; nj < 4; ++nj) {
      const int col = col0 + wc * 64 + nj * 16 + (l & 15);
      float bb = 0.0f;
      if constexpr (MODE == 0 || MODE == 1 || MODE == 6) bb = bias[col];
#pragma unroll
      for (int r = 0; r < 4; ++r) {
        const int row = rbase + r;
        if (row >= M) continue;
        float v = acc[mi][nj][r] + bb;
        if constexpr (MODE == 1) v += b2f(elem[(size_t)row * 256 + col]);
        if constexpr (MODE == 0 || MODE == 1) v = fmaxf(v, 0.0f);
        if constexpr (MODE == 0 || MODE == 1 || MODE == 5) {
          ((unsigned short*)outA)[(size_t)row * 256 + col] = f2b(v);
        } else if constexpr (MODE == 2) {
          ((unsigned short*)outA)[(size_t)row * 128 + col] = f2b(v);
        } else {
          ((float*)outA)[(size_t)row * 128 + col] = v;
        }
      }
    }
  }
}

// ================= passB: bucket-scatter (blocks 0..127) + t1 GEMM (rest) =================
__global__ __launch_bounds__(256) void passB_kernel(
    const int* __restrict__ esrc, const int* __restrict__ edst,
    const int* __restrict__ base_m, const int* __restrict__ base_u,
    int* __restrict__ ebuf_m, int* __restrict__ ebuf_u,
    const unsigned short* __restrict__ A, const unsigned short* __restrict__ Bt,
    unsigned short* __restrict__ t1) {
  __shared__ unsigned short Alds[128 * 32];
  __shared__ unsigned short Blds[128 * 32];
  const int bx = blockIdx.x;
  if (bx < NBLK) {
    int* cur = (int*)Alds;  // 313 ints
    for (int i = threadIdx.x; i < NBKT_M; i += 256) cur[i] = base_m[bx * NBKT_M + i];
    __syncthreads();
    const int base = bx * EPB, end = base + EPB;
    for (int i = base + threadIdx.x; i < end; i += 256) {
      const int d = edst[i], s = esrc[i];
      const int pos = atomicAdd(&cur[d >> 6], 1);
      ebuf_m[pos] = (s << 6) | (d & 63);  // s < 2^17 -> fits
    }
    return;
  }
  if (bx < 2 * NBLK) {
    const int b = bx - NBLK;
    int* cur = (int*)Alds;  // 196 ints
    for (int i = threadIdx.x; i < NBKT_U; i += 256) cur[i] = base_u[b * NBKT_U + i];
    __syncthreads();
    const int base = b * EPB, end = base + EPB;
    for (int i = base + threadIdx.x; i < end; i += 256) {
      const int d = edst[i], s = esrc[i];
      const int pos = atomicAdd(&cur[s >> 9], 1);
      ebuf_u[pos] = (d << 9) | (s & 511);  // d < 2^15 -> fits
    }
    return;
  }
  const int bi = bx - 2 * NBLK;  // 0..313
  gemm_core<5>(A, XMW, Bt, XMW, 416, nullptr, nullptr, t1, NM,
               bi % 157, bi / 157, Alds, Blds);
}

// ================= passC: per-bucket CSR + off (movie [0,313), user [313,509)) =================
__global__ __launch_bounds__(256) void passC_kernel(
    const int* __restrict__ ebuf_m, const int* __restrict__ bo_m,
    int* __restrict__ off_m, int* __restrict__ csr_m,
    const int* __restrict__ ebuf_u, const int* __restrict__ bo_u,
    int* __restrict__ off_u, int* __restrict__ csr_u) {
  __shared__ int hist[512];
  const int bx = blockIdx.x;
  if (bx < NBKT_M) {
    const int B = bx;
    const int lo = bo_m[B], hi = bo_m[B + 1];
    const int nbin = (NM - B * 64 < 64) ? (NM - B * 64) : 64;
    for (int i = threadIdx.x; i < 64; i += 256) hist[i] = 0;
    __syncthreads();
    for (int i = lo + threadIdx.x; i < hi; i += 256)
      atomicAdd(&hist[ebuf_m[i] & 63], 1);
    __syncthreads();
    if (threadIdx.x < 64) {
      const int lane = threadIdx.x;
      const int v = hist[lane];
      int s = v;
#pragma unroll
      for (int d = 1; d < 64; d <<= 1) {
        int t = __shfl_up(s, d, 64);
        if (lane >= d) s += t;
      }
      const int ex = s - v;
      if (lane < nbin) off_m[B * 64 + lane] = lo + ex;
      if (B == NBKT_M - 1 && lane == 0) off_m[NM] = hi;
      hist[lane] = ex;  // becomes cursor
    }
    __syncthreads();
    for (int i = lo + threadIdx.x; i < hi; i += 256) {
      const int p = ebuf_m[i];
      const int pos = atomicAdd(&hist[p & 63], 1);
      csr_m[lo + pos] = p >> 6;
    }
    return;
  }
  // user side
  const int B = bx - NBKT_M;
  const int lo = bo_u[B], hi = bo_u[B + 1];
  const int nbin = (NU - B * 512 < 512) ? (NU - B * 512) : 512;
  for (int i = threadIdx.x; i < 512; i += 256) hist[i] = 0;
  __syncthreads();
  for (int i = lo + threadIdx.x; i < hi; i += 256)
    atomicAdd(&hist[ebuf_u[i] & 511], 1);
  __syncthreads();
  if (threadIdx.x < 64) {
    const int lane = threadIdx.x;
    int carry = 0;
    for (int c0 = 0; c0 < 512; c0 += 64) {
      const int v = hist[c0 + lane];
      int s = v;
#pragma unroll
      for (int d = 1; d < 64; d <<= 1) {
        int t = __shfl_up(s, d, 64);
        if (lane >= d) s += t;
      }
      const int ex = carry + s - v;
      if (c0 + lane < nbin) off_u[B * 512 + c0 + lane] = lo + ex;
      hist[c0 + lane] = ex;  // cursor (overwrites count after it's consumed)
      carry += __shfl(s, 63, 64);
    }
    if (B == NBKT_U - 1 && lane == 0) off_u[NU] = hi;
  }
  __syncthreads();
  for (int i = lo + threadIdx.x; i < hi; i += 256) {
    const int p = ebuf_u[i];
    const int pos = atomicAdd(&hist[p & 511], 1);
    csr_u[lo + pos] = p >> 9;
  }
}

// ================= gather core (full row, bf16 out) =================
template <int D>
__device__ __forceinline__ void gather_core(
    const unsigned short* __restrict__ table, const int* __restrict__ off,
    const int* __restrict__ idx, unsigned short* __restrict__ out,
    int n, int ostride, int bi) {
  constexpr int LPN = D / 8;
  constexpr int NPB = 256 / LPN;
  const int t = threadIdx.x;
  const int g = t / LPN;
  const int cl = (t % LPN) * 8;
  const int node = bi * NPB + g;
  if (node >= n) return;
  const int beg = off[node], end = off[node + 1];
  const float sc = 1.0f / fmaxf((float)(end - beg), 1.0f);
  float a[8] = {0, 0, 0, 0, 0, 0, 0, 0}, b[8] = {0, 0, 0, 0, 0, 0, 0, 0};
  int p = beg;
  for (; p + 3 < end; p += 4) {
    const int r0 = idx[p], r1 = idx[p + 1], r2 = idx[p + 2], r3 = idx[p + 3];
    u16x8 v0 = *reinterpret_cast<const u16x8*>(&table[(size_t)r0 * D + cl]);
    u16x8 v1 = *reinterpret_cast<const u16x8*>(&table[(size_t)r1 * D + cl]);
    u16x8 v2 = *reinterpret_cast<const u16x8*>(&table[(size_t)r2 * D + cl]);
    u16x8 v3 = *reinterpret_cast<const u16x8*>(&table[(size_t)r3 * D + cl]);
#pragma unroll
    for (int j = 0; j < 8; ++j) { a[j] += b2f(v0[j]); b[j] += b2f(v1[j]); }
#pragma unroll
    for (int j = 0; j < 8; ++j) { a[j] += b2f(v2[j]); b[j] += b2f(v3[j]); }
  }
  for (; p < end; ++p) {
    const int r0 = idx[p];
    u16x8 v0 = *reinterpret_cast<const u16x8*>(&table[(size_t)r0 * D + cl]);
#pragma unroll
    for (int j = 0; j < 8; ++j) a[j] += b2f(v0[j]);
  }
  u16x8 o;
#pragma unroll
  for (int j = 0; j < 8; ++j) o[j] = f2b((a[j] + b[j]) * sc);
  *reinterpret_cast<u16x8*>(&out[(size_t)node * ostride + cl]) = o;
}

// ================= gather slice (64 cols = 128B/row, bf16 out) =================
__device__ __forceinline__ void gather_slice64(
    const unsigned short* __restrict__ table, int tstride,
    const int* __restrict__ off, const int* __restrict__ idx,
    unsigned short* __restrict__ out, int ostride, int n, int col0, int bi) {
  const int t = threadIdx.x;
  const int g = t >> 3;
  const int cl = col0 + (t & 7) * 8;
  const int node = bi * 32 + g;
  if (node >= n) return;
  const int beg = off[node], end = off[node + 1];
  const float sc = 1.0f / fmaxf((float)(end - beg), 1.0f);
  float a[8] = {0, 0, 0, 0, 0, 0, 0, 0}, b[8] = {0, 0, 0, 0, 0, 0, 0, 0};
  int p = beg;
  for (; p + 3 < end; p += 4) {
    const int r0 = idx[p], r1 = idx[p + 1], r2 = idx[p + 2], r3 = idx[p + 3];
    u16x8 v0 = *reinterpret_cast<const u16x8*>(&table[(size_t)r0 * tstride + cl]);
    u16x8 v1 = *reinterpret_cast<const u16x8*>(&table[(size_t)r1 * tstride + cl]);
    u16x8 v2 = *reinterpret_cast<const u16x8*>(&table[(size_t)r2 * tstride + cl]);
    u16x8 v3 = *reinterpret_cast<const u16x8*>(&table[(size_t)r3 * tstride + cl]);
#pragma unroll
    for (int j = 0; j < 8; ++j) { a[j] += b2f(v0[j]); b[j] += b2f(v1[j]); }
#pragma unroll
    for (int j = 0; j < 8; ++j) { a[j] += b2f(v2[j]); b[j] += b2f(v3[j]); }
  }
  for (; p < end; ++p) {
    const int r0 = idx[p];
    u16x8 v0 = *reinterpret_cast<const u16x8*>(&table[(size_t)r0 * tstride + cl]);
#pragma unroll
    for (int j = 0; j < 8; ++j) a[j] += b2f(v0[j]);
  }
  u16x8 o;
#pragma unroll
  for (int j = 0; j < 8; ++j) o[j] = f2b((a[j] + b[j]) * sc);
  *reinterpret_cast<u16x8*>(&out[(size_t)node * ostride + cl]) = o;
}

// ================= gather-add slice (64 cols, f32 += mean) =================
__device__ __forceinline__ void gather_add_slice64(
    const unsigned short* __restrict__ table, int tstride,
    const int* __restrict__ off, const int* __restrict__ idx,
    float* __restrict__ out, int ostride, int n, int col0, int bi) {
  const int t = threadIdx.x;
  const int g = t >> 3;
  const int cl = col0 + (t & 7) * 8;
  const int node = bi * 32 + g;
  if (node >= n) return;
  const int beg = off[node], end = off[node + 1];
  const float sc = 1.0f / fmaxf((float)(end - beg), 1.0f);
  float a[8] = {0, 0, 0, 0, 0, 0, 0, 0}, b[8] = {0, 0, 0, 0, 0, 0, 0, 0};
  int p = beg;
  for (; p + 3 < end; p += 4) {
    const int r0 = idx[p], r1 = idx[p + 1], r2 = idx[p + 2], r3 = idx[p + 3];
    u16x8 v0 = *reinterpret_cast<const u16x8*>(&table[(size_t)r0 * tstride + cl]);
    u16x8 v1 = *reinterpret_cast<const u16x8*>(&table[(size_t)r1 * tstride + cl]);
    u16x8 v2 = *reinterpret_cast<const u16x8*>(&table[(size_t)r2 * tstride + cl]);
    u16x8 v3 = *reinterpret_cast<const u16x8*>(&table[(size_t)r3 * tstride + cl]);
#pragma unroll
    for (int j = 0; j < 8; ++j) { a[j] += b2f(v0[j]); b[j] += b2f(v1[j]); }
#pragma unroll
    for (int j = 0; j < 8; ++j) { a[j] += b2f(v2[j]); b[j] += b2f(v3[j]); }
  }
  for (; p < end; ++p) {
    const int r0 = idx[p];
    u16x8 v0 = *reinterpret_cast<const u16x8*>(&table[(size_t)r0 * tstride + cl]);
#pragma unroll
    for (int j = 0; j < 8; ++j) a[j] += b2f(v0[j]);
  }
  float* dst = &out[(size_t)node * ostride + cl];
  float4 o0 = *reinterpret_cast<const float4*>(dst);
  float4 o1 = *reinterpret_cast<const float4*>(dst + 4);
  o0.x += (a[0] + b[0]) * sc; o0.y += (a[1] + b[1]) * sc;
  o0.z += (a[2] + b[2]) * sc; o0.w += (a[3] + b[3]) * sc;
  o1.x += (a[4] + b[4]) * sc; o1.y += (a[5] + b[5]) * sc;
  o1.z += (a[6] + b[6]) * sc; o1.w += (a[7] + b[7]) * sc;
  *reinterpret_cast<float4*>(dst) = o0;
  *reinterpret_cast<float4*>(dst + 4) = o1;
}

// ================= gather-add full 128 (f32 += mean), 16 nodes/block =================
__device__ __forceinline__ void gather_add_f32_128(
    const unsigned short* __restrict__ table, const int* __restrict__ off,
    const int* __restrict__ idx, float* __restrict__ out, int n, int bi) {
  const int t = threadIdx.x;
  const int g = t >> 4;
  const int cl = (t & 15) * 8;
  const int node = bi * 16 + g;
  if (node >= n) return;
  const int beg = off[node], end = off[node + 1];
  const float sc = 1.0f / fmaxf((float)(end - beg), 1.0f);
  float a[8] = {0, 0, 0, 0, 0, 0, 0, 0}, b[8] = {0, 0, 0, 0, 0, 0, 0, 0};
  int p = beg;
  for (; p + 3 < end; p += 4) {
    const int r0 = idx[p], r1 = idx[p + 1], r2 = idx[p + 2], r3 = idx[p + 3];
    u16x8 v0 = *reinterpret_cast<const u16x8*>(&table[(size_t)r0 * 128 + cl]);
    u16x8 v1 = *reinterpret_cast<const u16x8*>(&table[(size_t)r1 * 128 + cl]);
    u16x8 v2 = *reinterpret_cast<const u16x8*>(&table[(size_t)r2 * 128 + cl]);
    u16x8 v3 = *reinterpret_cast<const u16x8*>(&table[(size_t)r3 * 128 + cl]);
#pragma unroll
    for (int j = 0; j < 8; ++j) { a[j] += b2f(v0[j]); b[j] += b2f(v1[j]); }
#pragma unroll
    for (int j = 0; j < 8; ++j) { a[j] += b2f(v2[j]); b[j] += b2f(v3[j]); }
  }
  for (; p < end; ++p) {
    const int r0 = idx[p];
    u16x8 v0 = *reinterpret_cast<const u16x8*>(&table[(size_t)r0 * 128 + cl]);
#pragma unroll
    for (int j = 0; j < 8; ++j) a[j] += b2f(v0[j]);
  }
  float* dst = &out[(size_t)node * 128 + cl];
  float4 o0 = *reinterpret_cast<const float4*>(dst);
  float4 o1 = *reinterpret_cast<const float4*>(dst + 4);
  o0.x += (a[0] + b[0]) * sc; o0.y += (a[1] + b[1]) * sc;
  o0.z += (a[2] + b[2]) * sc; o0.w += (a[3] + b[3]) * sc;
  o1.x += (a[4] + b[4]) * sc; o1.y += (a[5] + b[5]) * sc;
  o1.z += (a[6] + b[6]) * sc; o1.w += (a[7] + b[7]) * sc;
  *reinterpret_cast<float4*>(dst) = o0;
  *reinterpret_cast<float4*>(dst + 4) = o1;
}

// gatherA: blocks [0,12500): M1u sliced (4 x 3125); rest 1250: M1m full-width
__global__ __launch_bounds__(256) void gatherA_kernel(
    const unsigned short* __restrict__ t1, const int* __restrict__ off_u,
    const int* __restrict__ csr_u, unsigned short* __restrict__ M1u,
    const unsigned short* __restrict__ xu, const int* __restrict__ off_m,
    const int* __restrict__ csr_m, unsigned short* __restrict__ xmcat) {
  if (blockIdx.x < 12500) {
    const int s = blockIdx.x / 3125;
    const int bi = blockIdx.x % 3125;
    gather_slice64(t1, 256, off_u, csr_u, M1u, 256, NU, s * 64, bi);
  } else {
    gather_core<128>(xu, off_m, csr_m, xmcat, NM, XMW, blockIdx.x - 12500);
  }
}

// gemmA: blocks [0,314) mode0 h_movie; rest 1564 mode1 h_user
__global__ __launch_bounds__(256) void gemmA_kernel(
    const unsigned short* __restrict__ xmcat, const unsigned short* __restrict__ wL1,
    const float* __restrict__ b1_rm, unsigned short* __restrict__ hm,
    const unsigned short* __restrict__ xu, const unsigned short* __restrict__ w1mur,
    const unsigned short* __restrict__ M1u, const float* __restrict__ b1_mu,
    unsigned short* __restrict__ hu) {
  __shared__ unsigned short Alds[128 * 32];
  __shared__ unsigned short Blds[128 * 32];
  if (blockIdx.x < 314) {
    int bi = blockIdx.x;
    gemm_core<0>(xmcat, XMW, wL1, XMW, XMW, nullptr, b1_rm, hm, NM,
                 bi % 157, bi / 157, Alds, Blds);
  } else {
    int bi = blockIdx.x - 314;
    gemm_core<1>(xu, 128, w1mur, 128, 128, M1u, b1_mu, hu, NU,
                 bi % 782, bi / 782, Alds, Blds);
  }
}

// gemmB2: [0,782) hul; [782,939) t2; [939,1721) pre_user; [1721,1878) pre_movie
__global__ __launch_bounds__(256) void gemmB2_kernel(
    const unsigned short* __restrict__ hu, const unsigned short* __restrict__ w2rml,
    unsigned short* __restrict__ hul,
    const unsigned short* __restrict__ hm, const unsigned short* __restrict__ w2mul,
    unsigned short* __restrict__ t2,
    const unsigned short* __restrict__ w2mur, const float* __restrict__ b2_mu,
    float* __restrict__ out_user,
    const unsigned short* __restrict__ w2rmr, const float* __restrict__ b2_rm,
    float* __restrict__ out_movie) {
  __shared__ unsigned short Alds[128 * 32];
  __shared__ unsigned short Blds[128 * 32];
  if (blockIdx.x < 782) {
    gemm_core<2>(hu, 256, w2rml, 256, 256, nullptr, nullptr, hul, NU,
                 blockIdx.x, 0, Alds, Blds);
  } else if (blockIdx.x < 939) {
    gemm_core<2>(hm, 256, w2mul, 256, 256, nullptr, nullptr, t2, NM,
                 blockIdx.x - 782, 0, Alds, Blds);
  } else if (blockIdx.x < 1721) {
    gemm_core<6>(hu, 256, w2mur, 256, 256, nullptr, b2_mu, out_user, NU,
                 blockIdx.x - 939, 0, Alds, Blds);
  } else {
    gemm_core<6>(hm, 256, w2rmr, 256, 256, nullptr, b2_rm, out_movie, NM,
                 blockIdx.x - 1721, 0, Alds, Blds);
  }
}

// gatherBC: blocks [0,6250): M2u sliced (2 x 3125) += out_user; rest 1250: M2m += out_movie
__global__ __launch_bounds__(256) void gatherBC_kernel(
    const unsigned short* __restrict__ t2, const int* __restrict__ off_u,
    const int* __restrict__ csr_u, float* __restrict__ out_user,
    const unsigned short* __restrict__ hul, const int* __restrict__ off_m,
    const int* __restrict__ csr_m, float* __restrict__ out_movie) {
  if (blockIdx.x < 6250) {
    const int s = blockIdx.x / 3125;
    const int bi = blockIdx.x % 3125;
    gather_add_slice64(t2, 128, off_u, csr_u, out_user, 128, NU, s * 64, bi);
  } else {
    gather_add_f32_128(hul, off_m, csr_m, out_movie, NM, blockIdx.x - 6250);
  }
}

extern "C" void kernel_launch(void* const* d_in, const int* in_sizes, int n_in,
                              void* d_out, int out_size, void* d_ws, size_t ws_size,
                              hipStream_t stream) {
  const float* x_user  = (const float*)d_in[0];
  const float* x_movie = (const float*)d_in[1];
  const int*   esrc    = (const int*)d_in[2];
  const int*   edst    = (const int*)d_in[3];
  const float* w1_rm_l = (const float*)d_in[4];
  const float* b1_rm   = (const float*)d_in[5];
  const float* w1_rm_r = (const float*)d_in[6];
  const float* w1_mu_l = (const float*)d_in[7];
  const float* b1_mu   = (const float*)d_in[8];
  const float* w1_mu_r = (const float*)d_in[9];
  const float* w2_rm_l = (const float*)d_in[10];
  const float* b2_rm   = (const float*)d_in[11];
  const float* w2_rm_r = (const float*)d_in[12];
  const float* w2_mu_l = (const float*)d_in[13];
  const float* b2_mu   = (const float*)d_in[14];
  const float* w2_mu_r = (const float*)d_in[15];

  if (ws_size < 214240008ull) return;
  char* wsb = (char*)d_ws;
  unsigned short* xu_bf  = (unsigned short*)(wsb + 0);           // 100000x128
  unsigned short* xmcat  = (unsigned short*)(wsb + 25600000);    // 20000x544
  unsigned short* hm_bf  = (unsigned short*)(wsb + 47360000);    // 20000x256
  unsigned short* t1_bf  = (unsigned short*)(wsb + 57600000);    // 20000x256
  unsigned short* t2_bf  = (unsigned short*)(wsb + 67840000);    // 20000x128
  unsigned short* M1u_bf = (unsigned short*)(wsb + 72960000);    // 100000x256
  unsigned short* hul_bf = (unsigned short*)(wsb + 72960000);    // 100000x128 (aliases M1u, dead)
  unsigned short* hu_bf  = (unsigned short*)(wsb + 149760000);   // 100000x256
  int* ebuf_m = (int*)(wsb + 149760000);                         // 1M ints (dead before hu write)
  int* ebuf_u = (int*)(wsb + 153760000);                         // 1M ints
  unsigned short* wts = (unsigned short*)(wsb + 200960000);
  unsigned short* wL1_t   = wts;            // 512x544
  unsigned short* w1mur_t = wts + 278528;   // 256x128
  unsigned short* wL2u_t  = wts + 311296;   // 256x256 [w2_rm_l | w2_mu_r]
  unsigned short* w2mul_t = wts + 376832;   // 128x256
  unsigned short* w2rmr_t = wts + 409600;   // 128x256
  int* iw     = (int*)(wsb + 201844736);
  int* cnt_m  = iw;                  // 64*313 = 20032
  int* base_m = iw + 20032;          // 20032
  int* cnt_u  = iw + 40064;          // 64*196 = 12544
  int* base_u = iw + 52608;          // 12544
  int* bo_m   = iw + 65152;          // 314
  int* bo_u   = iw + 65466;          // 197  (ends 65663 < 120000)
  int* off_m  = iw + 120000;         // 20001 (+pad)
  int* off_u  = iw + 140004;         // 100001 (+pad)
  int* csr_m  = iw + 240008;         // 1M
  int* csr_u  = iw + 1240008;        // 1M

  float* out_movie = (float*)d_out;
  float* out_user  = (float*)d_out + (size_t)NM * OUTDIM;

  // 1) passA: bucket counts (128 blocks) || prep conversions+transposes
  passA_kernel<<<2 * NBLK + (PRC + 255) / 256, 256, 0, stream>>>(
      esrc, edst, cnt_m, cnt_u,
      x_user, xu_bf, x_movie, xmcat,
      w1_rm_l, w1_rm_r, w1_mu_l, w1_mu_r, w2_rm_l, w2_mu_r, w2_mu_l, w2_rm_r,
      wL1_t, w1mur_t, wL2u_t, w2mul_t, w2rmr_t);

  // 2) scanAB: per-bucket bases + bucket offsets
  scanAB_kernel<<<2, 256, 0, stream>>>(cnt_m, base_m, bo_m, cnt_u, base_u, bo_u);

  // 3) passB: bucket-scatter (128 blocks) || t1 = x_movie @ w1_mu_l
  passB_kernel<<<2 * NBLK + 314, 256, 0, stream>>>(
      esrc, edst, base_m, base_u, ebuf_m, ebuf_u,
      xmcat + 128, wL1_t + 256 * XMW + 128, t1_bf);

  // 4) passC: per-bucket CSR + off arrays
  passC_kernel<<<NBKT_M + NBKT_U, 256, 0, stream>>>(
      ebuf_m, bo_m, off_m, csr_m, ebuf_u, bo_u, off_u, csr_u);

  // 5) gatherA: M1u sliced (L2-resident slices) || M1m
  gatherA_kernel<<<12500 + 1250, 256, 0, stream>>>(
      t1_bf, off_u, csr_u, M1u_bf, xu_bf, off_m, csr_m, xmcat);

  // 6) gemmA: h_movie || h_user
  gemmA_kernel<<<314 + 1564, 256, 0, stream>>>(
      xmcat, wL1_t, b1_rm, hm_bf, xu_bf, w1mur_t, M1u_bf, b1_mu, hu_bf);

  // 7) gemmB2: hul || t2 || pre_user || pre_movie
  gemmB2_kernel<<<1878, 256, 0, stream>>>(
      hu_bf, wL2u_t, hul_bf, hm_bf, w2mul_t, t2_bf,
      wL2u_t + 128 * 256, b2_mu, out_user, w2rmr_t, b2_rm, out_movie);

  // 8) gatherBC: += mean into outputs (f32, exclusive per node)
  gatherBC_kernel<<<6250 + 1250, 256, 0, stream>>>(
      t2_bf, off_u, csr_u, out_user, hul_bf, off_m, csr_m, out_movie);
}